// Round 9
// baseline (1117.332 us; speedup 1.0000x reference)
//
#include <hip/hip_runtime.h>
#include <hip/hip_bf16.h>

#define NN 4096
#define HD 128
#define KE 32
#define KI 20
#define XLD 132   // X LDS row stride in u32 (16B-aligned rows)
#define PLOF 68   // lo-plane column offset within a row (16B-aligned)

// output element offsets
#define OFF_H   0
#define OFF_POS 524288
#define OFF_F   536576
#define OFF_S   548864
#define OFF_C   794624
#define OFF_ST  1056768

typedef unsigned short u16;
typedef unsigned int u32;
typedef unsigned long long u64;
typedef __attribute__((ext_vector_type(8))) short bf16x8;   // 8 bf16 (4 VGPR)
typedef __attribute__((ext_vector_type(4))) float f32x4;

__device__ __forceinline__ float b2f(u16 u) {
  union { u32 i; float f; } c; c.i = ((u32)u) << 16; return c.f;
}
__device__ __forceinline__ float silu_f(float x) { return x / (1.f + __expf(-x)); }
__device__ __forceinline__ void stout(void* out, int fp32m, size_t i, float v) {
  if (fp32m) ((float*)out)[i] = v;
  else ((__hip_bfloat16*)out)[i] = __float2bfloat16(v);
}
// RNE float->bf16 bits (reference path, used in pack_weights)
__device__ __forceinline__ u32 f2b(float f) {
  u32 u = __float_as_uint(f);
  return (u + 0x7fffu + ((u >> 16) & 1u)) >> 16;
}
// hi/lo split of two adjacent values -> plane words (H=[b:a] hi, L=[b:a] lo)
__device__ __forceinline__ void packplane(float a, float b, u32& H, u32& L) {
  asm("v_cvt_pk_bf16_f32 %0, %1, %2" : "=v"(H) : "v"(a), "v"(b));
  float hfa = __uint_as_float(H << 16);
  float hfb = __uint_as_float(H & 0xffff0000u);
  asm("v_cvt_pk_bf16_f32 %0, %1, %2" : "=v"(L) : "v"(a - hfa), "v"(b - hfb));
}

// ---------------- dtype probe ----------------
__global__ void probe_dtype(const u16* __restrict__ h, int* __restrict__ flag) {
  if (threadIdx.x == 0) atomicExch(flag, 0);
  __syncthreads();
  int bad = 0;
  for (int i = threadIdx.x; i < 8192; i += 256) {
    float v = b2f(h[i]);
    if (!(v > -1000.f && v < 1000.f)) bad = 1;
  }
  if (bad) atomicOr(flag, 1);
}

// ---------------- convert all float tensors -> fp32 workspace ----------------
struct CvtTable {
  const void* src[25];
  int dstoff[25];
  int cnt[25];
};

__global__ void convert_all(CvtTable tab, float* __restrict__ wsf, const int* __restrict__ flag) {
  const int seg = blockIdx.y;
  const int i = blockIdx.x * 256 + threadIdx.x;
  if (i >= tab.cnt[seg]) return;
  float v;
  if (*flag) v = ((const float*)tab.src[seg])[i];
  else       v = b2f(((const u16*)tab.src[seg])[i]);
  wsf[tab.dstoff[seg] + i] = v;
}

// ------- pack stage weights: interleaved hi/lo MFMA fragments -------
// Layout: [mat 18][kt 4][ot 8][lane 64][16 u16] where [0..8)=hi j, [8..16)=lo j.
__global__ void pack_weights(const float* __restrict__ wsf, int offEW1, int offEW2, int offCW1,
                             u16* __restrict__ WBP) {
  int tid = blockIdx.x * 256 + threadIdx.x;
  if (tid >= 18 * 32768) return;
  int m = tid >> 15;
  int rix = tid & 32767;
  int layer = m / 3, s = m % 3;
  const float* src;
  if (s == 0)      src = wsf + offEW1 + (size_t)layer * 257 * HD + 128 * HD;
  else if (s == 1) src = wsf + offEW2 + (size_t)layer * HD * HD;
  else             src = wsf + offCW1 + (size_t)layer * HD * HD;
  int jh = rix & 15, lane = (rix >> 4) & 63, ot = (rix >> 10) & 7, kt = rix >> 13;
  int j = jh & 7;
  int f = kt * 32 + (lane >> 4) * 8 + j;
  int o = ot * 16 + (lane & 15);
  float v = src[f * HD + o];
  u32 hb = f2b(v);
  float hf = __uint_as_float(hb << 16);
  u32 lb = f2b(v - hf);
  WBP[tid] = (jh < 8) ? (u16)hb : (u16)lb;
}

// ---------------- graph boundaries from sorted batch ----------------
__global__ void graph_bounds(const int* __restrict__ batch, int* __restrict__ gstart) {
  int n = blockIdx.x * 256 + threadIdx.x;
  if (n >= NN) return;
  int v = batch[n];
  int pv = (n == 0) ? -1 : batch[n - 1];
  for (int b = pv + 1; b <= v; b++) gstart[b] = n;
  if (n == NN - 1) for (int b = v + 1; b <= 32; b++) gstart[b] = NN;
}

// ---------------- exact k-NN within cutoff (one wave per node) ----------------
__global__ __launch_bounds__(256) void neigh_kernel(
    const float* __restrict__ pos, const int* __restrict__ batch,
    const int* __restrict__ gstart, int* __restrict__ idx, int* __restrict__ cnt,
    int Ksel, float cut2) {
  const int lane = threadIdx.x & 63;
  const int i = blockIdx.x * 4 + (threadIdx.x >> 6);
  const int b = batch[i];
  const int gs = gstart[b];
  const int ge = gstart[b + 1];
  const int span = ge - gs;
  const float px = pos[i * 3 + 0], py = pos[i * 3 + 1], pz = pos[i * 3 + 2];
  u64 key[16];
#pragma unroll
  for (int tq = 0; tq < 16; tq++) {
    u64 k64 = ~0ull;
    if (tq * 64 < span) {
      int j = gs + tq * 64 + lane;
      if (j < ge && j != i) {
        float dx = px - pos[j * 3 + 0];
        float dy = py - pos[j * 3 + 1];
        float dz = pz - pos[j * 3 + 2];
        float d2 = dx * dx + dy * dy + dz * dz;
        if (d2 <= cut2) k64 = (((u64)__float_as_uint(d2)) << 32) | (u32)j;
      }
    }
    key[tq] = k64;
  }
  u64 thresh = 0;
  int myidx = i;
  int mycnt = 0;
  for (int s = 0; s < Ksel; s++) {
    u64 m = ~0ull;
#pragma unroll
    for (int tq = 0; tq < 16; tq++) {
      if (tq * 64 < span) {
        u64 kk = key[tq];
        if (kk >= thresh && kk < m) m = kk;
      }
    }
    for (int off = 32; off > 0; off >>= 1) {
      u64 o = __shfl_down(m, (unsigned)off, 64);
      if (o < m) m = o;
    }
    m = __shfl(m, 0, 64);
    if (m != ~0ull) {
      if (lane == s) myidx = (int)(m & 0xffffffffu);
      mycnt++;
      thresh = m + 1;
    } else break;
  }
  if (lane < Ksel) idx[i * Ksel + lane] = myidx;
  if (lane == 0) cnt[i] = mycnt;
}

// ---------------- fused EGNN layer: 256 thr / 4 waves / 2 nodes ----------------
// Edge stages: wave w owns o-tiles {w, w+4}. MFMA pass is kt-outer/Et-inner:
// only the current kt's 4 weight fragment pairs are live (16 VGPR vs 64 when
// all hoisted -- round 8's version spilled ~13 dwords/thread, WRITE_SIZE 30MB).
// Per-accumulator MFMA order unchanged (kt ascending, 3 terms): bit-identical.
__global__ __launch_bounds__(256, 4) void egnn_layer(
    const float* __restrict__ h_in, const float* __restrict__ pos_in,
    float* __restrict__ h_out, float* __restrict__ pos_out,
    const int* __restrict__ idx, const int* __restrict__ cnt,
    const float* __restrict__ ew1, const float* __restrict__ eb1,
    const float* __restrict__ eb2, const float* __restrict__ cb1,
    const float* __restrict__ cw2,
    const float* __restrict__ nw1, const float* __restrict__ nb1,
    const float* __restrict__ nw2, const float* __restrict__ nb2,
    const u16* __restrict__ wbp) {
  __shared__ __align__(16) u32 xp[64 * XLD];
  __shared__ float hi_s[2][HD], hp_s[2][HD], msum_s[2][HD];
  __shared__ float shpool[512];   // ce_red[64][8] (stages) then u_s[2][128] (MLP)
  __shared__ float rel_s[3][64], d2_s[64], mf_s[64], ce_s[64];
  __shared__ int idx_s[64], cn_s[2];
  float (*ce_red)[8] = reinterpret_cast<float(*)[8]>(shpool);
  float (*u_s)[HD] = reinterpret_cast<float(*)[HD]>(shpool);

  const int t = threadIdx.x;
  const int i0 = blockIdx.x * 2;
  const int lane = t & 63;
  const int w = __builtin_amdgcn_readfirstlane(t >> 6);  // 0..3
  const int l16 = lane & 15, q = lane >> 4;

  if (t < 64) idx_s[t] = idx[(size_t)(i0 + (t >> 5)) * KE + (t & 31)];
  else if (t < 66) cn_s[t - 64] = cnt[i0 + (t - 64)];
  {
    const int nd = t >> 7, f = t & 127;
    hi_s[nd][f] = h_in[(size_t)(i0 + nd) * HD + f];
  }
  __syncthreads();
  const int nt0 = __builtin_amdgcn_readfirstlane((cn_s[0] + 15) >> 4);
  const int nt1 = __builtin_amdgcn_readfirstlane((cn_s[1] + 15) >> 4);
#define LIVE(Et) (((Et) < 2) ? ((Et) < nt0) : ((Et) - 2 < nt1))

  if (t < 64) {
    const int nd = t >> 5, ic = i0 + nd;
    const int j = idx_s[t];
    const float rx = pos_in[ic * 3 + 0] - pos_in[j * 3 + 0];
    const float ry = pos_in[ic * 3 + 1] - pos_in[j * 3 + 1];
    const float rz = pos_in[ic * 3 + 2] - pos_in[j * 3 + 2];
    rel_s[0][t] = rx; rel_s[1][t] = ry; rel_s[2][t] = rz;
    d2_s[t] = rx * rx + ry * ry + rz * rz;
    mf_s[t] = ((t & 31) < cn_s[nd]) ? 1.0f : 0.0f;
  }
  // gather hj -> hi/lo planes; thread covers 32 f of one e row
  {
    const int e = t & 63;
    const int myEt = e >> 4;
    const bool glive = (myEt < 2) ? (myEt < nt0) : (myEt - 2 < nt1);
    if (glive) {
      const int j = idx_s[e];
      const int f0 = (t >> 6) * 32;
      const float4* src = (const float4*)(h_in + (size_t)j * HD + f0);
#pragma unroll
      for (int half = 0; half < 2; half++) {
        float4 v0 = src[half * 4 + 0], v1 = src[half * 4 + 1];
        float4 v2 = src[half * 4 + 2], v3 = src[half * 4 + 3];
        u32 H0, L0, H1, L1, H2, L2, H3, L3, H4, L4, H5, L5, H6, L6, H7, L7;
        packplane(v0.x, v0.y, H0, L0); packplane(v0.z, v0.w, H1, L1);
        packplane(v1.x, v1.y, H2, L2); packplane(v1.z, v1.w, H3, L3);
        packplane(v2.x, v2.y, H4, L4); packplane(v2.z, v2.w, H5, L5);
        packplane(v3.x, v3.y, H6, L6); packplane(v3.z, v3.w, H7, L7);
        u32* dh = xp + e * XLD + ((f0 + half * 16) >> 1);
        uint4 a; a.x = H0; a.y = H1; a.z = H2; a.w = H3;
        uint4 b; b.x = H4; b.y = H5; b.z = H6; b.w = H7;
        uint4 c; c.x = L0; c.y = L1; c.z = L2; c.w = L3;
        uint4 d; d.x = L4; d.y = L5; d.z = L6; d.w = L7;
        *(uint4*)(dh) = a;        *(uint4*)(dh + 4) = b;
        *(uint4*)(dh + PLOF) = c; *(uint4*)(dh + PLOF + 4) = d;
      }
    }
  }
  // hpart: hp_s[nd][o] = (sum f0..63) + (sum f64..127) + eb1  (round-7 order)
  {
    const int nd = t >> 7, oo = t & 127;
    float a = 0.f, b = 0.f;
#pragma unroll 4
    for (int f = 0; f < 64; f++) a = fmaf(hi_s[nd][f], ew1[(size_t)f * HD + oo], a);
#pragma unroll 4
    for (int f = 64; f < 128; f++) b = fmaf(hi_s[nd][f], ew1[(size_t)f * HD + oo], b);
    hp_s[nd][oo] = a + b + eb1[oo];
  }
  __syncthreads();

  // macro: one full 3-term dual-tile MFMA pass, kt-outer (low register pressure)
#define MFMA_PASS(WPBASE, accA, accB)                                          \
  {                                                                            \
    f32x4 z = {0.f, 0.f, 0.f, 0.f};                                            \
    accA[0] = z; accA[1] = z; accA[2] = z; accA[3] = z;                        \
    accB[0] = z; accB[1] = z; accB[2] = z; accB[3] = z;                        \
    _Pragma("unroll")                                                          \
    for (int kt = 0; kt < 4; kt++) {                                           \
      const u16* wa = (WPBASE) + (size_t)((kt * 8 + w) * 64 + lane) * 16;      \
      bf16x8 whA = *(const bf16x8*)(wa);                                       \
      bf16x8 wlA = *(const bf16x8*)(wa + 8);                                   \
      const u16* wb = (WPBASE) + (size_t)((kt * 8 + w + 4) * 64 + lane) * 16;  \
      bf16x8 whB = *(const bf16x8*)(wb);                                       \
      bf16x8 wlB = *(const bf16x8*)(wb + 8);                                   \
      _Pragma("unroll")                                                        \
      for (int Et = 0; Et < 4; Et++) {                                         \
        if (LIVE(Et)) {                                                        \
          const u32* xr = xp + (Et * 16 + l16) * XLD + kt * 16 + q * 4;        \
          bf16x8 xh = *(const bf16x8*)(xr);                                    \
          bf16x8 xl = *(const bf16x8*)(xr + PLOF);                             \
          accA[Et] = __builtin_amdgcn_mfma_f32_16x16x32_bf16(whA, xl, accA[Et], 0, 0, 0); \
          accA[Et] = __builtin_amdgcn_mfma_f32_16x16x32_bf16(wlA, xh, accA[Et], 0, 0, 0); \
          accA[Et] = __builtin_amdgcn_mfma_f32_16x16x32_bf16(whA, xh, accA[Et], 0, 0, 0); \
          accB[Et] = __builtin_amdgcn_mfma_f32_16x16x32_bf16(whB, xl, accB[Et], 0, 0, 0); \
          accB[Et] = __builtin_amdgcn_mfma_f32_16x16x32_bf16(wlB, xh, accB[Et], 0, 0, 0); \
          accB[Et] = __builtin_amdgcn_mfma_f32_16x16x32_bf16(whB, xh, accB[Et], 0, 0, 0); \
        }                                                                      \
      }                                                                        \
    }                                                                          \
  }

  // ---- stage B ----
  {
    f32x4 accA[4], accB[4];
    MFMA_PASS(wbp, accA, accB)
    __syncthreads();  // all plane reads done before in-place overwrite
#define EPIB(ACC, OT)                                                          \
    {                                                                          \
      const int o = (OT) * 16 + q * 4;                                         \
      const float4 w24 = *(const float4*)(ew1 + 256 * HD + o);                 \
      _Pragma("unroll")                                                        \
      for (int Et = 0; Et < 4; Et++) {                                         \
        if (LIVE(Et)) {                                                        \
          const int ee = Et * 16 + l16;                                        \
          const float d2e = d2_s[ee];                                          \
          const float4 hp4 = *(const float4*)(&hp_s[Et >> 1][o]);              \
          float s0 = silu_f(ACC[Et][0] + hp4.x + d2e * w24.x);                 \
          float s1 = silu_f(ACC[Et][1] + hp4.y + d2e * w24.y);                 \
          float s2 = silu_f(ACC[Et][2] + hp4.z + d2e * w24.z);                 \
          float s3 = silu_f(ACC[Et][3] + hp4.w + d2e * w24.w);                 \
          u32 H0, L0, H1, L1;                                                  \
          packplane(s0, s1, H0, L0);                                           \
          packplane(s2, s3, H1, L1);                                           \
          u32* dst = xp + ee * XLD + (OT) * 8 + q * 2;                         \
          uint2 hh; hh.x = H0; hh.y = H1;                                      \
          uint2 ll; ll.x = L0; ll.y = L1;                                      \
          *(uint2*)(dst) = hh;                                                 \
          *(uint2*)(dst + PLOF) = ll;                                          \
        }                                                                      \
      }                                                                        \
    }
    EPIB(accA, w)
    EPIB(accB, (w + 4))
#undef EPIB
  }
  __syncthreads();

  // ---- stage C (+ msum -> LDS) ----
  {
    f32x4 accA[4], accB[4];
    MFMA_PASS(wbp + 32768, accA, accB)
    __syncthreads();  // all reads done before in-place overwrite
    float msA0[4] = {0.f, 0.f, 0.f, 0.f}, msA1[4] = {0.f, 0.f, 0.f, 0.f};
    float msB0[4] = {0.f, 0.f, 0.f, 0.f}, msB1[4] = {0.f, 0.f, 0.f, 0.f};
#define EPIC(ACC, OT, MS0, MS1)                                                \
    {                                                                          \
      const int o = (OT) * 16 + q * 4;                                         \
      const float4 eb4 = *(const float4*)(eb2 + o);                            \
      _Pragma("unroll")                                                        \
      for (int Et = 0; Et < 4; Et++) {                                         \
        if (LIVE(Et)) {                                                        \
          const int ee = Et * 16 + l16;                                        \
          const float mfv = mf_s[ee];                                          \
          float m0 = (mfv != 0.f) ? silu_f(ACC[Et][0] + eb4.x) : 0.f;          \
          float m1 = (mfv != 0.f) ? silu_f(ACC[Et][1] + eb4.y) : 0.f;          \
          float m2 = (mfv != 0.f) ? silu_f(ACC[Et][2] + eb4.z) : 0.f;          \
          float m3 = (mfv != 0.f) ? silu_f(ACC[Et][3] + eb4.w) : 0.f;          \
          if (Et < 2) { MS0[0] += m0; MS0[1] += m1; MS0[2] += m2; MS0[3] += m3; } \
          else        { MS1[0] += m0; MS1[1] += m1; MS1[2] += m2; MS1[3] += m3; } \
          u32 H0, L0, H1, L1;                                                  \
          packplane(m0, m1, H0, L0);                                           \
          packplane(m2, m3, H1, L1);                                           \
          u32* dst = xp + ee * XLD + (OT) * 8 + q * 2;                         \
          uint2 hh; hh.x = H0; hh.y = H1;                                      \
          uint2 ll; ll.x = L0; ll.y = L1;                                      \
          *(uint2*)(dst) = hh;                                                 \
          *(uint2*)(dst + PLOF) = ll;                                          \
        }                                                                      \
      }                                                                        \
    }
    EPIC(accA, w, msA0, msA1)
    EPIC(accB, (w + 4), msB0, msB1)
#undef EPIC
#define RED16(v) v += __shfl_xor(v, 1); v += __shfl_xor(v, 2); \
                 v += __shfl_xor(v, 4); v += __shfl_xor(v, 8);
#pragma unroll
    for (int r = 0; r < 4; r++) { RED16(msA0[r]) RED16(msA1[r]) RED16(msB0[r]) RED16(msB1[r]) }
#undef RED16
    if (l16 == 0) {
      float4 a0; a0.x = msA0[0]; a0.y = msA0[1]; a0.z = msA0[2]; a0.w = msA0[3];
      float4 a1; a1.x = msA1[0]; a1.y = msA1[1]; a1.z = msA1[2]; a1.w = msA1[3];
      float4 b0; b0.x = msB0[0]; b0.y = msB0[1]; b0.z = msB0[2]; b0.w = msB0[3];
      float4 b1; b1.x = msB1[0]; b1.y = msB1[1]; b1.z = msB1[2]; b1.w = msB1[3];
      *(float4*)(&msum_s[0][w * 16 + q * 4]) = a0;
      *(float4*)(&msum_s[1][w * 16 + q * 4]) = a1;
      *(float4*)(&msum_s[0][(w + 4) * 16 + q * 4]) = b0;
      *(float4*)(&msum_s[1][(w + 4) * 16 + q * 4]) = b1;
    }
  }
  __syncthreads();

  // ---- stage D: coord head ----
  {
    f32x4 accA[4], accB[4];
    MFMA_PASS(wbp + 65536, accA, accB)
#define EPID(ACC, OT)                                                          \
    {                                                                          \
      const int o = (OT) * 16 + q * 4;                                         \
      const float4 cb4 = *(const float4*)(cb1 + o);                            \
      const float4 cw4 = *(const float4*)(cw2 + o);                            \
      _Pragma("unroll")                                                        \
      for (int Et = 0; Et < 4; Et++) {                                         \
        if (LIVE(Et)) {                                                        \
          float p = silu_f(ACC[Et][0] + cb4.x) * cw4.x;                        \
          p = fmaf(silu_f(ACC[Et][1] + cb4.y), cw4.y, p);                      \
          p = fmaf(silu_f(ACC[Et][2] + cb4.z), cw4.z, p);                      \
          p = fmaf(silu_f(ACC[Et][3] + cb4.w), cw4.w, p);                      \
          p += __shfl_xor(p, 16);                                              \
          p += __shfl_xor(p, 32);                                              \
          if (lane < 16) ce_red[Et * 16 + lane][OT] = p;                       \
        }                                                                      \
      }                                                                        \
    }
    EPID(accA, w)
    EPID(accB, (w + 4))
#undef EPID
  }
  __syncthreads();
  if (t < 64) {
    float c = 0.f;
#pragma unroll
    for (int wv = 0; wv < 8; wv++) c += ce_red[t][wv];
    ce_s[t] = (mf_s[t] != 0.f) ? c : 0.f;
  }
  __syncthreads();
  // ---- pos update + node MLP1 (u_s aliases ce_red: consumed above) ----
  if (t < 6) {
    const int nd = t / 3, ax = t - nd * 3, ic = i0 + nd;
    float s = 0.f;
#pragma unroll
    for (int k = 0; k < 32; k++) s = fmaf(rel_s[ax][nd * 32 + k], ce_s[nd * 32 + k], s);
    const float cntf = fmaxf((float)cn_s[nd], 1.f);
    pos_out[ic * 3 + ax] = pos_in[ic * 3 + ax] + s / cntf;
  }
  {
    const int nd = t >> 7, oo = t & 127;
    float p1 = 0.f, p2 = 0.f;
#pragma unroll 4
    for (int f = 0; f < 128; f++) p1 = fmaf(hi_s[nd][f], nw1[(size_t)f * HD + oo], p1);
#pragma unroll 4
    for (int f = 0; f < 128; f++) p2 = fmaf(msum_s[nd][f], nw1[(size_t)(128 + f) * HD + oo], p2);
    const float uv = silu_f(p1 + p2 + nb1[oo]);
    __syncthreads();          // ce_red fully consumed before aliased write
    u_s[nd][oo] = uv;
  }
  __syncthreads();
  // ---- node MLP2 + residual ----
  {
    const int nd = t >> 7, oo = t & 127;
    float q1 = 0.f, q2 = 0.f;
#pragma unroll 4
    for (int f = 0; f < 64; f++) q1 = fmaf(u_s[nd][f], nw2[(size_t)f * HD + oo], q1);
#pragma unroll 4
    for (int f = 64; f < 128; f++) q2 = fmaf(u_s[nd][f], nw2[(size_t)f * HD + oo], q2);
    h_out[(size_t)(i0 + nd) * HD + oo] = hi_s[nd][oo] + q1 + q2 + nb2[oo];
  }
#undef LIVE
#undef MFMA_PASS
}

// ---------------- final heads (per node) ----------------
__global__ __launch_bounds__(256) void heads_kernel(
    const float* __restrict__ h, const float* __restrict__ pos,
    const float* __restrict__ fw1, const float* __restrict__ fb1,
    const float* __restrict__ fw2, const float* __restrict__ fb2,
    const float* __restrict__ cw1g, const float* __restrict__ cb1g,
    const float* __restrict__ cw2g, const float* __restrict__ cb2g,
    const float* __restrict__ sw, const float* __restrict__ sb,
    const float* __restrict__ iw,
    float* __restrict__ At, float* __restrict__ Bt,
    void* __restrict__ out, const int* __restrict__ flag) {
  __shared__ float hi_s[HD], v1[HD], red_s[256];
  const int i = blockIdx.x, t = threadIdx.x;
  const int fm = *flag;
  if (t < HD) hi_s[t] = h[(size_t)i * HD + t];
  __syncthreads();
  const int o = t & 127, ph = t >> 7;
  // forces MLP1
  {
    float p = 0.f;
#pragma unroll 4
    for (int f = ph * 64; f < ph * 64 + 64; f++) p = fmaf(hi_s[f], fw1[f * HD + o], p);
    red_s[t] = p;
  }
  __syncthreads();
  if (t < HD) v1[t] = tanhf(red_s[t] + red_s[t + 128] + fb1[t]);
  __syncthreads();
  if (t < 3) {
    float p = 0.f;
    for (int f = 0; f < HD; f++) p = fmaf(v1[f], fw2[f * 3 + t], p);
    stout(out, fm, OFF_F + (size_t)i * 3 + t, p + fb2[t]);
  }
  __syncthreads();
  // conformer MLP1
  {
    float p = 0.f;
#pragma unroll 4
    for (int f = ph * 64; f < ph * 64 + 64; f++) p = fmaf(hi_s[f], cw1g[f * HD + o], p);
    red_s[t] = p;
  }
  __syncthreads();
  if (t < HD) v1[t] = fmaxf(red_s[t] + red_s[t + 128] + cb1g[t], 0.f);
  __syncthreads();
  // conformer MLP2
  {
    const int oo = t & 63, pc = t >> 6;
    float p = 0.f;
#pragma unroll 4
    for (int f = pc * 32; f < pc * 32 + 32; f++) p = fmaf(v1[f], cw2g[f * 64 + oo], p);
    red_s[t] = p;
  }
  __syncthreads();
  if (t < 64)
    stout(out, fm, OFF_C + (size_t)i * 64 + t,
          red_s[t] + red_s[t + 64] + red_s[t + 128] + red_s[t + 192] + cb2g[t]);
  __syncthreads();
  // steric
  if (t < HD) red_s[t] = hi_s[t] * sw[t];
  __syncthreads();
  if (t == 0) {
    float p = 0.f;
    for (int f = 0; f < HD; f++) p += red_s[f];
    stout(out, fm, OFF_ST + (size_t)i, p + sb[0]);
  }
  __syncthreads();
  // interaction head per-node dots
  {
    const int g = t >> 5, l = t & 31;
    float p = 0.f;
    if (g < 6) {
      const int tt = g >> 1, half = g & 1;
#pragma unroll
      for (int r2 = 0; r2 < 4; r2++)
        p = fmaf(hi_s[l * 4 + r2], iw[tt * 258 + half * 128 + l * 4 + r2], p);
    }
    red_s[t] = p;
  }
  __syncthreads();
  if (t < 6) {
    float p = 0.f;
    for (int l = 0; l < 32; l++) p += red_s[t * 32 + l];
    const int tt = t >> 1;
    if ((t & 1) == 0) At[tt * NN + i] = p;
    else Bt[tt * NN + i] = p;
  }
  if (t < HD) stout(out, fm, OFF_H + (size_t)i * HD + t, hi_s[t]);
  if (t >= 128 && t < 131) stout(out, fm, OFF_POS + (size_t)i * 3 + (t - 128), pos[i * 3 + (t - 128)]);
}

// ---------------- interaction scores ----------------
__global__ void scores_kernel(const float* __restrict__ pos, const int* __restrict__ idx2,
                              const int* __restrict__ cnt2, const float* __restrict__ At,
                              const float* __restrict__ Bt, const float* __restrict__ iw,
                              const float* __restrict__ ib, void* __restrict__ out,
                              const int* __restrict__ flag) {
  int tid = blockIdx.x * 256 + threadIdx.x;
  if (tid >= 3 * NN * KI) return;
  const int fm = *flag;
  const int tt = tid / (NN * KI);
  const int r = tid % (NN * KI);
  const int n = r / KI;
  const int k = r % KI;
  float v = 0.f;
  if (k < cnt2[n]) {
    int j = idx2[n * KI + k];
    float dx = pos[n * 3 + 0] - pos[j * 3 + 0];
    float dy = pos[n * 3 + 1] - pos[j * 3 + 1];
    float dz = pos[n * 3 + 2] - pos[j * 3 + 2];
    float d2 = dx * dx + dy * dy + dz * dz;
    float dist = sqrtf(d2 + 1e-12f);
    float s = At[tt * NN + n] + Bt[tt * NN + j] + dist * iw[tt * 258 + 256] +
              (dist * 0.1f) * iw[tt * 258 + 257] + ib[tt];
    v = 1.f / (1.f + __expf(-s));
  }
  stout(out, fm, OFF_S + (size_t)tid, v);
}

extern "C" void kernel_launch(void* const* d_in, const int* in_sizes, int n_in,
                              void* d_out, int out_size, void* d_ws, size_t ws_size,
                              hipStream_t stream) {
  (void)in_sizes; (void)n_in; (void)out_size; (void)ws_size;

  float* wsf = (float*)d_ws;
  float* h_a = wsf + 0;             // 524288
  float* pos_a = wsf + 524288;      // 12288
  float* h_b = wsf + 536576;        // 524288
  float* pos_b = wsf + 1060864;     // 12288
  float* At = wsf + 1073152;        // 12288
  float* Bt = wsf + 1085440;        // 12288
  const int W0 = 1097728;

  static const int wcnt[23] = {197376, 768, 98304, 768, 98304, 768, 768,
                               196608, 768, 98304, 768, 16384, 128, 384, 3,
                               774, 3, 16384, 128, 8192, 64, 128, 1};
  int woff[23];
  {
    int o = W0;
    for (int k = 0; k < 23; k++) { woff[k] = o; o += wcnt[k]; }
  }
  const int IOFF = woff[22] + wcnt[22];
  int* ibase = (int*)d_ws;
  int* idx1 = ibase + IOFF;
  int* cnt1 = idx1 + NN * KE;
  int* idx2 = cnt1 + NN;
  int* cnt2 = idx2 + NN * KI;
  int* gstart = cnt2 + NN;
  int* flag = gstart + 33;
  // packed interleaved MFMA weight fragments, 16B-aligned
  int wboff = (int)((flag + 1) - ibase);
  wboff = (wboff + 3) & ~3;
  u16* WBP = (u16*)(ibase + wboff);

  const float* EW1 = wsf + woff[0];
  const float* EB1 = wsf + woff[1];
  const float* EB2 = wsf + woff[3];
  const float* CB1 = wsf + woff[5];
  const float* CW2 = wsf + woff[6];
  const float* NW1 = wsf + woff[7];
  const float* NB1 = wsf + woff[8];
  const float* NW2 = wsf + woff[9];
  const float* NB2 = wsf + woff[10];
  const float* FW1 = wsf + woff[11];
  const float* FB1 = wsf + woff[12];
  const float* FW2 = wsf + woff[13];
  const float* FB2 = wsf + woff[14];
  const float* IW = wsf + woff[15];
  const float* IB = wsf + woff[16];
  const float* CW1G = wsf + woff[17];
  const float* CB1G = wsf + woff[18];
  const float* CW2G = wsf + woff[19];
  const float* CB2G = wsf + woff[20];
  const float* SW = wsf + woff[21];
  const float* SB = wsf + woff[22];

  probe_dtype<<<1, 256, 0, stream>>>((const u16*)d_in[0], flag);

  CvtTable tab;
  tab.src[0] = d_in[0]; tab.dstoff[0] = 0;       tab.cnt[0] = NN * HD;
  tab.src[1] = d_in[1]; tab.dstoff[1] = 524288;  tab.cnt[1] = NN * 3;
  for (int k = 0; k < 23; k++) {
    tab.src[2 + k] = d_in[3 + k];
    tab.dstoff[2 + k] = woff[k];
    tab.cnt[2 + k] = wcnt[k];
  }
  {
    dim3 g((NN * HD + 255) / 256, 25, 1);
    convert_all<<<g, 256, 0, stream>>>(tab, wsf, flag);
  }
  pack_weights<<<(18 * 32768 + 255) / 256, 256, 0, stream>>>(
      wsf, woff[0], woff[2], woff[4], WBP);

  const int* batch = (const int*)d_in[2];
  graph_bounds<<<NN / 256, 256, 0, stream>>>(batch, gstart);

  const float cut2s[3] = {9.f, 36.f, 100.f};
  float *hin = h_a, *pin = pos_a, *hout = h_b, *pout = pos_b;
  for (int l = 0; l < 6; l++) {
    if ((l & 1) == 0)
      neigh_kernel<<<NN / 4, 256, 0, stream>>>(pin, batch, gstart, idx1, cnt1, KE, cut2s[l >> 1]);
    egnn_layer<<<NN / 2, 256, 0, stream>>>(
        hin, pin, hout, pout, idx1, cnt1,
        EW1 + (size_t)l * 257 * HD, EB1 + (size_t)l * HD,
        EB2 + (size_t)l * HD, CB1 + (size_t)l * HD, CW2 + (size_t)l * HD,
        NW1 + (size_t)l * 256 * HD, NB1 + (size_t)l * HD,
        NW2 + (size_t)l * HD * HD, NB2 + (size_t)l * HD,
        WBP + (size_t)l * 3 * 32768);
    float* th = hin; hin = hout; hout = th;
    float* tp = pin; pin = pout; pout = tp;
  }
  neigh_kernel<<<NN / 4, 256, 0, stream>>>(pin, batch, gstart, idx2, cnt2, KI, 100.f);
  heads_kernel<<<NN, 256, 0, stream>>>(hin, pin, FW1, FB1, FW2, FB2, CW1G, CB1G, CW2G, CB2G,
                                       SW, SB, IW, At, Bt, d_out, flag);
  scores_kernel<<<(3 * NN * KI + 255) / 256, 256, 0, stream>>>(
      pin, idx2, cnt2, At, Bt, IW, IB, d_out, flag);
}

// Round 10
// 1070.121 us; speedup vs baseline: 1.0441x; 1.0441x over previous
//
#include <hip/hip_runtime.h>
#include <hip/hip_bf16.h>

#define NN 4096
#define HD 128
#define KE 32
#define KI 20
#define XLD 132   // X LDS row stride in u32 (16B-aligned rows)
#define PLOF 68   // lo-plane column offset within a row (16B-aligned)

// output element offsets
#define OFF_H   0
#define OFF_POS 524288
#define OFF_F   536576
#define OFF_S   548864
#define OFF_C   794624
#define OFF_ST  1056768

typedef unsigned short u16;
typedef unsigned int u32;
typedef unsigned long long u64;
typedef __attribute__((ext_vector_type(8))) short bf16x8;   // 8 bf16 (4 VGPR)
typedef __attribute__((ext_vector_type(4))) float f32x4;

__device__ __forceinline__ float b2f(u16 u) {
  union { u32 i; float f; } c; c.i = ((u32)u) << 16; return c.f;
}
__device__ __forceinline__ float silu_f(float x) { return x / (1.f + __expf(-x)); }
__device__ __forceinline__ void stout(void* out, int fp32m, size_t i, float v) {
  if (fp32m) ((float*)out)[i] = v;
  else ((__hip_bfloat16*)out)[i] = __float2bfloat16(v);
}
// RNE float->bf16 bits (reference path, used in pack_weights)
__device__ __forceinline__ u32 f2b(float f) {
  u32 u = __float_as_uint(f);
  return (u + 0x7fffu + ((u >> 16) & 1u)) >> 16;
}
// hi/lo split of two adjacent values -> plane words (H=[b:a] hi, L=[b:a] lo)
__device__ __forceinline__ void packplane(float a, float b, u32& H, u32& L) {
  asm("v_cvt_pk_bf16_f32 %0, %1, %2" : "=v"(H) : "v"(a), "v"(b));
  float hfa = __uint_as_float(H << 16);
  float hfb = __uint_as_float(H & 0xffff0000u);
  asm("v_cvt_pk_bf16_f32 %0, %1, %2" : "=v"(L) : "v"(a - hfa), "v"(b - hfb));
}

// ---------------- dtype probe ----------------
__global__ void probe_dtype(const u16* __restrict__ h, int* __restrict__ flag) {
  if (threadIdx.x == 0) atomicExch(flag, 0);
  __syncthreads();
  int bad = 0;
  for (int i = threadIdx.x; i < 8192; i += 256) {
    float v = b2f(h[i]);
    if (!(v > -1000.f && v < 1000.f)) bad = 1;
  }
  if (bad) atomicOr(flag, 1);
}

// ---------------- convert all float tensors -> fp32 workspace ----------------
struct CvtTable {
  const void* src[25];
  int dstoff[25];
  int cnt[25];
};

__global__ void convert_all(CvtTable tab, float* __restrict__ wsf, const int* __restrict__ flag) {
  const int seg = blockIdx.y;
  const int i = blockIdx.x * 256 + threadIdx.x;
  if (i >= tab.cnt[seg]) return;
  float v;
  if (*flag) v = ((const float*)tab.src[seg])[i];
  else       v = b2f(((const u16*)tab.src[seg])[i]);
  wsf[tab.dstoff[seg] + i] = v;
}

// ------- pack stage weights: interleaved hi/lo MFMA fragments -------
// Layout: [mat 18][kt 4][ot 8][lane 64][16 u16] where [0..8)=hi j, [8..16)=lo j.
__global__ void pack_weights(const float* __restrict__ wsf, int offEW1, int offEW2, int offCW1,
                             u16* __restrict__ WBP) {
  int tid = blockIdx.x * 256 + threadIdx.x;
  if (tid >= 18 * 32768) return;
  int m = tid >> 15;
  int rix = tid & 32767;
  int layer = m / 3, s = m % 3;
  const float* src;
  if (s == 0)      src = wsf + offEW1 + (size_t)layer * 257 * HD + 128 * HD;
  else if (s == 1) src = wsf + offEW2 + (size_t)layer * HD * HD;
  else             src = wsf + offCW1 + (size_t)layer * HD * HD;
  int jh = rix & 15, lane = (rix >> 4) & 63, ot = (rix >> 10) & 7, kt = rix >> 13;
  int j = jh & 7;
  int f = kt * 32 + (lane >> 4) * 8 + j;
  int o = ot * 16 + (lane & 15);
  float v = src[f * HD + o];
  u32 hb = f2b(v);
  float hf = __uint_as_float(hb << 16);
  u32 lb = f2b(v - hf);
  WBP[tid] = (jh < 8) ? (u16)hb : (u16)lb;
}

// ---------------- graph boundaries from sorted batch ----------------
__global__ void graph_bounds(const int* __restrict__ batch, int* __restrict__ gstart) {
  int n = blockIdx.x * 256 + threadIdx.x;
  if (n >= NN) return;
  int v = batch[n];
  int pv = (n == 0) ? -1 : batch[n - 1];
  for (int b = pv + 1; b <= v; b++) gstart[b] = n;
  if (n == NN - 1) for (int b = v + 1; b <= 32; b++) gstart[b] = NN;
}

// ---------------- exact k-NN within cutoff (one wave per node) ----------------
__global__ __launch_bounds__(256) void neigh_kernel(
    const float* __restrict__ pos, const int* __restrict__ batch,
    const int* __restrict__ gstart, int* __restrict__ idx, int* __restrict__ cnt,
    int Ksel, float cut2) {
  const int lane = threadIdx.x & 63;
  const int i = blockIdx.x * 4 + (threadIdx.x >> 6);
  const int b = batch[i];
  const int gs = gstart[b];
  const int ge = gstart[b + 1];
  const int span = ge - gs;
  const float px = pos[i * 3 + 0], py = pos[i * 3 + 1], pz = pos[i * 3 + 2];
  u64 key[16];
#pragma unroll
  for (int tq = 0; tq < 16; tq++) {
    u64 k64 = ~0ull;
    if (tq * 64 < span) {
      int j = gs + tq * 64 + lane;
      if (j < ge && j != i) {
        float dx = px - pos[j * 3 + 0];
        float dy = py - pos[j * 3 + 1];
        float dz = pz - pos[j * 3 + 2];
        float d2 = dx * dx + dy * dy + dz * dz;
        if (d2 <= cut2) k64 = (((u64)__float_as_uint(d2)) << 32) | (u32)j;
      }
    }
    key[tq] = k64;
  }
  u64 thresh = 0;
  int myidx = i;
  int mycnt = 0;
  for (int s = 0; s < Ksel; s++) {
    u64 m = ~0ull;
#pragma unroll
    for (int tq = 0; tq < 16; tq++) {
      if (tq * 64 < span) {
        u64 kk = key[tq];
        if (kk >= thresh && kk < m) m = kk;
      }
    }
    for (int off = 32; off > 0; off >>= 1) {
      u64 o = __shfl_down(m, (unsigned)off, 64);
      if (o < m) m = o;
    }
    m = __shfl(m, 0, 64);
    if (m != ~0ull) {
      if (lane == s) myidx = (int)(m & 0xffffffffu);
      mycnt++;
      thresh = m + 1;
    } else break;
  }
  if (lane < Ksel) idx[i * Ksel + lane] = myidx;
  if (lane == 0) cnt[i] = mycnt;
}

// ---------------- fused EGNN layer: 256 thr / 4 waves / 2 nodes ----------------
// Edge stages: wave w owns o-tiles {w, w+4}. (256,3) occupancy floor: the fused
// kernel's peak register demand is ~130-140 unified regs (edge phase alone fits
// (256,4)'s 128 exactly -- round 7; fusion pushed it over and (256,4) spilled
// 13-28 dwords/thread -> 30-112 MB of scratch traffic, rounds 8/9). Budget 170
// regs at 3 waves/EU eliminates the spill; LDS 40KB still allows 3 blocks/CU.
__global__ __launch_bounds__(256, 3) void egnn_layer(
    const float* __restrict__ h_in, const float* __restrict__ pos_in,
    float* __restrict__ h_out, float* __restrict__ pos_out,
    const int* __restrict__ idx, const int* __restrict__ cnt,
    const float* __restrict__ ew1, const float* __restrict__ eb1,
    const float* __restrict__ eb2, const float* __restrict__ cb1,
    const float* __restrict__ cw2,
    const float* __restrict__ nw1, const float* __restrict__ nb1,
    const float* __restrict__ nw2, const float* __restrict__ nb2,
    const u16* __restrict__ wbp) {
  __shared__ __align__(16) u32 xp[64 * XLD];
  __shared__ float hi_s[2][HD], hp_s[2][HD], msum_s[2][HD];
  __shared__ float shpool[512];   // ce_red[64][8] (stages) then u_s[2][128] (MLP)
  __shared__ float rel_s[3][64], d2_s[64], mf_s[64], ce_s[64];
  __shared__ int idx_s[64], cn_s[2];
  float (*ce_red)[8] = reinterpret_cast<float(*)[8]>(shpool);
  float (*u_s)[HD] = reinterpret_cast<float(*)[HD]>(shpool);

  const int t = threadIdx.x;
  const int i0 = blockIdx.x * 2;
  const int lane = t & 63;
  const int w = __builtin_amdgcn_readfirstlane(t >> 6);  // 0..3
  const int l16 = lane & 15, q = lane >> 4;

  if (t < 64) idx_s[t] = idx[(size_t)(i0 + (t >> 5)) * KE + (t & 31)];
  else if (t < 66) cn_s[t - 64] = cnt[i0 + (t - 64)];
  {
    const int nd = t >> 7, f = t & 127;
    hi_s[nd][f] = h_in[(size_t)(i0 + nd) * HD + f];
  }
  __syncthreads();
  const int nt0 = __builtin_amdgcn_readfirstlane((cn_s[0] + 15) >> 4);
  const int nt1 = __builtin_amdgcn_readfirstlane((cn_s[1] + 15) >> 4);
#define LIVE(Et) (((Et) < 2) ? ((Et) < nt0) : ((Et) - 2 < nt1))

  if (t < 64) {
    const int nd = t >> 5, ic = i0 + nd;
    const int j = idx_s[t];
    const float rx = pos_in[ic * 3 + 0] - pos_in[j * 3 + 0];
    const float ry = pos_in[ic * 3 + 1] - pos_in[j * 3 + 1];
    const float rz = pos_in[ic * 3 + 2] - pos_in[j * 3 + 2];
    rel_s[0][t] = rx; rel_s[1][t] = ry; rel_s[2][t] = rz;
    d2_s[t] = rx * rx + ry * ry + rz * rz;
    mf_s[t] = ((t & 31) < cn_s[nd]) ? 1.0f : 0.0f;
  }
  // gather hj -> hi/lo planes; thread covers 32 f of one e row
  {
    const int e = t & 63;
    const int myEt = e >> 4;
    const bool glive = (myEt < 2) ? (myEt < nt0) : (myEt - 2 < nt1);
    if (glive) {
      const int j = idx_s[e];
      const int f0 = (t >> 6) * 32;
      const float4* src = (const float4*)(h_in + (size_t)j * HD + f0);
#pragma unroll
      for (int half = 0; half < 2; half++) {
        float4 v0 = src[half * 4 + 0], v1 = src[half * 4 + 1];
        float4 v2 = src[half * 4 + 2], v3 = src[half * 4 + 3];
        u32 H0, L0, H1, L1, H2, L2, H3, L3, H4, L4, H5, L5, H6, L6, H7, L7;
        packplane(v0.x, v0.y, H0, L0); packplane(v0.z, v0.w, H1, L1);
        packplane(v1.x, v1.y, H2, L2); packplane(v1.z, v1.w, H3, L3);
        packplane(v2.x, v2.y, H4, L4); packplane(v2.z, v2.w, H5, L5);
        packplane(v3.x, v3.y, H6, L6); packplane(v3.z, v3.w, H7, L7);
        u32* dh = xp + e * XLD + ((f0 + half * 16) >> 1);
        uint4 a; a.x = H0; a.y = H1; a.z = H2; a.w = H3;
        uint4 b; b.x = H4; b.y = H5; b.z = H6; b.w = H7;
        uint4 c; c.x = L0; c.y = L1; c.z = L2; c.w = L3;
        uint4 d; d.x = L4; d.y = L5; d.z = L6; d.w = L7;
        *(uint4*)(dh) = a;        *(uint4*)(dh + 4) = b;
        *(uint4*)(dh + PLOF) = c; *(uint4*)(dh + PLOF + 4) = d;
      }
    }
  }
  // hpart: hp_s[nd][o] = (sum f0..63) + (sum f64..127) + eb1  (round-7 order)
  {
    const int nd = t >> 7, oo = t & 127;
    float a = 0.f, b = 0.f;
#pragma unroll 4
    for (int f = 0; f < 64; f++) a = fmaf(hi_s[nd][f], ew1[(size_t)f * HD + oo], a);
#pragma unroll 4
    for (int f = 64; f < 128; f++) b = fmaf(hi_s[nd][f], ew1[(size_t)f * HD + oo], b);
    hp_s[nd][oo] = a + b + eb1[oo];
  }
  __syncthreads();

  // macro: one full 3-term dual-tile MFMA pass, kt-outer
#define MFMA_PASS(WPBASE, accA, accB)                                          \
  {                                                                            \
    f32x4 z = {0.f, 0.f, 0.f, 0.f};                                            \
    accA[0] = z; accA[1] = z; accA[2] = z; accA[3] = z;                        \
    accB[0] = z; accB[1] = z; accB[2] = z; accB[3] = z;                        \
    _Pragma("unroll")                                                          \
    for (int kt = 0; kt < 4; kt++) {                                           \
      const u16* wa = (WPBASE) + (size_t)((kt * 8 + w) * 64 + lane) * 16;      \
      bf16x8 whA = *(const bf16x8*)(wa);                                       \
      bf16x8 wlA = *(const bf16x8*)(wa + 8);                                   \
      const u16* wb = (WPBASE) + (size_t)((kt * 8 + w + 4) * 64 + lane) * 16;  \
      bf16x8 whB = *(const bf16x8*)(wb);                                       \
      bf16x8 wlB = *(const bf16x8*)(wb + 8);                                   \
      _Pragma("unroll")                                                        \
      for (int Et = 0; Et < 4; Et++) {                                         \
        if (LIVE(Et)) {                                                        \
          const u32* xr = xp + (Et * 16 + l16) * XLD + kt * 16 + q * 4;        \
          bf16x8 xh = *(const bf16x8*)(xr);                                    \
          bf16x8 xl = *(const bf16x8*)(xr + PLOF);                             \
          accA[Et] = __builtin_amdgcn_mfma_f32_16x16x32_bf16(whA, xl, accA[Et], 0, 0, 0); \
          accA[Et] = __builtin_amdgcn_mfma_f32_16x16x32_bf16(wlA, xh, accA[Et], 0, 0, 0); \
          accA[Et] = __builtin_amdgcn_mfma_f32_16x16x32_bf16(whA, xh, accA[Et], 0, 0, 0); \
          accB[Et] = __builtin_amdgcn_mfma_f32_16x16x32_bf16(whB, xl, accB[Et], 0, 0, 0); \
          accB[Et] = __builtin_amdgcn_mfma_f32_16x16x32_bf16(wlB, xh, accB[Et], 0, 0, 0); \
          accB[Et] = __builtin_amdgcn_mfma_f32_16x16x32_bf16(whB, xh, accB[Et], 0, 0, 0); \
        }                                                                      \
      }                                                                        \
    }                                                                          \
  }

  // ---- stage B ----
  {
    f32x4 accA[4], accB[4];
    MFMA_PASS(wbp, accA, accB)
    __syncthreads();  // all plane reads done before in-place overwrite
#define EPIB(ACC, OT)                                                          \
    {                                                                          \
      const int o = (OT) * 16 + q * 4;                                         \
      const float4 w24 = *(const float4*)(ew1 + 256 * HD + o);                 \
      _Pragma("unroll")                                                        \
      for (int Et = 0; Et < 4; Et++) {                                         \
        if (LIVE(Et)) {                                                        \
          const int ee = Et * 16 + l16;                                        \
          const float d2e = d2_s[ee];                                          \
          const float4 hp4 = *(const float4*)(&hp_s[Et >> 1][o]);              \
          float s0 = silu_f(ACC[Et][0] + hp4.x + d2e * w24.x);                 \
          float s1 = silu_f(ACC[Et][1] + hp4.y + d2e * w24.y);                 \
          float s2 = silu_f(ACC[Et][2] + hp4.z + d2e * w24.z);                 \
          float s3 = silu_f(ACC[Et][3] + hp4.w + d2e * w24.w);                 \
          u32 H0, L0, H1, L1;                                                  \
          packplane(s0, s1, H0, L0);                                           \
          packplane(s2, s3, H1, L1);                                           \
          u32* dst = xp + ee * XLD + (OT) * 8 + q * 2;                         \
          uint2 hh; hh.x = H0; hh.y = H1;                                      \
          uint2 ll; ll.x = L0; ll.y = L1;                                      \
          *(uint2*)(dst) = hh;                                                 \
          *(uint2*)(dst + PLOF) = ll;                                          \
        }                                                                      \
      }                                                                        \
    }
    EPIB(accA, w)
    EPIB(accB, (w + 4))
#undef EPIB
  }
  __syncthreads();

  // ---- stage C (+ msum -> LDS) ----
  {
    f32x4 accA[4], accB[4];
    MFMA_PASS(wbp + 32768, accA, accB)
    __syncthreads();  // all reads done before in-place overwrite
    float msA0[4] = {0.f, 0.f, 0.f, 0.f}, msA1[4] = {0.f, 0.f, 0.f, 0.f};
    float msB0[4] = {0.f, 0.f, 0.f, 0.f}, msB1[4] = {0.f, 0.f, 0.f, 0.f};
#define EPIC(ACC, OT, MS0, MS1)                                                \
    {                                                                          \
      const int o = (OT) * 16 + q * 4;                                         \
      const float4 eb4 = *(const float4*)(eb2 + o);                            \
      _Pragma("unroll")                                                        \
      for (int Et = 0; Et < 4; Et++) {                                         \
        if (LIVE(Et)) {                                                        \
          const int ee = Et * 16 + l16;                                        \
          const float mfv = mf_s[ee];                                          \
          float m0 = (mfv != 0.f) ? silu_f(ACC[Et][0] + eb4.x) : 0.f;          \
          float m1 = (mfv != 0.f) ? silu_f(ACC[Et][1] + eb4.y) : 0.f;          \
          float m2 = (mfv != 0.f) ? silu_f(ACC[Et][2] + eb4.z) : 0.f;          \
          float m3 = (mfv != 0.f) ? silu_f(ACC[Et][3] + eb4.w) : 0.f;          \
          if (Et < 2) { MS0[0] += m0; MS0[1] += m1; MS0[2] += m2; MS0[3] += m3; } \
          else        { MS1[0] += m0; MS1[1] += m1; MS1[2] += m2; MS1[3] += m3; } \
          u32 H0, L0, H1, L1;                                                  \
          packplane(m0, m1, H0, L0);                                           \
          packplane(m2, m3, H1, L1);                                           \
          u32* dst = xp + ee * XLD + (OT) * 8 + q * 2;                         \
          uint2 hh; hh.x = H0; hh.y = H1;                                      \
          uint2 ll; ll.x = L0; ll.y = L1;                                      \
          *(uint2*)(dst) = hh;                                                 \
          *(uint2*)(dst + PLOF) = ll;                                          \
        }                                                                      \
      }                                                                        \
    }
    EPIC(accA, w, msA0, msA1)
    EPIC(accB, (w + 4), msB0, msB1)
#undef EPIC
#define RED16(v) v += __shfl_xor(v, 1); v += __shfl_xor(v, 2); \
                 v += __shfl_xor(v, 4); v += __shfl_xor(v, 8);
#pragma unroll
    for (int r = 0; r < 4; r++) { RED16(msA0[r]) RED16(msA1[r]) RED16(msB0[r]) RED16(msB1[r]) }
#undef RED16
    if (l16 == 0) {
      float4 a0; a0.x = msA0[0]; a0.y = msA0[1]; a0.z = msA0[2]; a0.w = msA0[3];
      float4 a1; a1.x = msA1[0]; a1.y = msA1[1]; a1.z = msA1[2]; a1.w = msA1[3];
      float4 b0; b0.x = msB0[0]; b0.y = msB0[1]; b0.z = msB0[2]; b0.w = msB0[3];
      float4 b1; b1.x = msB1[0]; b1.y = msB1[1]; b1.z = msB1[2]; b1.w = msB1[3];
      *(float4*)(&msum_s[0][w * 16 + q * 4]) = a0;
      *(float4*)(&msum_s[1][w * 16 + q * 4]) = a1;
      *(float4*)(&msum_s[0][(w + 4) * 16 + q * 4]) = b0;
      *(float4*)(&msum_s[1][(w + 4) * 16 + q * 4]) = b1;
    }
  }
  __syncthreads();

  // ---- stage D: coord head ----
  {
    f32x4 accA[4], accB[4];
    MFMA_PASS(wbp + 65536, accA, accB)
#define EPID(ACC, OT)                                                          \
    {                                                                          \
      const int o = (OT) * 16 + q * 4;                                         \
      const float4 cb4 = *(const float4*)(cb1 + o);                            \
      const float4 cw4 = *(const float4*)(cw2 + o);                            \
      _Pragma("unroll")                                                        \
      for (int Et = 0; Et < 4; Et++) {                                         \
        if (LIVE(Et)) {                                                        \
          float p = silu_f(ACC[Et][0] + cb4.x) * cw4.x;                        \
          p = fmaf(silu_f(ACC[Et][1] + cb4.y), cw4.y, p);                      \
          p = fmaf(silu_f(ACC[Et][2] + cb4.z), cw4.z, p);                      \
          p = fmaf(silu_f(ACC[Et][3] + cb4.w), cw4.w, p);                      \
          p += __shfl_xor(p, 16);                                              \
          p += __shfl_xor(p, 32);                                              \
          if (lane < 16) ce_red[Et * 16 + lane][OT] = p;                       \
        }                                                                      \
      }                                                                        \
    }
    EPID(accA, w)
    EPID(accB, (w + 4))
#undef EPID
  }
  __syncthreads();
  if (t < 64) {
    float c = 0.f;
#pragma unroll
    for (int wv = 0; wv < 8; wv++) c += ce_red[t][wv];
    ce_s[t] = (mf_s[t] != 0.f) ? c : 0.f;
  }
  __syncthreads();
  // ---- pos update + node MLP1 (u_s aliases ce_red: consumed above) ----
  if (t < 6) {
    const int nd = t / 3, ax = t - nd * 3, ic = i0 + nd;
    float s = 0.f;
#pragma unroll
    for (int k = 0; k < 32; k++) s = fmaf(rel_s[ax][nd * 32 + k], ce_s[nd * 32 + k], s);
    const float cntf = fmaxf((float)cn_s[nd], 1.f);
    pos_out[ic * 3 + ax] = pos_in[ic * 3 + ax] + s / cntf;
  }
  {
    const int nd = t >> 7, oo = t & 127;
    float p1 = 0.f, p2 = 0.f;
#pragma unroll 4
    for (int f = 0; f < 128; f++) p1 = fmaf(hi_s[nd][f], nw1[(size_t)f * HD + oo], p1);
#pragma unroll 4
    for (int f = 0; f < 128; f++) p2 = fmaf(msum_s[nd][f], nw1[(size_t)(128 + f) * HD + oo], p2);
    const float uv = silu_f(p1 + p2 + nb1[oo]);
    __syncthreads();          // ce_red fully consumed before aliased write
    u_s[nd][oo] = uv;
  }
  __syncthreads();
  // ---- node MLP2 + residual ----
  {
    const int nd = t >> 7, oo = t & 127;
    float q1 = 0.f, q2 = 0.f;
#pragma unroll 4
    for (int f = 0; f < 64; f++) q1 = fmaf(u_s[nd][f], nw2[(size_t)f * HD + oo], q1);
#pragma unroll 4
    for (int f = 64; f < 128; f++) q2 = fmaf(u_s[nd][f], nw2[(size_t)f * HD + oo], q2);
    h_out[(size_t)(i0 + nd) * HD + oo] = hi_s[nd][oo] + q1 + q2 + nb2[oo];
  }
#undef LIVE
#undef MFMA_PASS
}

// ---------------- final heads (per node) ----------------
__global__ __launch_bounds__(256) void heads_kernel(
    const float* __restrict__ h, const float* __restrict__ pos,
    const float* __restrict__ fw1, const float* __restrict__ fb1,
    const float* __restrict__ fw2, const float* __restrict__ fb2,
    const float* __restrict__ cw1g, const float* __restrict__ cb1g,
    const float* __restrict__ cw2g, const float* __restrict__ cb2g,
    const float* __restrict__ sw, const float* __restrict__ sb,
    const float* __restrict__ iw,
    float* __restrict__ At, float* __restrict__ Bt,
    void* __restrict__ out, const int* __restrict__ flag) {
  __shared__ float hi_s[HD], v1[HD], red_s[256];
  const int i = blockIdx.x, t = threadIdx.x;
  const int fm = *flag;
  if (t < HD) hi_s[t] = h[(size_t)i * HD + t];
  __syncthreads();
  const int o = t & 127, ph = t >> 7;
  // forces MLP1
  {
    float p = 0.f;
#pragma unroll 4
    for (int f = ph * 64; f < ph * 64 + 64; f++) p = fmaf(hi_s[f], fw1[f * HD + o], p);
    red_s[t] = p;
  }
  __syncthreads();
  if (t < HD) v1[t] = tanhf(red_s[t] + red_s[t + 128] + fb1[t]);
  __syncthreads();
  if (t < 3) {
    float p = 0.f;
    for (int f = 0; f < HD; f++) p = fmaf(v1[f], fw2[f * 3 + t], p);
    stout(out, fm, OFF_F + (size_t)i * 3 + t, p + fb2[t]);
  }
  __syncthreads();
  // conformer MLP1
  {
    float p = 0.f;
#pragma unroll 4
    for (int f = ph * 64; f < ph * 64 + 64; f++) p = fmaf(hi_s[f], cw1g[f * HD + o], p);
    red_s[t] = p;
  }
  __syncthreads();
  if (t < HD) v1[t] = fmaxf(red_s[t] + red_s[t + 128] + cb1g[t], 0.f);
  __syncthreads();
  // conformer MLP2
  {
    const int oo = t & 63, pc = t >> 6;
    float p = 0.f;
#pragma unroll 4
    for (int f = pc * 32; f < pc * 32 + 32; f++) p = fmaf(v1[f], cw2g[f * 64 + oo], p);
    red_s[t] = p;
  }
  __syncthreads();
  if (t < 64)
    stout(out, fm, OFF_C + (size_t)i * 64 + t,
          red_s[t] + red_s[t + 64] + red_s[t + 128] + red_s[t + 192] + cb2g[t]);
  __syncthreads();
  // steric
  if (t < HD) red_s[t] = hi_s[t] * sw[t];
  __syncthreads();
  if (t == 0) {
    float p = 0.f;
    for (int f = 0; f < HD; f++) p += red_s[f];
    stout(out, fm, OFF_ST + (size_t)i, p + sb[0]);
  }
  __syncthreads();
  // interaction head per-node dots
  {
    const int g = t >> 5, l = t & 31;
    float p = 0.f;
    if (g < 6) {
      const int tt = g >> 1, half = g & 1;
#pragma unroll
      for (int r2 = 0; r2 < 4; r2++)
        p = fmaf(hi_s[l * 4 + r2], iw[tt * 258 + half * 128 + l * 4 + r2], p);
    }
    red_s[t] = p;
  }
  __syncthreads();
  if (t < 6) {
    float p = 0.f;
    for (int l = 0; l < 32; l++) p += red_s[t * 32 + l];
    const int tt = t >> 1;
    if ((t & 1) == 0) At[tt * NN + i] = p;
    else Bt[tt * NN + i] = p;
  }
  if (t < HD) stout(out, fm, OFF_H + (size_t)i * HD + t, hi_s[t]);
  if (t >= 128 && t < 131) stout(out, fm, OFF_POS + (size_t)i * 3 + (t - 128), pos[i * 3 + (t - 128)]);
}

// ---------------- interaction scores ----------------
__global__ void scores_kernel(const float* __restrict__ pos, const int* __restrict__ idx2,
                              const int* __restrict__ cnt2, const float* __restrict__ At,
                              const float* __restrict__ Bt, const float* __restrict__ iw,
                              const float* __restrict__ ib, void* __restrict__ out,
                              const int* __restrict__ flag) {
  int tid = blockIdx.x * 256 + threadIdx.x;
  if (tid >= 3 * NN * KI) return;
  const int fm = *flag;
  const int tt = tid / (NN * KI);
  const int r = tid % (NN * KI);
  const int n = r / KI;
  const int k = r % KI;
  float v = 0.f;
  if (k < cnt2[n]) {
    int j = idx2[n * KI + k];
    float dx = pos[n * 3 + 0] - pos[j * 3 + 0];
    float dy = pos[n * 3 + 1] - pos[j * 3 + 1];
    float dz = pos[n * 3 + 2] - pos[j * 3 + 2];
    float d2 = dx * dx + dy * dy + dz * dz;
    float dist = sqrtf(d2 + 1e-12f);
    float s = At[tt * NN + n] + Bt[tt * NN + j] + dist * iw[tt * 258 + 256] +
              (dist * 0.1f) * iw[tt * 258 + 257] + ib[tt];
    v = 1.f / (1.f + __expf(-s));
  }
  stout(out, fm, OFF_S + (size_t)tid, v);
}

extern "C" void kernel_launch(void* const* d_in, const int* in_sizes, int n_in,
                              void* d_out, int out_size, void* d_ws, size_t ws_size,
                              hipStream_t stream) {
  (void)in_sizes; (void)n_in; (void)out_size; (void)ws_size;

  float* wsf = (float*)d_ws;
  float* h_a = wsf + 0;             // 524288
  float* pos_a = wsf + 524288;      // 12288
  float* h_b = wsf + 536576;        // 524288
  float* pos_b = wsf + 1060864;     // 12288
  float* At = wsf + 1073152;        // 12288
  float* Bt = wsf + 1085440;        // 12288
  const int W0 = 1097728;

  static const int wcnt[23] = {197376, 768, 98304, 768, 98304, 768, 768,
                               196608, 768, 98304, 768, 16384, 128, 384, 3,
                               774, 3, 16384, 128, 8192, 64, 128, 1};
  int woff[23];
  {
    int o = W0;
    for (int k = 0; k < 23; k++) { woff[k] = o; o += wcnt[k]; }
  }
  const int IOFF = woff[22] + wcnt[22];
  int* ibase = (int*)d_ws;
  int* idx1 = ibase + IOFF;
  int* cnt1 = idx1 + NN * KE;
  int* idx2 = cnt1 + NN;
  int* cnt2 = idx2 + NN * KI;
  int* gstart = cnt2 + NN;
  int* flag = gstart + 33;
  // packed interleaved MFMA weight fragments, 16B-aligned
  int wboff = (int)((flag + 1) - ibase);
  wboff = (wboff + 3) & ~3;
  u16* WBP = (u16*)(ibase + wboff);

  const float* EW1 = wsf + woff[0];
  const float* EB1 = wsf + woff[1];
  const float* EB2 = wsf + woff[3];
  const float* CB1 = wsf + woff[5];
  const float* CW2 = wsf + woff[6];
  const float* NW1 = wsf + woff[7];
  const float* NB1 = wsf + woff[8];
  const float* NW2 = wsf + woff[9];
  const float* NB2 = wsf + woff[10];
  const float* FW1 = wsf + woff[11];
  const float* FB1 = wsf + woff[12];
  const float* FW2 = wsf + woff[13];
  const float* FB2 = wsf + woff[14];
  const float* IW = wsf + woff[15];
  const float* IB = wsf + woff[16];
  const float* CW1G = wsf + woff[17];
  const float* CB1G = wsf + woff[18];
  const float* CW2G = wsf + woff[19];
  const float* CB2G = wsf + woff[20];
  const float* SW = wsf + woff[21];
  const float* SB = wsf + woff[22];

  probe_dtype<<<1, 256, 0, stream>>>((const u16*)d_in[0], flag);

  CvtTable tab;
  tab.src[0] = d_in[0]; tab.dstoff[0] = 0;       tab.cnt[0] = NN * HD;
  tab.src[1] = d_in[1]; tab.dstoff[1] = 524288;  tab.cnt[1] = NN * 3;
  for (int k = 0; k < 23; k++) {
    tab.src[2 + k] = d_in[3 + k];
    tab.dstoff[2 + k] = woff[k];
    tab.cnt[2 + k] = wcnt[k];
  }
  {
    dim3 g((NN * HD + 255) / 256, 25, 1);
    convert_all<<<g, 256, 0, stream>>>(tab, wsf, flag);
  }
  pack_weights<<<(18 * 32768 + 255) / 256, 256, 0, stream>>>(
      wsf, woff[0], woff[2], woff[4], WBP);

  const int* batch = (const int*)d_in[2];
  graph_bounds<<<NN / 256, 256, 0, stream>>>(batch, gstart);

  const float cut2s[3] = {9.f, 36.f, 100.f};
  float *hin = h_a, *pin = pos_a, *hout = h_b, *pout = pos_b;
  for (int l = 0; l < 6; l++) {
    if ((l & 1) == 0)
      neigh_kernel<<<NN / 4, 256, 0, stream>>>(pin, batch, gstart, idx1, cnt1, KE, cut2s[l >> 1]);
    egnn_layer<<<NN / 2, 256, 0, stream>>>(
        hin, pin, hout, pout, idx1, cnt1,
        EW1 + (size_t)l * 257 * HD, EB1 + (size_t)l * HD,
        EB2 + (size_t)l * HD, CB1 + (size_t)l * HD, CW2 + (size_t)l * HD,
        NW1 + (size_t)l * 256 * HD, NB1 + (size_t)l * HD,
        NW2 + (size_t)l * HD * HD, NB2 + (size_t)l * HD,
        WBP + (size_t)l * 3 * 32768);
    float* th = hin; hin = hout; hout = th;
    float* tp = pin; pin = pout; pout = tp;
  }
  neigh_kernel<<<NN / 4, 256, 0, stream>>>(pin, batch, gstart, idx2, cnt2, KI, 100.f);
  heads_kernel<<<NN, 256, 0, stream>>>(hin, pin, FW1, FB1, FW2, FB2, CW1G, CB1G, CW2G, CB2G,
                                       SW, SB, IW, At, Bt, d_out, flag);
  scores_kernel<<<(3 * NN * KI + 255) / 256, 256, 0, stream>>>(
      pin, idx2, cnt2, At, Bt, IW, IB, d_out, flag);
}

// Round 11
// 916.249 us; speedup vs baseline: 1.2195x; 1.1679x over previous
//
#include <hip/hip_runtime.h>
#include <hip/hip_bf16.h>

#define NN 4096
#define HD 128
#define KE 32
#define KI 20
#define XLD 132   // X LDS row stride in u32 (16B-aligned rows)
#define PLOF 68   // lo-plane column offset within a row (16B-aligned)

// output element offsets
#define OFF_H   0
#define OFF_POS 524288
#define OFF_F   536576
#define OFF_S   548864
#define OFF_C   794624
#define OFF_ST  1056768

typedef unsigned short u16;
typedef unsigned int u32;
typedef unsigned long long u64;
typedef __attribute__((ext_vector_type(8))) short bf16x8;   // 8 bf16 (4 VGPR)
typedef __attribute__((ext_vector_type(4))) float f32x4;

__device__ __forceinline__ float b2f(u16 u) {
  union { u32 i; float f; } c; c.i = ((u32)u) << 16; return c.f;
}
__device__ __forceinline__ float silu_f(float x) { return x / (1.f + __expf(-x)); }
__device__ __forceinline__ void stout(void* out, int fp32m, size_t i, float v) {
  if (fp32m) ((float*)out)[i] = v;
  else ((__hip_bfloat16*)out)[i] = __float2bfloat16(v);
}
// RNE float->bf16 bits (reference path, used in pack_weights)
__device__ __forceinline__ u32 f2b(float f) {
  u32 u = __float_as_uint(f);
  return (u + 0x7fffu + ((u >> 16) & 1u)) >> 16;
}
// hi/lo split of two adjacent values -> plane words (H=[b:a] hi, L=[b:a] lo)
__device__ __forceinline__ void packplane(float a, float b, u32& H, u32& L) {
  asm("v_cvt_pk_bf16_f32 %0, %1, %2" : "=v"(H) : "v"(a), "v"(b));
  float hfa = __uint_as_float(H << 16);
  float hfb = __uint_as_float(H & 0xffff0000u);
  asm("v_cvt_pk_bf16_f32 %0, %1, %2" : "=v"(L) : "v"(a - hfa), "v"(b - hfb));
}

// ---------------- dtype probe ----------------
__global__ void probe_dtype(const u16* __restrict__ h, int* __restrict__ flag) {
  if (threadIdx.x == 0) atomicExch(flag, 0);
  __syncthreads();
  int bad = 0;
  for (int i = threadIdx.x; i < 8192; i += 256) {
    float v = b2f(h[i]);
    if (!(v > -1000.f && v < 1000.f)) bad = 1;
  }
  if (bad) atomicOr(flag, 1);
}

// ---------------- convert all float tensors -> fp32 workspace ----------------
struct CvtTable {
  const void* src[25];
  int dstoff[25];
  int cnt[25];
};

__global__ void convert_all(CvtTable tab, float* __restrict__ wsf, const int* __restrict__ flag) {
  const int seg = blockIdx.y;
  const int i = blockIdx.x * 256 + threadIdx.x;
  if (i >= tab.cnt[seg]) return;
  float v;
  if (*flag) v = ((const float*)tab.src[seg])[i];
  else       v = b2f(((const u16*)tab.src[seg])[i]);
  wsf[tab.dstoff[seg] + i] = v;
}

// ------- pack stage weights: interleaved hi/lo MFMA fragments -------
// Layout: [mat 18][kt 4][ot 8][lane 64][16 u16] where [0..8)=hi j, [8..16)=lo j.
__global__ void pack_weights(const float* __restrict__ wsf, int offEW1, int offEW2, int offCW1,
                             u16* __restrict__ WBP) {
  int tid = blockIdx.x * 256 + threadIdx.x;
  if (tid >= 18 * 32768) return;
  int m = tid >> 15;
  int rix = tid & 32767;
  int layer = m / 3, s = m % 3;
  const float* src;
  if (s == 0)      src = wsf + offEW1 + (size_t)layer * 257 * HD + 128 * HD;
  else if (s == 1) src = wsf + offEW2 + (size_t)layer * HD * HD;
  else             src = wsf + offCW1 + (size_t)layer * HD * HD;
  int jh = rix & 15, lane = (rix >> 4) & 63, ot = (rix >> 10) & 7, kt = rix >> 13;
  int j = jh & 7;
  int f = kt * 32 + (lane >> 4) * 8 + j;
  int o = ot * 16 + (lane & 15);
  float v = src[f * HD + o];
  u32 hb = f2b(v);
  float hf = __uint_as_float(hb << 16);
  u32 lb = f2b(v - hf);
  WBP[tid] = (jh < 8) ? (u16)hb : (u16)lb;
}

// ---------------- graph boundaries from sorted batch ----------------
__global__ void graph_bounds(const int* __restrict__ batch, int* __restrict__ gstart) {
  int n = blockIdx.x * 256 + threadIdx.x;
  if (n >= NN) return;
  int v = batch[n];
  int pv = (n == 0) ? -1 : batch[n - 1];
  for (int b = pv + 1; b <= v; b++) gstart[b] = n;
  if (n == NN - 1) for (int b = v + 1; b <= 32; b++) gstart[b] = NN;
}

// ---------------- exact k-NN within cutoff (one wave per node) ----------------
__global__ __launch_bounds__(256) void neigh_kernel(
    const float* __restrict__ pos, const int* __restrict__ batch,
    const int* __restrict__ gstart, int* __restrict__ idx, int* __restrict__ cnt,
    int Ksel, float cut2) {
  const int lane = threadIdx.x & 63;
  const int i = blockIdx.x * 4 + (threadIdx.x >> 6);
  const int b = batch[i];
  const int gs = gstart[b];
  const int ge = gstart[b + 1];
  const int span = ge - gs;
  const float px = pos[i * 3 + 0], py = pos[i * 3 + 1], pz = pos[i * 3 + 2];
  u64 key[16];
#pragma unroll
  for (int tq = 0; tq < 16; tq++) {
    u64 k64 = ~0ull;
    if (tq * 64 < span) {
      int j = gs + tq * 64 + lane;
      if (j < ge && j != i) {
        float dx = px - pos[j * 3 + 0];
        float dy = py - pos[j * 3 + 1];
        float dz = pz - pos[j * 3 + 2];
        float d2 = dx * dx + dy * dy + dz * dz;
        if (d2 <= cut2) k64 = (((u64)__float_as_uint(d2)) << 32) | (u32)j;
      }
    }
    key[tq] = k64;
  }
  u64 thresh = 0;
  int myidx = i;
  int mycnt = 0;
  for (int s = 0; s < Ksel; s++) {
    u64 m = ~0ull;
#pragma unroll
    for (int tq = 0; tq < 16; tq++) {
      if (tq * 64 < span) {
        u64 kk = key[tq];
        if (kk >= thresh && kk < m) m = kk;
      }
    }
    for (int off = 32; off > 0; off >>= 1) {
      u64 o = __shfl_down(m, (unsigned)off, 64);
      if (o < m) m = o;
    }
    m = __shfl(m, 0, 64);
    if (m != ~0ull) {
      if (lane == s) myidx = (int)(m & 0xffffffffu);
      mycnt++;
      thresh = m + 1;
    } else break;
  }
  if (lane < Ksel) idx[i * Ksel + lane] = myidx;
  if (lane == 0) cnt[i] = mycnt;
}

// ---------------- hpart: hpart[n][o] = h[n] . ew1[0:128,o] + eb1[o] ----------
// Used once for layer 0; layers 1..5 get hpart from node_hpart_kernel.
__global__ __launch_bounds__(256) void hpart_kernel(
    const float* __restrict__ h, const float* __restrict__ ew1,
    const float* __restrict__ eb1, float* __restrict__ hpart) {
  __shared__ float ht[8][HD];
  const int t = threadIdx.x;
  const int n0 = blockIdx.x * 8;
  {
    const int nd = t >> 5, f = (t & 31) * 4;
    *(float4*)(&ht[nd][f]) = *(const float4*)(h + (size_t)(n0 + nd) * HD + f);
  }
  __syncthreads();
  const int nd = t >> 5, ob = (t & 31) * 4;
  float a0 = 0.f, a1 = 0.f, a2 = 0.f, a3 = 0.f;
  float b0 = 0.f, b1 = 0.f, b2 = 0.f, b3 = 0.f;
#pragma unroll 4
  for (int f = 0; f < 64; f++) {
    const float x = ht[nd][f];
    const float4 w4 = *(const float4*)(ew1 + (size_t)f * HD + ob);
    a0 = fmaf(x, w4.x, a0); a1 = fmaf(x, w4.y, a1);
    a2 = fmaf(x, w4.z, a2); a3 = fmaf(x, w4.w, a3);
  }
#pragma unroll 4
  for (int f = 64; f < 128; f++) {
    const float x = ht[nd][f];
    const float4 w4 = *(const float4*)(ew1 + (size_t)f * HD + ob);
    b0 = fmaf(x, w4.x, b0); b1 = fmaf(x, w4.y, b1);
    b2 = fmaf(x, w4.z, b2); b3 = fmaf(x, w4.w, b3);
  }
  const float4 e4 = *(const float4*)(eb1 + ob);
  float4 o4;
  o4.x = a0 + b0 + e4.x; o4.y = a1 + b1 + e4.y;
  o4.z = a2 + b2 + e4.z; o4.w = a3 + b3 + e4.w;
  *(float4*)(hpart + (size_t)(n0 + nd) * HD + ob) = o4;
}

// ------- fused node MLP (layer l) + hpart (layer l+1), 8 nodes/block -------
// Phase 1-2: node MLP verbatim from round-7 node_kernel (bit-identical).
// h_out stashed in mt (dead after MLP1) -> phase 3: hpart chain verbatim from
// hpart_kernel reading mt. Cuts 1 dependent launch per layer (~28 us each).
__global__ __launch_bounds__(256) void node_hpart_kernel(
    const float* __restrict__ h_in, const float* __restrict__ msum,
    const float* __restrict__ nw1, const float* __restrict__ nb1,
    const float* __restrict__ nw2, const float* __restrict__ nb2,
    const float* __restrict__ ew1n, const float* __restrict__ eb1n,
    float* __restrict__ h_out, float* __restrict__ hpart) {
  __shared__ float ht[8][HD], mt[8][HD], ut[8][HD];
  const int t = threadIdx.x;
  const int n0 = blockIdx.x * 8;
  {
    const int nd = t >> 5, f = (t & 31) * 4;
    *(float4*)(&ht[nd][f]) = *(const float4*)(h_in + (size_t)(n0 + nd) * HD + f);
    *(float4*)(&mt[nd][f]) = *(const float4*)(msum + (size_t)(n0 + nd) * HD + f);
  }
  __syncthreads();
  const int nd = t >> 5, ob = (t & 31) * 4;
  float p1[4] = {0.f, 0.f, 0.f, 0.f}, p2[4] = {0.f, 0.f, 0.f, 0.f};
#pragma unroll 4
  for (int f = 0; f < 128; f++) {
    const float x = ht[nd][f];
    const float4 w4 = *(const float4*)(nw1 + (size_t)f * HD + ob);
    p1[0] = fmaf(x, w4.x, p1[0]); p1[1] = fmaf(x, w4.y, p1[1]);
    p1[2] = fmaf(x, w4.z, p1[2]); p1[3] = fmaf(x, w4.w, p1[3]);
  }
#pragma unroll 4
  for (int f = 0; f < 128; f++) {
    const float x = mt[nd][f];
    const float4 w4 = *(const float4*)(nw1 + (size_t)(128 + f) * HD + ob);
    p2[0] = fmaf(x, w4.x, p2[0]); p2[1] = fmaf(x, w4.y, p2[1]);
    p2[2] = fmaf(x, w4.z, p2[2]); p2[3] = fmaf(x, w4.w, p2[3]);
  }
  {
    const float4 b4 = *(const float4*)(nb1 + ob);
    ut[nd][ob + 0] = silu_f(p1[0] + p2[0] + b4.x);
    ut[nd][ob + 1] = silu_f(p1[1] + p2[1] + b4.y);
    ut[nd][ob + 2] = silu_f(p1[2] + p2[2] + b4.z);
    ut[nd][ob + 3] = silu_f(p1[3] + p2[3] + b4.w);
  }
  __syncthreads();
  float q1[4] = {0.f, 0.f, 0.f, 0.f}, q2[4] = {0.f, 0.f, 0.f, 0.f};
#pragma unroll 4
  for (int f = 0; f < 64; f++) {
    const float x = ut[nd][f];
    const float4 w4 = *(const float4*)(nw2 + (size_t)f * HD + ob);
    q1[0] = fmaf(x, w4.x, q1[0]); q1[1] = fmaf(x, w4.y, q1[1]);
    q1[2] = fmaf(x, w4.z, q1[2]); q1[3] = fmaf(x, w4.w, q1[3]);
  }
#pragma unroll 4
  for (int f = 64; f < 128; f++) {
    const float x = ut[nd][f];
    const float4 w4 = *(const float4*)(nw2 + (size_t)f * HD + ob);
    q2[0] = fmaf(x, w4.x, q2[0]); q2[1] = fmaf(x, w4.y, q2[1]);
    q2[2] = fmaf(x, w4.z, q2[2]); q2[3] = fmaf(x, w4.w, q2[3]);
  }
  {
    const float4 b4 = *(const float4*)(nb2 + ob);
    float4 o4;
    o4.x = ht[nd][ob + 0] + q1[0] + q2[0] + b4.x;
    o4.y = ht[nd][ob + 1] + q1[1] + q2[1] + b4.y;
    o4.z = ht[nd][ob + 2] + q1[2] + q2[2] + b4.z;
    o4.w = ht[nd][ob + 3] + q1[3] + q2[3] + b4.w;
    *(float4*)(h_out + (size_t)(n0 + nd) * HD + ob) = o4;
    *(float4*)(&mt[nd][ob]) = o4;   // mt dead after MLP1; no reader until barrier
  }
  __syncthreads();
  // ---- hpart for next layer (verbatim hpart_kernel chain, x = h_out in mt) ----
  {
    float a0 = 0.f, a1 = 0.f, a2 = 0.f, a3 = 0.f;
    float b0 = 0.f, b1 = 0.f, b2 = 0.f, b3 = 0.f;
#pragma unroll 4
    for (int f = 0; f < 64; f++) {
      const float x = mt[nd][f];
      const float4 w4 = *(const float4*)(ew1n + (size_t)f * HD + ob);
      a0 = fmaf(x, w4.x, a0); a1 = fmaf(x, w4.y, a1);
      a2 = fmaf(x, w4.z, a2); a3 = fmaf(x, w4.w, a3);
    }
#pragma unroll 4
    for (int f = 64; f < 128; f++) {
      const float x = mt[nd][f];
      const float4 w4 = *(const float4*)(ew1n + (size_t)f * HD + ob);
      b0 = fmaf(x, w4.x, b0); b1 = fmaf(x, w4.y, b1);
      b2 = fmaf(x, w4.z, b2); b3 = fmaf(x, w4.w, b3);
    }
    const float4 e4 = *(const float4*)(eb1n + ob);
    float4 o4;
    o4.x = a0 + b0 + e4.x; o4.y = a1 + b1 + e4.y;
    o4.z = a2 + b2 + e4.z; o4.w = a3 + b3 + e4.w;
    *(float4*)(hpart + (size_t)(n0 + nd) * HD + ob) = o4;
  }
}

// ---------------- edge kernel: 256 thr / 4 waves / 2 nodes ----------------
// Byte-identical to the round-7 edge kernel (68.7 us dense, 64 VGPR, no spill).
__global__ __launch_bounds__(256, 4) void egnn_edge(
    const float* __restrict__ h_in, const float* __restrict__ pos_in,
    float* __restrict__ pos_out,
    const int* __restrict__ idx, const int* __restrict__ cnt,
    const float* __restrict__ hpart, const float* __restrict__ ew1d2,
    const float* __restrict__ eb2, const float* __restrict__ cb1,
    const float* __restrict__ cw2,
    float* __restrict__ msum, const u16* __restrict__ wbp) {
  __shared__ __align__(16) u32 xp[64 * XLD];
  __shared__ float hp_s[2][HD];
  __shared__ float rel_s[3][64], d2_s[64], mf_s[64], ce_s[64];
  __shared__ float ce_red[64][9];
  __shared__ int idx_s[64], cn_s[2];

  const int t = threadIdx.x;
  const int i0 = blockIdx.x * 2;
  const int lane = t & 63;
  const int w = __builtin_amdgcn_readfirstlane(t >> 6);  // 0..3
  const int l16 = lane & 15, q = lane >> 4;

  if (t < 64) idx_s[t] = idx[(size_t)(i0 + (t >> 5)) * KE + (t & 31)];
  else if (t < 66) cn_s[t - 64] = cnt[i0 + (t - 64)];
  __syncthreads();
  const int nt0 = __builtin_amdgcn_readfirstlane((cn_s[0] + 15) >> 4);
  const int nt1 = __builtin_amdgcn_readfirstlane((cn_s[1] + 15) >> 4);
#define LIVE(Et) (((Et) < 2) ? ((Et) < nt0) : ((Et) - 2 < nt1))

  if (t < 64) {
    const int nd = t >> 5, ic = i0 + nd;
    const int j = idx_s[t];
    const float rx = pos_in[ic * 3 + 0] - pos_in[j * 3 + 0];
    const float ry = pos_in[ic * 3 + 1] - pos_in[j * 3 + 1];
    const float rz = pos_in[ic * 3 + 2] - pos_in[j * 3 + 2];
    rel_s[0][t] = rx; rel_s[1][t] = ry; rel_s[2][t] = rz;
    d2_s[t] = rx * rx + ry * ry + rz * rz;
    mf_s[t] = ((t & 31) < cn_s[nd]) ? 1.0f : 0.0f;
  }
  {
    const int nd = t >> 7, f = t & 127;
    hp_s[nd][f] = hpart[(size_t)(i0 + nd) * HD + f];
  }
  // gather hj -> hi/lo planes; thread covers 32 f of one e row
  {
    const int e = t & 63;
    const int myEt = e >> 4;
    const bool glive = (myEt < 2) ? (myEt < nt0) : (myEt - 2 < nt1);
    if (glive) {
      const int j = idx_s[e];
      const int f0 = (t >> 6) * 32;
      const float4* src = (const float4*)(h_in + (size_t)j * HD + f0);
#pragma unroll
      for (int half = 0; half < 2; half++) {
        float4 v0 = src[half * 4 + 0], v1 = src[half * 4 + 1];
        float4 v2 = src[half * 4 + 2], v3 = src[half * 4 + 3];
        u32 H0, L0, H1, L1, H2, L2, H3, L3, H4, L4, H5, L5, H6, L6, H7, L7;
        packplane(v0.x, v0.y, H0, L0); packplane(v0.z, v0.w, H1, L1);
        packplane(v1.x, v1.y, H2, L2); packplane(v1.z, v1.w, H3, L3);
        packplane(v2.x, v2.y, H4, L4); packplane(v2.z, v2.w, H5, L5);
        packplane(v3.x, v3.y, H6, L6); packplane(v3.z, v3.w, H7, L7);
        u32* dh = xp + e * XLD + ((f0 + half * 16) >> 1);
        uint4 a; a.x = H0; a.y = H1; a.z = H2; a.w = H3;
        uint4 b; b.x = H4; b.y = H5; b.z = H6; b.w = H7;
        uint4 c; c.x = L0; c.y = L1; c.z = L2; c.w = L3;
        uint4 d; d.x = L4; d.y = L5; d.z = L6; d.w = L7;
        *(uint4*)(dh) = a;        *(uint4*)(dh + 4) = b;
        *(uint4*)(dh + PLOF) = c; *(uint4*)(dh + PLOF + 4) = d;
      }
    }
  }
  __syncthreads();

  // macro: one full 3-term dual-tile MFMA pass over live e-tiles
#define MFMA_PASS(WPBASE, accA, accB)                                          \
  {                                                                            \
    f32x4 z = {0.f, 0.f, 0.f, 0.f};                                            \
    accA[0] = z; accA[1] = z; accA[2] = z; accA[3] = z;                        \
    accB[0] = z; accB[1] = z; accB[2] = z; accB[3] = z;                        \
    bf16x8 whA[4], wlA[4], whB[4], wlB[4];                                     \
    _Pragma("unroll")                                                          \
    for (int kt = 0; kt < 4; kt++) {                                           \
      const u16* wa = (WPBASE) + (size_t)((kt * 8 + w) * 64 + lane) * 16;      \
      whA[kt] = *(const bf16x8*)(wa); wlA[kt] = *(const bf16x8*)(wa + 8);      \
      const u16* wb = (WPBASE) + (size_t)((kt * 8 + w + 4) * 64 + lane) * 16;  \
      whB[kt] = *(const bf16x8*)(wb); wlB[kt] = *(const bf16x8*)(wb + 8);      \
    }                                                                          \
    _Pragma("unroll")                                                          \
    for (int Et = 0; Et < 4; Et++) {                                           \
      if (LIVE(Et)) {                                                          \
        _Pragma("unroll")                                                      \
        for (int kt = 0; kt < 4; kt++) {                                       \
          const u32* xr = xp + (Et * 16 + l16) * XLD + kt * 16 + q * 4;        \
          bf16x8 xh = *(const bf16x8*)(xr);                                    \
          bf16x8 xl = *(const bf16x8*)(xr + PLOF);                             \
          accA[Et] = __builtin_amdgcn_mfma_f32_16x16x32_bf16(whA[kt], xl, accA[Et], 0, 0, 0); \
          accA[Et] = __builtin_amdgcn_mfma_f32_16x16x32_bf16(wlA[kt], xh, accA[Et], 0, 0, 0); \
          accA[Et] = __builtin_amdgcn_mfma_f32_16x16x32_bf16(whA[kt], xh, accA[Et], 0, 0, 0); \
          accB[Et] = __builtin_amdgcn_mfma_f32_16x16x32_bf16(whB[kt], xl, accB[Et], 0, 0, 0); \
          accB[Et] = __builtin_amdgcn_mfma_f32_16x16x32_bf16(wlB[kt], xh, accB[Et], 0, 0, 0); \
          accB[Et] = __builtin_amdgcn_mfma_f32_16x16x32_bf16(whB[kt], xh, accB[Et], 0, 0, 0); \
        }                                                                      \
      }                                                                        \
    }                                                                          \
  }

  // ---- stage B ----
  {
    f32x4 accA[4], accB[4];
    MFMA_PASS(wbp, accA, accB)
    __syncthreads();  // all plane reads done before in-place overwrite
#define EPIB(ACC, OT)                                                          \
    {                                                                          \
      const int o = (OT) * 16 + q * 4;                                         \
      const float4 w24 = *(const float4*)(ew1d2 + o);                          \
      _Pragma("unroll")                                                        \
      for (int Et = 0; Et < 4; Et++) {                                         \
        if (LIVE(Et)) {                                                        \
          const int ee = Et * 16 + l16;                                        \
          const float d2e = d2_s[ee];                                          \
          const float4 hp4 = *(const float4*)(&hp_s[Et >> 1][o]);              \
          float s0 = silu_f(ACC[Et][0] + hp4.x + d2e * w24.x);                 \
          float s1 = silu_f(ACC[Et][1] + hp4.y + d2e * w24.y);                 \
          float s2 = silu_f(ACC[Et][2] + hp4.z + d2e * w24.z);                 \
          float s3 = silu_f(ACC[Et][3] + hp4.w + d2e * w24.w);                 \
          u32 H0, L0, H1, L1;                                                  \
          packplane(s0, s1, H0, L0);                                           \
          packplane(s2, s3, H1, L1);                                           \
          u32* dst = xp + ee * XLD + (OT) * 8 + q * 2;                         \
          uint2 hh; hh.x = H0; hh.y = H1;                                      \
          uint2 ll; ll.x = L0; ll.y = L1;                                      \
          *(uint2*)(dst) = hh;                                                 \
          *(uint2*)(dst + PLOF) = ll;                                          \
        }                                                                      \
      }                                                                        \
    }
    EPIB(accA, w)
    EPIB(accB, (w + 4))
#undef EPIB
  }
  __syncthreads();

  // ---- stage C (+ msum) ----
  {
    f32x4 accA[4], accB[4];
    MFMA_PASS(wbp + 32768, accA, accB)
    __syncthreads();  // all reads done before in-place overwrite
    float msA0[4] = {0.f, 0.f, 0.f, 0.f}, msA1[4] = {0.f, 0.f, 0.f, 0.f};
    float msB0[4] = {0.f, 0.f, 0.f, 0.f}, msB1[4] = {0.f, 0.f, 0.f, 0.f};
#define EPIC(ACC, OT, MS0, MS1)                                                \
    {                                                                          \
      const int o = (OT) * 16 + q * 4;                                         \
      const float4 eb4 = *(const float4*)(eb2 + o);                            \
      _Pragma("unroll")                                                        \
      for (int Et = 0; Et < 4; Et++) {                                         \
        if (LIVE(Et)) {                                                        \
          const int ee = Et * 16 + l16;                                        \
          const float mfv = mf_s[ee];                                          \
          float m0 = (mfv != 0.f) ? silu_f(ACC[Et][0] + eb4.x) : 0.f;          \
          float m1 = (mfv != 0.f) ? silu_f(ACC[Et][1] + eb4.y) : 0.f;          \
          float m2 = (mfv != 0.f) ? silu_f(ACC[Et][2] + eb4.z) : 0.f;          \
          float m3 = (mfv != 0.f) ? silu_f(ACC[Et][3] + eb4.w) : 0.f;          \
          if (Et < 2) { MS0[0] += m0; MS0[1] += m1; MS0[2] += m2; MS0[3] += m3; } \
          else        { MS1[0] += m0; MS1[1] += m1; MS1[2] += m2; MS1[3] += m3; } \
          u32 H0, L0, H1, L1;                                                  \
          packplane(m0, m1, H0, L0);                                           \
          packplane(m2, m3, H1, L1);                                           \
          u32* dst = xp + ee * XLD + (OT) * 8 + q * 2;                         \
          uint2 hh; hh.x = H0; hh.y = H1;                                      \
          uint2 ll; ll.x = L0; ll.y = L1;                                      \
          *(uint2*)(dst) = hh;                                                 \
          *(uint2*)(dst + PLOF) = ll;                                          \
        }                                                                      \
      }                                                                        \
    }
    EPIC(accA, w, msA0, msA1)
    EPIC(accB, (w + 4), msB0, msB1)
#undef EPIC
#define RED16(v) v += __shfl_xor(v, 1); v += __shfl_xor(v, 2); \
                 v += __shfl_xor(v, 4); v += __shfl_xor(v, 8);
#pragma unroll
    for (int r = 0; r < 4; r++) { RED16(msA0[r]) RED16(msA1[r]) RED16(msB0[r]) RED16(msB1[r]) }
#undef RED16
    if (l16 == 0) {
      float4 a0; a0.x = msA0[0]; a0.y = msA0[1]; a0.z = msA0[2]; a0.w = msA0[3];
      float4 a1; a1.x = msA1[0]; a1.y = msA1[1]; a1.z = msA1[2]; a1.w = msA1[3];
      float4 b0; b0.x = msB0[0]; b0.y = msB0[1]; b0.z = msB0[2]; b0.w = msB0[3];
      float4 b1; b1.x = msB1[0]; b1.y = msB1[1]; b1.z = msB1[2]; b1.w = msB1[3];
      *(float4*)(msum + (size_t)i0 * HD + w * 16 + q * 4) = a0;
      *(float4*)(msum + (size_t)(i0 + 1) * HD + w * 16 + q * 4) = a1;
      *(float4*)(msum + (size_t)i0 * HD + (w + 4) * 16 + q * 4) = b0;
      *(float4*)(msum + (size_t)(i0 + 1) * HD + (w + 4) * 16 + q * 4) = b1;
    }
  }
  __syncthreads();

  // ---- stage D: coord head ----
  {
    f32x4 accA[4], accB[4];
    MFMA_PASS(wbp + 65536, accA, accB)
#define EPID(ACC, OT)                                                          \
    {                                                                          \
      const int o = (OT) * 16 + q * 4;                                         \
      const float4 cb4 = *(const float4*)(cb1 + o);                            \
      const float4 cw4 = *(const float4*)(cw2 + o);                            \
      _Pragma("unroll")                                                        \
      for (int Et = 0; Et < 4; Et++) {                                         \
        if (LIVE(Et)) {                                                        \
          float p = silu_f(ACC[Et][0] + cb4.x) * cw4.x;                        \
          p = fmaf(silu_f(ACC[Et][1] + cb4.y), cw4.y, p);                      \
          p = fmaf(silu_f(ACC[Et][2] + cb4.z), cw4.z, p);                      \
          p = fmaf(silu_f(ACC[Et][3] + cb4.w), cw4.w, p);                      \
          p += __shfl_xor(p, 16);                                              \
          p += __shfl_xor(p, 32);                                              \
          if (lane < 16) ce_red[Et * 16 + lane][OT] = p;                       \
        }                                                                      \
      }                                                                        \
    }
    EPID(accA, w)
    EPID(accB, (w + 4))
#undef EPID
  }
  __syncthreads();
  if (t < 64) {
    float c = 0.f;
#pragma unroll
    for (int wv = 0; wv < 8; wv++) c += ce_red[t][wv];
    ce_s[t] = (mf_s[t] != 0.f) ? c : 0.f;
  }
  __syncthreads();
  if (t < 6) {
    const int nd = t / 3, ax = t - nd * 3, ic = i0 + nd;
    float s = 0.f;
#pragma unroll
    for (int k = 0; k < 32; k++) s = fmaf(rel_s[ax][nd * 32 + k], ce_s[nd * 32 + k], s);
    const float cntf = fmaxf((float)cn_s[nd], 1.f);
    pos_out[ic * 3 + ax] = pos_in[ic * 3 + ax] + s / cntf;
  }
#undef LIVE
#undef MFMA_PASS
}

// ---------------- final heads (per node) ----------------
__global__ __launch_bounds__(256) void heads_kernel(
    const float* __restrict__ h, const float* __restrict__ pos,
    const float* __restrict__ fw1, const float* __restrict__ fb1,
    const float* __restrict__ fw2, const float* __restrict__ fb2,
    const float* __restrict__ cw1g, const float* __restrict__ cb1g,
    const float* __restrict__ cw2g, const float* __restrict__ cb2g,
    const float* __restrict__ sw, const float* __restrict__ sb,
    const float* __restrict__ iw,
    float* __restrict__ At, float* __restrict__ Bt,
    void* __restrict__ out, const int* __restrict__ flag) {
  __shared__ float hi_s[HD], v1[HD], red_s[256];
  const int i = blockIdx.x, t = threadIdx.x;
  const int fm = *flag;
  if (t < HD) hi_s[t] = h[(size_t)i * HD + t];
  __syncthreads();
  const int o = t & 127, ph = t >> 7;
  // forces MLP1
  {
    float p = 0.f;
#pragma unroll 4
    for (int f = ph * 64; f < ph * 64 + 64; f++) p = fmaf(hi_s[f], fw1[f * HD + o], p);
    red_s[t] = p;
  }
  __syncthreads();
  if (t < HD) v1[t] = tanhf(red_s[t] + red_s[t + 128] + fb1[t]);
  __syncthreads();
  if (t < 3) {
    float p = 0.f;
    for (int f = 0; f < HD; f++) p = fmaf(v1[f], fw2[f * 3 + t], p);
    stout(out, fm, OFF_F + (size_t)i * 3 + t, p + fb2[t]);
  }
  __syncthreads();
  // conformer MLP1
  {
    float p = 0.f;
#pragma unroll 4
    for (int f = ph * 64; f < ph * 64 + 64; f++) p = fmaf(hi_s[f], cw1g[f * HD + o], p);
    red_s[t] = p;
  }
  __syncthreads();
  if (t < HD) v1[t] = fmaxf(red_s[t] + red_s[t + 128] + cb1g[t], 0.f);
  __syncthreads();
  // conformer MLP2
  {
    const int oo = t & 63, pc = t >> 6;
    float p = 0.f;
#pragma unroll 4
    for (int f = pc * 32; f < pc * 32 + 32; f++) p = fmaf(v1[f], cw2g[f * 64 + oo], p);
    red_s[t] = p;
  }
  __syncthreads();
  if (t < 64)
    stout(out, fm, OFF_C + (size_t)i * 64 + t,
          red_s[t] + red_s[t + 64] + red_s[t + 128] + red_s[t + 192] + cb2g[t]);
  __syncthreads();
  // steric
  if (t < HD) red_s[t] = hi_s[t] * sw[t];
  __syncthreads();
  if (t == 0) {
    float p = 0.f;
    for (int f = 0; f < HD; f++) p += red_s[f];
    stout(out, fm, OFF_ST + (size_t)i, p + sb[0]);
  }
  __syncthreads();
  // interaction head per-node dots
  {
    const int g = t >> 5, l = t & 31;
    float p = 0.f;
    if (g < 6) {
      const int tt = g >> 1, half = g & 1;
#pragma unroll
      for (int r2 = 0; r2 < 4; r2++)
        p = fmaf(hi_s[l * 4 + r2], iw[tt * 258 + half * 128 + l * 4 + r2], p);
    }
    red_s[t] = p;
  }
  __syncthreads();
  if (t < 6) {
    float p = 0.f;
    for (int l = 0; l < 32; l++) p += red_s[t * 32 + l];
    const int tt = t >> 1;
    if ((t & 1) == 0) At[tt * NN + i] = p;
    else Bt[tt * NN + i] = p;
  }
  if (t < HD) stout(out, fm, OFF_H + (size_t)i * HD + t, hi_s[t]);
  if (t >= 128 && t < 131) stout(out, fm, OFF_POS + (size_t)i * 3 + (t - 128), pos[i * 3 + (t - 128)]);
}

// ---------------- interaction scores ----------------
__global__ void scores_kernel(const float* __restrict__ pos, const int* __restrict__ idx2,
                              const int* __restrict__ cnt2, const float* __restrict__ At,
                              const float* __restrict__ Bt, const float* __restrict__ iw,
                              const float* __restrict__ ib, void* __restrict__ out,
                              const int* __restrict__ flag) {
  int tid = blockIdx.x * 256 + threadIdx.x;
  if (tid >= 3 * NN * KI) return;
  const int fm = *flag;
  const int tt = tid / (NN * KI);
  const int r = tid % (NN * KI);
  const int n = r / KI;
  const int k = r % KI;
  float v = 0.f;
  if (k < cnt2[n]) {
    int j = idx2[n * KI + k];
    float dx = pos[n * 3 + 0] - pos[j * 3 + 0];
    float dy = pos[n * 3 + 1] - pos[j * 3 + 1];
    float dz = pos[n * 3 + 2] - pos[j * 3 + 2];
    float d2 = dx * dx + dy * dy + dz * dz;
    float dist = sqrtf(d2 + 1e-12f);
    float s = At[tt * NN + n] + Bt[tt * NN + j] + dist * iw[tt * 258 + 256] +
              (dist * 0.1f) * iw[tt * 258 + 257] + ib[tt];
    v = 1.f / (1.f + __expf(-s));
  }
  stout(out, fm, OFF_S + (size_t)tid, v);
}

extern "C" void kernel_launch(void* const* d_in, const int* in_sizes, int n_in,
                              void* d_out, int out_size, void* d_ws, size_t ws_size,
                              hipStream_t stream) {
  (void)in_sizes; (void)n_in; (void)out_size; (void)ws_size;

  float* wsf = (float*)d_ws;
  float* h_a = wsf + 0;             // 524288
  float* pos_a = wsf + 524288;      // 12288
  float* h_b = wsf + 536576;        // 524288
  float* pos_b = wsf + 1060864;     // 12288
  float* At = wsf + 1073152;        // 12288
  float* Bt = wsf + 1085440;        // 12288
  const int W0 = 1097728;

  static const int wcnt[23] = {197376, 768, 98304, 768, 98304, 768, 768,
                               196608, 768, 98304, 768, 16384, 128, 384, 3,
                               774, 3, 16384, 128, 8192, 64, 128, 1};
  int woff[23];
  {
    int o = W0;
    for (int k = 0; k < 23; k++) { woff[k] = o; o += wcnt[k]; }
  }
  const int IOFF = woff[22] + wcnt[22];
  int* ibase = (int*)d_ws;
  int* idx1 = ibase + IOFF;
  int* cnt1 = idx1 + NN * KE;
  int* idx2 = cnt1 + NN;
  int* cnt2 = idx2 + NN * KI;
  int* gstart = cnt2 + NN;
  int* flag = gstart + 33;
  // packed interleaved MFMA weight fragments, 16B-aligned
  int wboff = (int)((flag + 1) - ibase);
  wboff = (wboff + 3) & ~3;
  u16* WBP = (u16*)(ibase + wboff);
  // hpart / msum staging buffers (fp32, NN x HD each)
  float* HPART = wsf + (wboff + 18 * 32768 / 2);
  float* MSUM = HPART + (size_t)NN * HD;

  const float* EW1 = wsf + woff[0];
  const float* EB1 = wsf + woff[1];
  const float* EB2 = wsf + woff[3];
  const float* CB1 = wsf + woff[5];
  const float* CW2 = wsf + woff[6];
  const float* NW1 = wsf + woff[7];
  const float* NB1 = wsf + woff[8];
  const float* NW2 = wsf + woff[9];
  const float* NB2 = wsf + woff[10];
  const float* FW1 = wsf + woff[11];
  const float* FB1 = wsf + woff[12];
  const float* FW2 = wsf + woff[13];
  const float* FB2 = wsf + woff[14];
  const float* IW = wsf + woff[15];
  const float* IB = wsf + woff[16];
  const float* CW1G = wsf + woff[17];
  const float* CB1G = wsf + woff[18];
  const float* CW2G = wsf + woff[19];
  const float* CB2G = wsf + woff[20];
  const float* SW = wsf + woff[21];
  const float* SB = wsf + woff[22];

  probe_dtype<<<1, 256, 0, stream>>>((const u16*)d_in[0], flag);

  CvtTable tab;
  tab.src[0] = d_in[0]; tab.dstoff[0] = 0;       tab.cnt[0] = NN * HD;
  tab.src[1] = d_in[1]; tab.dstoff[1] = 524288;  tab.cnt[1] = NN * 3;
  for (int k = 0; k < 23; k++) {
    tab.src[2 + k] = d_in[3 + k];
    tab.dstoff[2 + k] = woff[k];
    tab.cnt[2 + k] = wcnt[k];
  }
  {
    dim3 g((NN * HD + 255) / 256, 25, 1);
    convert_all<<<g, 256, 0, stream>>>(tab, wsf, flag);
  }
  pack_weights<<<(18 * 32768 + 255) / 256, 256, 0, stream>>>(
      wsf, woff[0], woff[2], woff[4], WBP);

  const int* batch = (const int*)d_in[2];
  graph_bounds<<<NN / 256, 256, 0, stream>>>(batch, gstart);

  const float cut2s[3] = {9.f, 36.f, 100.f};
  float *hin = h_a, *pin = pos_a, *hout = h_b, *pout = pos_b;
  // hpart for layer 0
  hpart_kernel<<<NN / 8, 256, 0, stream>>>(h_a, EW1, EB1, HPART);
  for (int l = 0; l < 6; l++) {
    if ((l & 1) == 0)
      neigh_kernel<<<NN / 4, 256, 0, stream>>>(pin, batch, gstart, idx1, cnt1, KE, cut2s[l >> 1]);
    egnn_edge<<<NN / 2, 256, 0, stream>>>(
        hin, pin, pout, idx1, cnt1, HPART,
        EW1 + (size_t)l * 257 * HD + 256 * HD,
        EB2 + (size_t)l * HD, CB1 + (size_t)l * HD, CW2 + (size_t)l * HD,
        MSUM, WBP + (size_t)l * 3 * 32768);
    const int ln = (l < 5) ? (l + 1) : l;   // last layer's hpart is unused
    node_hpart_kernel<<<NN / 8, 256, 0, stream>>>(
        hin, MSUM,
        NW1 + (size_t)l * 256 * HD, NB1 + (size_t)l * HD,
        NW2 + (size_t)l * HD * HD, NB2 + (size_t)l * HD,
        EW1 + (size_t)ln * 257 * HD, EB1 + (size_t)ln * HD,
        hout, HPART);
    float* th = hin; hin = hout; hout = th;
    float* tp = pin; pin = pout; pout = tp;
  }
  neigh_kernel<<<NN / 4, 256, 0, stream>>>(pin, batch, gstart, idx2, cnt2, KI, 100.f);
  heads_kernel<<<NN, 256, 0, stream>>>(hin, pin, FW1, FB1, FW2, FB2, CW1G, CB1G, CW2G, CB2G,
                                       SW, SB, IW, At, Bt, d_out, flag);
  scores_kernel<<<(3 * NN * KI + 255) / 256, 256, 0, stream>>>(
      pin, idx2, cnt2, At, Bt, IW, IB, d_out, flag);
}

// Round 12
// 856.545 us; speedup vs baseline: 1.3045x; 1.0697x over previous
//
#include <hip/hip_runtime.h>
#include <hip/hip_bf16.h>

#define NN 4096
#define HD 128
#define KE 32
#define KI 20
#define XLD 132   // X LDS row stride in u32 (16B-aligned rows)
#define PLOF 68   // lo-plane column offset within a row (16B-aligned)

// output element offsets
#define OFF_H   0
#define OFF_POS 524288
#define OFF_F   536576
#define OFF_S   548864
#define OFF_C   794624
#define OFF_ST  1056768

typedef unsigned short u16;
typedef unsigned int u32;
typedef unsigned long long u64;
typedef __attribute__((ext_vector_type(8))) short bf16x8;   // 8 bf16 (4 VGPR)
typedef __attribute__((ext_vector_type(4))) float f32x4;

__device__ __forceinline__ float b2f(u16 u) {
  union { u32 i; float f; } c; c.i = ((u32)u) << 16; return c.f;
}
__device__ __forceinline__ float silu_f(float x) { return x / (1.f + __expf(-x)); }
__device__ __forceinline__ void stout(void* out, int fp32m, size_t i, float v) {
  if (fp32m) ((float*)out)[i] = v;
  else ((__hip_bfloat16*)out)[i] = __float2bfloat16(v);
}
// RNE float->bf16 bits (reference path, used in pack_weights)
__device__ __forceinline__ u32 f2b(float f) {
  u32 u = __float_as_uint(f);
  return (u + 0x7fffu + ((u >> 16) & 1u)) >> 16;
}
// hi/lo split of two adjacent values -> plane words (H=[b:a] hi, L=[b:a] lo)
__device__ __forceinline__ void packplane(float a, float b, u32& H, u32& L) {
  asm("v_cvt_pk_bf16_f32 %0, %1, %2" : "=v"(H) : "v"(a), "v"(b));
  float hfa = __uint_as_float(H << 16);
  float hfb = __uint_as_float(H & 0xffff0000u);
  asm("v_cvt_pk_bf16_f32 %0, %1, %2" : "=v"(L) : "v"(a - hfa), "v"(b - hfb));
}

// ---------------- dtype probe ----------------
__global__ void probe_dtype(const u16* __restrict__ h, int* __restrict__ flag) {
  if (threadIdx.x == 0) atomicExch(flag, 0);
  __syncthreads();
  int bad = 0;
  for (int i = threadIdx.x; i < 8192; i += 256) {
    float v = b2f(h[i]);
    if (!(v > -1000.f && v < 1000.f)) bad = 1;
  }
  if (bad) atomicOr(flag, 1);
}

// ---------------- convert all float tensors -> fp32 workspace ----------------
struct CvtTable {
  const void* src[25];
  int dstoff[25];
  int cnt[25];
};

__global__ void convert_all(CvtTable tab, float* __restrict__ wsf, const int* __restrict__ flag) {
  const int seg = blockIdx.y;
  const int i = blockIdx.x * 256 + threadIdx.x;
  if (i >= tab.cnt[seg]) return;
  float v;
  if (*flag) v = ((const float*)tab.src[seg])[i];
  else       v = b2f(((const u16*)tab.src[seg])[i]);
  wsf[tab.dstoff[seg] + i] = v;
}

// ------- pack stage weights: interleaved hi/lo MFMA fragments -------
// Layout: [mat 18][kt 4][ot 8][lane 64][16 u16] where [0..8)=hi j, [8..16)=lo j.
__global__ void pack_weights(const float* __restrict__ wsf, int offEW1, int offEW2, int offCW1,
                             u16* __restrict__ WBP) {
  int tid = blockIdx.x * 256 + threadIdx.x;
  if (tid >= 18 * 32768) return;
  int m = tid >> 15;
  int rix = tid & 32767;
  int layer = m / 3, s = m % 3;
  const float* src;
  if (s == 0)      src = wsf + offEW1 + (size_t)layer * 257 * HD + 128 * HD;
  else if (s == 1) src = wsf + offEW2 + (size_t)layer * HD * HD;
  else             src = wsf + offCW1 + (size_t)layer * HD * HD;
  int jh = rix & 15, lane = (rix >> 4) & 63, ot = (rix >> 10) & 7, kt = rix >> 13;
  int j = jh & 7;
  int f = kt * 32 + (lane >> 4) * 8 + j;
  int o = ot * 16 + (lane & 15);
  float v = src[f * HD + o];
  u32 hb = f2b(v);
  float hf = __uint_as_float(hb << 16);
  u32 lb = f2b(v - hf);
  WBP[tid] = (jh < 8) ? (u16)hb : (u16)lb;
}

// ---------------- graph boundaries from sorted batch ----------------
__global__ void graph_bounds(const int* __restrict__ batch, int* __restrict__ gstart) {
  int n = blockIdx.x * 256 + threadIdx.x;
  if (n >= NN) return;
  int v = batch[n];
  int pv = (n == 0) ? -1 : batch[n - 1];
  for (int b = pv + 1; b <= v; b++) gstart[b] = n;
  if (n == NN - 1) for (int b = v + 1; b <= 32; b++) gstart[b] = NN;
}

// ---------------- exact k-NN within cutoff (one wave per node) ----------------
__global__ __launch_bounds__(256) void neigh_kernel(
    const float* __restrict__ pos, const int* __restrict__ batch,
    const int* __restrict__ gstart, int* __restrict__ idx, int* __restrict__ cnt,
    int Ksel, float cut2) {
  const int lane = threadIdx.x & 63;
  const int i = blockIdx.x * 4 + (threadIdx.x >> 6);
  const int b = batch[i];
  const int gs = gstart[b];
  const int ge = gstart[b + 1];
  const int span = ge - gs;
  const float px = pos[i * 3 + 0], py = pos[i * 3 + 1], pz = pos[i * 3 + 2];
  u64 key[16];
#pragma unroll
  for (int tq = 0; tq < 16; tq++) {
    u64 k64 = ~0ull;
    if (tq * 64 < span) {
      int j = gs + tq * 64 + lane;
      if (j < ge && j != i) {
        float dx = px - pos[j * 3 + 0];
        float dy = py - pos[j * 3 + 1];
        float dz = pz - pos[j * 3 + 2];
        float d2 = dx * dx + dy * dy + dz * dz;
        if (d2 <= cut2) k64 = (((u64)__float_as_uint(d2)) << 32) | (u32)j;
      }
    }
    key[tq] = k64;
  }
  u64 thresh = 0;
  int myidx = i;
  int mycnt = 0;
  for (int s = 0; s < Ksel; s++) {
    u64 m = ~0ull;
#pragma unroll
    for (int tq = 0; tq < 16; tq++) {
      if (tq * 64 < span) {
        u64 kk = key[tq];
        if (kk >= thresh && kk < m) m = kk;
      }
    }
    for (int off = 32; off > 0; off >>= 1) {
      u64 o = __shfl_down(m, (unsigned)off, 64);
      if (o < m) m = o;
    }
    m = __shfl(m, 0, 64);
    if (m != ~0ull) {
      if (lane == s) myidx = (int)(m & 0xffffffffu);
      mycnt++;
      thresh = m + 1;
    } else break;
  }
  if (lane < Ksel) idx[i * Ksel + lane] = myidx;
  if (lane == 0) cnt[i] = mycnt;
}

// ---------------- hpart: hpart[n][o] = h[n] . ew1[0:128,o] + eb1[o] ----------
// Used once for layer 0; layers 1..5 get hpart from node_hpart_kernel.
__global__ __launch_bounds__(256) void hpart_kernel(
    const float* __restrict__ h, const float* __restrict__ ew1,
    const float* __restrict__ eb1, float* __restrict__ hpart) {
  __shared__ float ht[2][HD];
  const int t = threadIdx.x;
  const int n0 = blockIdx.x * 2;
  const int nd = t >> 7, oo = t & 127;
  ht[nd][oo] = h[(size_t)(n0 + nd) * HD + oo];
  __syncthreads();
  float a = 0.f, b = 0.f;
#pragma unroll 8
  for (int f = 0; f < 64; f++) a = fmaf(ht[nd][f], ew1[(size_t)f * HD + oo], a);
#pragma unroll 8
  for (int f = 64; f < 128; f++) b = fmaf(ht[nd][f], ew1[(size_t)f * HD + oo], b);
  hpart[(size_t)(n0 + nd) * HD + oo] = a + b + eb1[oo];
}

// ------- fused node MLP (layer l) + hpart (layer l+1), 2 nodes/block -------
// Round-11's 8-node version ran 512 blocks = 2 blocks/CU: its ~512 dependent
// L2 weight loads/thread were latency-exposed (~58 us/dispatch). 2048 blocks
// (8/CU, up to 32 waves/CU) hides the latency. Per-output fp chains verbatim
// (f-ascending fmaf, half-split sums) -> bit-identical output.
__global__ __launch_bounds__(256) void node_hpart_kernel(
    const float* __restrict__ h_in, const float* __restrict__ msum,
    const float* __restrict__ nw1, const float* __restrict__ nb1,
    const float* __restrict__ nw2, const float* __restrict__ nb2,
    const float* __restrict__ ew1n, const float* __restrict__ eb1n,
    float* __restrict__ h_out, float* __restrict__ hpart, int do_hpart) {
  __shared__ float ht[2][HD], mt[2][HD], ut[2][HD];
  const int t = threadIdx.x;
  const int n0 = blockIdx.x * 2;
  const int nd = t >> 7, oo = t & 127;
  ht[nd][oo] = h_in[(size_t)(n0 + nd) * HD + oo];
  mt[nd][oo] = msum[(size_t)(n0 + nd) * HD + oo];
  __syncthreads();
  float p1 = 0.f, p2 = 0.f;
#pragma unroll 8
  for (int f = 0; f < 128; f++) p1 = fmaf(ht[nd][f], nw1[(size_t)f * HD + oo], p1);
#pragma unroll 8
  for (int f = 0; f < 128; f++) p2 = fmaf(mt[nd][f], nw1[(size_t)(128 + f) * HD + oo], p2);
  ut[nd][oo] = silu_f(p1 + p2 + nb1[oo]);
  __syncthreads();
  float q1 = 0.f, q2 = 0.f;
#pragma unroll 8
  for (int f = 0; f < 64; f++) q1 = fmaf(ut[nd][f], nw2[(size_t)f * HD + oo], q1);
#pragma unroll 8
  for (int f = 64; f < 128; f++) q2 = fmaf(ut[nd][f], nw2[(size_t)f * HD + oo], q2);
  const float ho = ht[nd][oo] + q1 + q2 + nb2[oo];
  h_out[(size_t)(n0 + nd) * HD + oo] = ho;
  if (do_hpart) {
    // mt fully consumed (p2 loop) before the ut barrier; no reader since.
    mt[nd][oo] = ho;
    __syncthreads();
    float a = 0.f, b = 0.f;
#pragma unroll 8
    for (int f = 0; f < 64; f++) a = fmaf(mt[nd][f], ew1n[(size_t)f * HD + oo], a);
#pragma unroll 8
    for (int f = 64; f < 128; f++) b = fmaf(mt[nd][f], ew1n[(size_t)f * HD + oo], b);
    hpart[(size_t)(n0 + nd) * HD + oo] = a + b + eb1n[oo];
  }
}

// ---------------- edge kernel: 256 thr / 4 waves / 2 nodes ----------------
// Byte-identical to the round-7 edge kernel (68.7 us dense, 64 VGPR, no spill).
__global__ __launch_bounds__(256, 4) void egnn_edge(
    const float* __restrict__ h_in, const float* __restrict__ pos_in,
    float* __restrict__ pos_out,
    const int* __restrict__ idx, const int* __restrict__ cnt,
    const float* __restrict__ hpart, const float* __restrict__ ew1d2,
    const float* __restrict__ eb2, const float* __restrict__ cb1,
    const float* __restrict__ cw2,
    float* __restrict__ msum, const u16* __restrict__ wbp) {
  __shared__ __align__(16) u32 xp[64 * XLD];
  __shared__ float hp_s[2][HD];
  __shared__ float rel_s[3][64], d2_s[64], mf_s[64], ce_s[64];
  __shared__ float ce_red[64][9];
  __shared__ int idx_s[64], cn_s[2];

  const int t = threadIdx.x;
  const int i0 = blockIdx.x * 2;
  const int lane = t & 63;
  const int w = __builtin_amdgcn_readfirstlane(t >> 6);  // 0..3
  const int l16 = lane & 15, q = lane >> 4;

  if (t < 64) idx_s[t] = idx[(size_t)(i0 + (t >> 5)) * KE + (t & 31)];
  else if (t < 66) cn_s[t - 64] = cnt[i0 + (t - 64)];
  __syncthreads();
  const int nt0 = __builtin_amdgcn_readfirstlane((cn_s[0] + 15) >> 4);
  const int nt1 = __builtin_amdgcn_readfirstlane((cn_s[1] + 15) >> 4);
#define LIVE(Et) (((Et) < 2) ? ((Et) < nt0) : ((Et) - 2 < nt1))

  if (t < 64) {
    const int nd = t >> 5, ic = i0 + nd;
    const int j = idx_s[t];
    const float rx = pos_in[ic * 3 + 0] - pos_in[j * 3 + 0];
    const float ry = pos_in[ic * 3 + 1] - pos_in[j * 3 + 1];
    const float rz = pos_in[ic * 3 + 2] - pos_in[j * 3 + 2];
    rel_s[0][t] = rx; rel_s[1][t] = ry; rel_s[2][t] = rz;
    d2_s[t] = rx * rx + ry * ry + rz * rz;
    mf_s[t] = ((t & 31) < cn_s[nd]) ? 1.0f : 0.0f;
  }
  {
    const int nd = t >> 7, f = t & 127;
    hp_s[nd][f] = hpart[(size_t)(i0 + nd) * HD + f];
  }
  // gather hj -> hi/lo planes; thread covers 32 f of one e row
  {
    const int e = t & 63;
    const int myEt = e >> 4;
    const bool glive = (myEt < 2) ? (myEt < nt0) : (myEt - 2 < nt1);
    if (glive) {
      const int j = idx_s[e];
      const int f0 = (t >> 6) * 32;
      const float4* src = (const float4*)(h_in + (size_t)j * HD + f0);
#pragma unroll
      for (int half = 0; half < 2; half++) {
        float4 v0 = src[half * 4 + 0], v1 = src[half * 4 + 1];
        float4 v2 = src[half * 4 + 2], v3 = src[half * 4 + 3];
        u32 H0, L0, H1, L1, H2, L2, H3, L3, H4, L4, H5, L5, H6, L6, H7, L7;
        packplane(v0.x, v0.y, H0, L0); packplane(v0.z, v0.w, H1, L1);
        packplane(v1.x, v1.y, H2, L2); packplane(v1.z, v1.w, H3, L3);
        packplane(v2.x, v2.y, H4, L4); packplane(v2.z, v2.w, H5, L5);
        packplane(v3.x, v3.y, H6, L6); packplane(v3.z, v3.w, H7, L7);
        u32* dh = xp + e * XLD + ((f0 + half * 16) >> 1);
        uint4 a; a.x = H0; a.y = H1; a.z = H2; a.w = H3;
        uint4 b; b.x = H4; b.y = H5; b.z = H6; b.w = H7;
        uint4 c; c.x = L0; c.y = L1; c.z = L2; c.w = L3;
        uint4 d; d.x = L4; d.y = L5; d.z = L6; d.w = L7;
        *(uint4*)(dh) = a;        *(uint4*)(dh + 4) = b;
        *(uint4*)(dh + PLOF) = c; *(uint4*)(dh + PLOF + 4) = d;
      }
    }
  }
  __syncthreads();

  // macro: one full 3-term dual-tile MFMA pass over live e-tiles
#define MFMA_PASS(WPBASE, accA, accB)                                          \
  {                                                                            \
    f32x4 z = {0.f, 0.f, 0.f, 0.f};                                            \
    accA[0] = z; accA[1] = z; accA[2] = z; accA[3] = z;                        \
    accB[0] = z; accB[1] = z; accB[2] = z; accB[3] = z;                        \
    bf16x8 whA[4], wlA[4], whB[4], wlB[4];                                     \
    _Pragma("unroll")                                                          \
    for (int kt = 0; kt < 4; kt++) {                                           \
      const u16* wa = (WPBASE) + (size_t)((kt * 8 + w) * 64 + lane) * 16;      \
      whA[kt] = *(const bf16x8*)(wa); wlA[kt] = *(const bf16x8*)(wa + 8);      \
      const u16* wb = (WPBASE) + (size_t)((kt * 8 + w + 4) * 64 + lane) * 16;  \
      whB[kt] = *(const bf16x8*)(wb); wlB[kt] = *(const bf16x8*)(wb + 8);      \
    }                                                                          \
    _Pragma("unroll")                                                          \
    for (int Et = 0; Et < 4; Et++) {                                           \
      if (LIVE(Et)) {                                                          \
        _Pragma("unroll")                                                      \
        for (int kt = 0; kt < 4; kt++) {                                       \
          const u32* xr = xp + (Et * 16 + l16) * XLD + kt * 16 + q * 4;        \
          bf16x8 xh = *(const bf16x8*)(xr);                                    \
          bf16x8 xl = *(const bf16x8*)(xr + PLOF);                             \
          accA[Et] = __builtin_amdgcn_mfma_f32_16x16x32_bf16(whA[kt], xl, accA[Et], 0, 0, 0); \
          accA[Et] = __builtin_amdgcn_mfma_f32_16x16x32_bf16(wlA[kt], xh, accA[Et], 0, 0, 0); \
          accA[Et] = __builtin_amdgcn_mfma_f32_16x16x32_bf16(whA[kt], xh, accA[Et], 0, 0, 0); \
          accB[Et] = __builtin_amdgcn_mfma_f32_16x16x32_bf16(whB[kt], xl, accB[Et], 0, 0, 0); \
          accB[Et] = __builtin_amdgcn_mfma_f32_16x16x32_bf16(wlB[kt], xh, accB[Et], 0, 0, 0); \
          accB[Et] = __builtin_amdgcn_mfma_f32_16x16x32_bf16(whB[kt], xh, accB[Et], 0, 0, 0); \
        }                                                                      \
      }                                                                        \
    }                                                                          \
  }

  // ---- stage B ----
  {
    f32x4 accA[4], accB[4];
    MFMA_PASS(wbp, accA, accB)
    __syncthreads();  // all plane reads done before in-place overwrite
#define EPIB(ACC, OT)                                                          \
    {                                                                          \
      const int o = (OT) * 16 + q * 4;                                         \
      const float4 w24 = *(const float4*)(ew1d2 + o);                          \
      _Pragma("unroll")                                                        \
      for (int Et = 0; Et < 4; Et++) {                                         \
        if (LIVE(Et)) {                                                        \
          const int ee = Et * 16 + l16;                                        \
          const float d2e = d2_s[ee];                                          \
          const float4 hp4 = *(const float4*)(&hp_s[Et >> 1][o]);              \
          float s0 = silu_f(ACC[Et][0] + hp4.x + d2e * w24.x);                 \
          float s1 = silu_f(ACC[Et][1] + hp4.y + d2e * w24.y);                 \
          float s2 = silu_f(ACC[Et][2] + hp4.z + d2e * w24.z);                 \
          float s3 = silu_f(ACC[Et][3] + hp4.w + d2e * w24.w);                 \
          u32 H0, L0, H1, L1;                                                  \
          packplane(s0, s1, H0, L0);                                           \
          packplane(s2, s3, H1, L1);                                           \
          u32* dst = xp + ee * XLD + (OT) * 8 + q * 2;                         \
          uint2 hh; hh.x = H0; hh.y = H1;                                      \
          uint2 ll; ll.x = L0; ll.y = L1;                                      \
          *(uint2*)(dst) = hh;                                                 \
          *(uint2*)(dst + PLOF) = ll;                                          \
        }                                                                      \
      }                                                                        \
    }
    EPIB(accA, w)
    EPIB(accB, (w + 4))
#undef EPIB
  }
  __syncthreads();

  // ---- stage C (+ msum) ----
  {
    f32x4 accA[4], accB[4];
    MFMA_PASS(wbp + 32768, accA, accB)
    __syncthreads();  // all reads done before in-place overwrite
    float msA0[4] = {0.f, 0.f, 0.f, 0.f}, msA1[4] = {0.f, 0.f, 0.f, 0.f};
    float msB0[4] = {0.f, 0.f, 0.f, 0.f}, msB1[4] = {0.f, 0.f, 0.f, 0.f};
#define EPIC(ACC, OT, MS0, MS1)                                                \
    {                                                                          \
      const int o = (OT) * 16 + q * 4;                                         \
      const float4 eb4 = *(const float4*)(eb2 + o);                            \
      _Pragma("unroll")                                                        \
      for (int Et = 0; Et < 4; Et++) {                                         \
        if (LIVE(Et)) {                                                        \
          const int ee = Et * 16 + l16;                                        \
          const float mfv = mf_s[ee];                                          \
          float m0 = (mfv != 0.f) ? silu_f(ACC[Et][0] + eb4.x) : 0.f;          \
          float m1 = (mfv != 0.f) ? silu_f(ACC[Et][1] + eb4.y) : 0.f;          \
          float m2 = (mfv != 0.f) ? silu_f(ACC[Et][2] + eb4.z) : 0.f;          \
          float m3 = (mfv != 0.f) ? silu_f(ACC[Et][3] + eb4.w) : 0.f;          \
          if (Et < 2) { MS0[0] += m0; MS0[1] += m1; MS0[2] += m2; MS0[3] += m3; } \
          else        { MS1[0] += m0; MS1[1] += m1; MS1[2] += m2; MS1[3] += m3; } \
          u32 H0, L0, H1, L1;                                                  \
          packplane(m0, m1, H0, L0);                                           \
          packplane(m2, m3, H1, L1);                                           \
          u32* dst = xp + ee * XLD + (OT) * 8 + q * 2;                         \
          uint2 hh; hh.x = H0; hh.y = H1;                                      \
          uint2 ll; ll.x = L0; ll.y = L1;                                      \
          *(uint2*)(dst) = hh;                                                 \
          *(uint2*)(dst + PLOF) = ll;                                          \
        }                                                                      \
      }                                                                        \
    }
    EPIC(accA, w, msA0, msA1)
    EPIC(accB, (w + 4), msB0, msB1)
#undef EPIC
#define RED16(v) v += __shfl_xor(v, 1); v += __shfl_xor(v, 2); \
                 v += __shfl_xor(v, 4); v += __shfl_xor(v, 8);
#pragma unroll
    for (int r = 0; r < 4; r++) { RED16(msA0[r]) RED16(msA1[r]) RED16(msB0[r]) RED16(msB1[r]) }
#undef RED16
    if (l16 == 0) {
      float4 a0; a0.x = msA0[0]; a0.y = msA0[1]; a0.z = msA0[2]; a0.w = msA0[3];
      float4 a1; a1.x = msA1[0]; a1.y = msA1[1]; a1.z = msA1[2]; a1.w = msA1[3];
      float4 b0; b0.x = msB0[0]; b0.y = msB0[1]; b0.z = msB0[2]; b0.w = msB0[3];
      float4 b1; b1.x = msB1[0]; b1.y = msB1[1]; b1.z = msB1[2]; b1.w = msB1[3];
      *(float4*)(msum + (size_t)i0 * HD + w * 16 + q * 4) = a0;
      *(float4*)(msum + (size_t)(i0 + 1) * HD + w * 16 + q * 4) = a1;
      *(float4*)(msum + (size_t)i0 * HD + (w + 4) * 16 + q * 4) = b0;
      *(float4*)(msum + (size_t)(i0 + 1) * HD + (w + 4) * 16 + q * 4) = b1;
    }
  }
  __syncthreads();

  // ---- stage D: coord head ----
  {
    f32x4 accA[4], accB[4];
    MFMA_PASS(wbp + 65536, accA, accB)
#define EPID(ACC, OT)                                                          \
    {                                                                          \
      const int o = (OT) * 16 + q * 4;                                         \
      const float4 cb4 = *(const float4*)(cb1 + o);                            \
      const float4 cw4 = *(const float4*)(cw2 + o);                            \
      _Pragma("unroll")                                                        \
      for (int Et = 0; Et < 4; Et++) {                                         \
        if (LIVE(Et)) {                                                        \
          float p = silu_f(ACC[Et][0] + cb4.x) * cw4.x;                        \
          p = fmaf(silu_f(ACC[Et][1] + cb4.y), cw4.y, p);                      \
          p = fmaf(silu_f(ACC[Et][2] + cb4.z), cw4.z, p);                      \
          p = fmaf(silu_f(ACC[Et][3] + cb4.w), cw4.w, p);                      \
          p += __shfl_xor(p, 16);                                              \
          p += __shfl_xor(p, 32);                                              \
          if (lane < 16) ce_red[Et * 16 + lane][OT] = p;                       \
        }                                                                      \
      }                                                                        \
    }
    EPID(accA, w)
    EPID(accB, (w + 4))
#undef EPID
  }
  __syncthreads();
  if (t < 64) {
    float c = 0.f;
#pragma unroll
    for (int wv = 0; wv < 8; wv++) c += ce_red[t][wv];
    ce_s[t] = (mf_s[t] != 0.f) ? c : 0.f;
  }
  __syncthreads();
  if (t < 6) {
    const int nd = t / 3, ax = t - nd * 3, ic = i0 + nd;
    float s = 0.f;
#pragma unroll
    for (int k = 0; k < 32; k++) s = fmaf(rel_s[ax][nd * 32 + k], ce_s[nd * 32 + k], s);
    const float cntf = fmaxf((float)cn_s[nd], 1.f);
    pos_out[ic * 3 + ax] = pos_in[ic * 3 + ax] + s / cntf;
  }
#undef LIVE
#undef MFMA_PASS
}

// ---------------- final heads (per node) ----------------
__global__ __launch_bounds__(256) void heads_kernel(
    const float* __restrict__ h, const float* __restrict__ pos,
    const float* __restrict__ fw1, const float* __restrict__ fb1,
    const float* __restrict__ fw2, const float* __restrict__ fb2,
    const float* __restrict__ cw1g, const float* __restrict__ cb1g,
    const float* __restrict__ cw2g, const float* __restrict__ cb2g,
    const float* __restrict__ sw, const float* __restrict__ sb,
    const float* __restrict__ iw,
    float* __restrict__ At, float* __restrict__ Bt,
    void* __restrict__ out, const int* __restrict__ flag) {
  __shared__ float hi_s[HD], v1[HD], red_s[256];
  const int i = blockIdx.x, t = threadIdx.x;
  const int fm = *flag;
  if (t < HD) hi_s[t] = h[(size_t)i * HD + t];
  __syncthreads();
  const int o = t & 127, ph = t >> 7;
  // forces MLP1
  {
    float p = 0.f;
#pragma unroll 4
    for (int f = ph * 64; f < ph * 64 + 64; f++) p = fmaf(hi_s[f], fw1[f * HD + o], p);
    red_s[t] = p;
  }
  __syncthreads();
  if (t < HD) v1[t] = tanhf(red_s[t] + red_s[t + 128] + fb1[t]);
  __syncthreads();
  if (t < 3) {
    float p = 0.f;
    for (int f = 0; f < HD; f++) p = fmaf(v1[f], fw2[f * 3 + t], p);
    stout(out, fm, OFF_F + (size_t)i * 3 + t, p + fb2[t]);
  }
  __syncthreads();
  // conformer MLP1
  {
    float p = 0.f;
#pragma unroll 4
    for (int f = ph * 64; f < ph * 64 + 64; f++) p = fmaf(hi_s[f], cw1g[f * HD + o], p);
    red_s[t] = p;
  }
  __syncthreads();
  if (t < HD) v1[t] = fmaxf(red_s[t] + red_s[t + 128] + cb1g[t], 0.f);
  __syncthreads();
  // conformer MLP2
  {
    const int oo = t & 63, pc = t >> 6;
    float p = 0.f;
#pragma unroll 4
    for (int f = pc * 32; f < pc * 32 + 32; f++) p = fmaf(v1[f], cw2g[f * 64 + oo], p);
    red_s[t] = p;
  }
  __syncthreads();
  if (t < 64)
    stout(out, fm, OFF_C + (size_t)i * 64 + t,
          red_s[t] + red_s[t + 64] + red_s[t + 128] + red_s[t + 192] + cb2g[t]);
  __syncthreads();
  // steric
  if (t < HD) red_s[t] = hi_s[t] * sw[t];
  __syncthreads();
  if (t == 0) {
    float p = 0.f;
    for (int f = 0; f < HD; f++) p += red_s[f];
    stout(out, fm, OFF_ST + (size_t)i, p + sb[0]);
  }
  __syncthreads();
  // interaction head per-node dots
  {
    const int g = t >> 5, l = t & 31;
    float p = 0.f;
    if (g < 6) {
      const int tt = g >> 1, half = g & 1;
#pragma unroll
      for (int r2 = 0; r2 < 4; r2++)
        p = fmaf(hi_s[l * 4 + r2], iw[tt * 258 + half * 128 + l * 4 + r2], p);
    }
    red_s[t] = p;
  }
  __syncthreads();
  if (t < 6) {
    float p = 0.f;
    for (int l = 0; l < 32; l++) p += red_s[t * 32 + l];
    const int tt = t >> 1;
    if ((t & 1) == 0) At[tt * NN + i] = p;
    else Bt[tt * NN + i] = p;
  }
  if (t < HD) stout(out, fm, OFF_H + (size_t)i * HD + t, hi_s[t]);
  if (t >= 128 && t < 131) stout(out, fm, OFF_POS + (size_t)i * 3 + (t - 128), pos[i * 3 + (t - 128)]);
}

// ---------------- interaction scores ----------------
__global__ void scores_kernel(const float* __restrict__ pos, const int* __restrict__ idx2,
                              const int* __restrict__ cnt2, const float* __restrict__ At,
                              const float* __restrict__ Bt, const float* __restrict__ iw,
                              const float* __restrict__ ib, void* __restrict__ out,
                              const int* __restrict__ flag) {
  int tid = blockIdx.x * 256 + threadIdx.x;
  if (tid >= 3 * NN * KI) return;
  const int fm = *flag;
  const int tt = tid / (NN * KI);
  const int r = tid % (NN * KI);
  const int n = r / KI;
  const int k = r % KI;
  float v = 0.f;
  if (k < cnt2[n]) {
    int j = idx2[n * KI + k];
    float dx = pos[n * 3 + 0] - pos[j * 3 + 0];
    float dy = pos[n * 3 + 1] - pos[j * 3 + 1];
    float dz = pos[n * 3 + 2] - pos[j * 3 + 2];
    float d2 = dx * dx + dy * dy + dz * dz;
    float dist = sqrtf(d2 + 1e-12f);
    float s = At[tt * NN + n] + Bt[tt * NN + j] + dist * iw[tt * 258 + 256] +
              (dist * 0.1f) * iw[tt * 258 + 257] + ib[tt];
    v = 1.f / (1.f + __expf(-s));
  }
  stout(out, fm, OFF_S + (size_t)tid, v);
}

extern "C" void kernel_launch(void* const* d_in, const int* in_sizes, int n_in,
                              void* d_out, int out_size, void* d_ws, size_t ws_size,
                              hipStream_t stream) {
  (void)in_sizes; (void)n_in; (void)out_size; (void)ws_size;

  float* wsf = (float*)d_ws;
  float* h_a = wsf + 0;             // 524288
  float* pos_a = wsf + 524288;      // 12288
  float* h_b = wsf + 536576;        // 524288
  float* pos_b = wsf + 1060864;     // 12288
  float* At = wsf + 1073152;        // 12288
  float* Bt = wsf + 1085440;        // 12288
  const int W0 = 1097728;

  static const int wcnt[23] = {197376, 768, 98304, 768, 98304, 768, 768,
                               196608, 768, 98304, 768, 16384, 128, 384, 3,
                               774, 3, 16384, 128, 8192, 64, 128, 1};
  int woff[23];
  {
    int o = W0;
    for (int k = 0; k < 23; k++) { woff[k] = o; o += wcnt[k]; }
  }
  const int IOFF = woff[22] + wcnt[22];
  int* ibase = (int*)d_ws;
  int* idx1 = ibase + IOFF;
  int* cnt1 = idx1 + NN * KE;
  int* idx2 = cnt1 + NN;
  int* cnt2 = idx2 + NN * KI;
  int* gstart = cnt2 + NN;
  int* flag = gstart + 33;
  // packed interleaved MFMA weight fragments, 16B-aligned
  int wboff = (int)((flag + 1) - ibase);
  wboff = (wboff + 3) & ~3;
  u16* WBP = (u16*)(ibase + wboff);
  // hpart / msum staging buffers (fp32, NN x HD each)
  float* HPART = wsf + (wboff + 18 * 32768 / 2);
  float* MSUM = HPART + (size_t)NN * HD;

  const float* EW1 = wsf + woff[0];
  const float* EB1 = wsf + woff[1];
  const float* EB2 = wsf + woff[3];
  const float* CB1 = wsf + woff[5];
  const float* CW2 = wsf + woff[6];
  const float* NW1 = wsf + woff[7];
  const float* NB1 = wsf + woff[8];
  const float* NW2 = wsf + woff[9];
  const float* NB2 = wsf + woff[10];
  const float* FW1 = wsf + woff[11];
  const float* FB1 = wsf + woff[12];
  const float* FW2 = wsf + woff[13];
  const float* FB2 = wsf + woff[14];
  const float* IW = wsf + woff[15];
  const float* IB = wsf + woff[16];
  const float* CW1G = wsf + woff[17];
  const float* CB1G = wsf + woff[18];
  const float* CW2G = wsf + woff[19];
  const float* CB2G = wsf + woff[20];
  const float* SW = wsf + woff[21];
  const float* SB = wsf + woff[22];

  probe_dtype<<<1, 256, 0, stream>>>((const u16*)d_in[0], flag);

  CvtTable tab;
  tab.src[0] = d_in[0]; tab.dstoff[0] = 0;       tab.cnt[0] = NN * HD;
  tab.src[1] = d_in[1]; tab.dstoff[1] = 524288;  tab.cnt[1] = NN * 3;
  for (int k = 0; k < 23; k++) {
    tab.src[2 + k] = d_in[3 + k];
    tab.dstoff[2 + k] = woff[k];
    tab.cnt[2 + k] = wcnt[k];
  }
  {
    dim3 g((NN * HD + 255) / 256, 25, 1);
    convert_all<<<g, 256, 0, stream>>>(tab, wsf, flag);
  }
  pack_weights<<<(18 * 32768 + 255) / 256, 256, 0, stream>>>(
      wsf, woff[0], woff[2], woff[4], WBP);

  const int* batch = (const int*)d_in[2];
  graph_bounds<<<NN / 256, 256, 0, stream>>>(batch, gstart);

  const float cut2s[3] = {9.f, 36.f, 100.f};
  float *hin = h_a, *pin = pos_a, *hout = h_b, *pout = pos_b;
  // hpart for layer 0
  hpart_kernel<<<NN / 2, 256, 0, stream>>>(h_a, EW1, EB1, HPART);
  for (int l = 0; l < 6; l++) {
    if ((l & 1) == 0)
      neigh_kernel<<<NN / 4, 256, 0, stream>>>(pin, batch, gstart, idx1, cnt1, KE, cut2s[l >> 1]);
    egnn_edge<<<NN / 2, 256, 0, stream>>>(
        hin, pin, pout, idx1, cnt1, HPART,
        EW1 + (size_t)l * 257 * HD + 256 * HD,
        EB2 + (size_t)l * HD, CB1 + (size_t)l * HD, CW2 + (size_t)l * HD,
        MSUM, WBP + (size_t)l * 3 * 32768);
    const int ln = (l < 5) ? (l + 1) : l;   // last layer's hpart is unused
    node_hpart_kernel<<<NN / 2, 256, 0, stream>>>(
        hin, MSUM,
        NW1 + (size_t)l * 256 * HD, NB1 + (size_t)l * HD,
        NW2 + (size_t)l * HD * HD, NB2 + (size_t)l * HD,
        EW1 + (size_t)ln * 257 * HD, EB1 + (size_t)ln * HD,
        hout, HPART, (l < 5) ? 1 : 0);
    float* th = hin; hin = hout; hout = th;
    float* tp = pin; pin = pout; pout = tp;
  }
  neigh_kernel<<<NN / 4, 256, 0, stream>>>(pin, batch, gstart, idx2, cnt2, KI, 100.f);
  heads_kernel<<<NN, 256, 0, stream>>>(hin, pin, FW1, FB1, FW2, FB2, CW1G, CB1G, CW2G, CB2G,
                                       SW, SB, IW, At, Bt, d_out, flag);
  scores_kernel<<<(3 * NN * KI + 255) / 256, 256, 0, stream>>>(
      pin, idx2, cnt2, At, Bt, IW, IB, d_out, flag);
}

// Round 13
// 848.323 us; speedup vs baseline: 1.3171x; 1.0097x over previous
//
#include <hip/hip_runtime.h>
#include <hip/hip_bf16.h>

#define NN 4096
#define HD 128
#define KE 32
#define KI 20
#define XLD 132   // X LDS row stride in u32 (16B-aligned rows)
#define PLOF 68   // lo-plane column offset within a row (16B-aligned)

// output element offsets
#define OFF_H   0
#define OFF_POS 524288
#define OFF_F   536576
#define OFF_S   548864
#define OFF_C   794624
#define OFF_ST  1056768

// XCD-aware bijective block swizzle (grid divisible by 8): consecutive logical
// blocks land on the SAME XCD -> per-XCD L2 keeps the graph-local h/hpart span
// hot instead of all 8 XCDs re-fetching everything from HBM (edge FETCH_SIZE
// showed ~12.4MB vs ~6MB working set = cross-XCD replication).
#define XCD_SWZ(bid0, nwg) ((((bid0) & 7) * ((nwg) >> 3)) + ((bid0) >> 3))

typedef unsigned short u16;
typedef unsigned int u32;
typedef unsigned long long u64;
typedef __attribute__((ext_vector_type(8))) short bf16x8;   // 8 bf16 (4 VGPR)
typedef __attribute__((ext_vector_type(4))) float f32x4;

__device__ __forceinline__ float b2f(u16 u) {
  union { u32 i; float f; } c; c.i = ((u32)u) << 16; return c.f;
}
__device__ __forceinline__ float silu_f(float x) { return x / (1.f + __expf(-x)); }
__device__ __forceinline__ void stout(void* out, int fp32m, size_t i, float v) {
  if (fp32m) ((float*)out)[i] = v;
  else ((__hip_bfloat16*)out)[i] = __float2bfloat16(v);
}
// RNE float->bf16 bits (reference path, used in pack_weights)
__device__ __forceinline__ u32 f2b(float f) {
  u32 u = __float_as_uint(f);
  return (u + 0x7fffu + ((u >> 16) & 1u)) >> 16;
}
// hi/lo split of two adjacent values -> plane words (H=[b:a] hi, L=[b:a] lo)
__device__ __forceinline__ void packplane(float a, float b, u32& H, u32& L) {
  asm("v_cvt_pk_bf16_f32 %0, %1, %2" : "=v"(H) : "v"(a), "v"(b));
  float hfa = __uint_as_float(H << 16);
  float hfb = __uint_as_float(H & 0xffff0000u);
  asm("v_cvt_pk_bf16_f32 %0, %1, %2" : "=v"(L) : "v"(a - hfa), "v"(b - hfb));
}

// ---------------- dtype probe ----------------
__global__ void probe_dtype(const u16* __restrict__ h, int* __restrict__ flag) {
  if (threadIdx.x == 0) atomicExch(flag, 0);
  __syncthreads();
  int bad = 0;
  for (int i = threadIdx.x; i < 8192; i += 256) {
    float v = b2f(h[i]);
    if (!(v > -1000.f && v < 1000.f)) bad = 1;
  }
  if (bad) atomicOr(flag, 1);
}

// ---------------- convert all float tensors -> fp32 workspace ----------------
struct CvtTable {
  const void* src[25];
  int dstoff[25];
  int cnt[25];
};

__global__ void convert_all(CvtTable tab, float* __restrict__ wsf, const int* __restrict__ flag) {
  const int seg = blockIdx.y;
  const int i = blockIdx.x * 256 + threadIdx.x;
  if (i >= tab.cnt[seg]) return;
  float v;
  if (*flag) v = ((const float*)tab.src[seg])[i];
  else       v = b2f(((const u16*)tab.src[seg])[i]);
  wsf[tab.dstoff[seg] + i] = v;
}

// ------- pack stage weights: interleaved hi/lo MFMA fragments -------
// Layout: [mat 18][kt 4][ot 8][lane 64][16 u16] where [0..8)=hi j, [8..16)=lo j.
__global__ void pack_weights(const float* __restrict__ wsf, int offEW1, int offEW2, int offCW1,
                             u16* __restrict__ WBP) {
  int tid = blockIdx.x * 256 + threadIdx.x;
  if (tid >= 18 * 32768) return;
  int m = tid >> 15;
  int rix = tid & 32767;
  int layer = m / 3, s = m % 3;
  const float* src;
  if (s == 0)      src = wsf + offEW1 + (size_t)layer * 257 * HD + 128 * HD;
  else if (s == 1) src = wsf + offEW2 + (size_t)layer * HD * HD;
  else             src = wsf + offCW1 + (size_t)layer * HD * HD;
  int jh = rix & 15, lane = (rix >> 4) & 63, ot = (rix >> 10) & 7, kt = rix >> 13;
  int j = jh & 7;
  int f = kt * 32 + (lane >> 4) * 8 + j;
  int o = ot * 16 + (lane & 15);
  float v = src[f * HD + o];
  u32 hb = f2b(v);
  float hf = __uint_as_float(hb << 16);
  u32 lb = f2b(v - hf);
  WBP[tid] = (jh < 8) ? (u16)hb : (u16)lb;
}

// ---------------- graph boundaries from sorted batch ----------------
__global__ void graph_bounds(const int* __restrict__ batch, int* __restrict__ gstart) {
  int n = blockIdx.x * 256 + threadIdx.x;
  if (n >= NN) return;
  int v = batch[n];
  int pv = (n == 0) ? -1 : batch[n - 1];
  for (int b = pv + 1; b <= v; b++) gstart[b] = n;
  if (n == NN - 1) for (int b = v + 1; b <= 32; b++) gstart[b] = NN;
}

// ---------------- exact k-NN within cutoff (one wave per node) ----------------
__global__ __launch_bounds__(256) void neigh_kernel(
    const float* __restrict__ pos, const int* __restrict__ batch,
    const int* __restrict__ gstart, int* __restrict__ idx, int* __restrict__ cnt,
    int Ksel, float cut2) {
  const int lane = threadIdx.x & 63;
  const int bid = XCD_SWZ((int)blockIdx.x, (int)gridDim.x);
  const int i = bid * 4 + (threadIdx.x >> 6);
  const int b = batch[i];
  const int gs = gstart[b];
  const int ge = gstart[b + 1];
  const int span = ge - gs;
  const float px = pos[i * 3 + 0], py = pos[i * 3 + 1], pz = pos[i * 3 + 2];
  u64 key[16];
#pragma unroll
  for (int tq = 0; tq < 16; tq++) {
    u64 k64 = ~0ull;
    if (tq * 64 < span) {
      int j = gs + tq * 64 + lane;
      if (j < ge && j != i) {
        float dx = px - pos[j * 3 + 0];
        float dy = py - pos[j * 3 + 1];
        float dz = pz - pos[j * 3 + 2];
        float d2 = dx * dx + dy * dy + dz * dz;
        if (d2 <= cut2) k64 = (((u64)__float_as_uint(d2)) << 32) | (u32)j;
      }
    }
    key[tq] = k64;
  }
  u64 thresh = 0;
  int myidx = i;
  int mycnt = 0;
  for (int s = 0; s < Ksel; s++) {
    u64 m = ~0ull;
#pragma unroll
    for (int tq = 0; tq < 16; tq++) {
      if (tq * 64 < span) {
        u64 kk = key[tq];
        if (kk >= thresh && kk < m) m = kk;
      }
    }
    for (int off = 32; off > 0; off >>= 1) {
      u64 o = __shfl_down(m, (unsigned)off, 64);
      if (o < m) m = o;
    }
    m = __shfl(m, 0, 64);
    if (m != ~0ull) {
      if (lane == s) myidx = (int)(m & 0xffffffffu);
      mycnt++;
      thresh = m + 1;
    } else break;
  }
  if (lane < Ksel) idx[i * Ksel + lane] = myidx;
  if (lane == 0) cnt[i] = mycnt;
}

// ---------------- hpart: hpart[n][o] = h[n] . ew1[0:128,o] + eb1[o] ----------
__global__ __launch_bounds__(256) void hpart_kernel(
    const float* __restrict__ h, const float* __restrict__ ew1,
    const float* __restrict__ eb1, float* __restrict__ hpart) {
  __shared__ float ht[2][HD];
  const int t = threadIdx.x;
  const int bid = XCD_SWZ((int)blockIdx.x, (int)gridDim.x);
  const int n0 = bid * 2;
  const int nd = t >> 7, oo = t & 127;
  ht[nd][oo] = h[(size_t)(n0 + nd) * HD + oo];
  __syncthreads();
  float a = 0.f, b = 0.f;
#pragma unroll 8
  for (int f = 0; f < 64; f++) a = fmaf(ht[nd][f], ew1[(size_t)f * HD + oo], a);
#pragma unroll 8
  for (int f = 64; f < 128; f++) b = fmaf(ht[nd][f], ew1[(size_t)f * HD + oo], b);
  hpart[(size_t)(n0 + nd) * HD + oo] = a + b + eb1[oo];
}

// ------- fused node MLP (layer l) + hpart (layer l+1), 2 nodes/block -------
__global__ __launch_bounds__(256) void node_hpart_kernel(
    const float* __restrict__ h_in, const float* __restrict__ msum,
    const float* __restrict__ nw1, const float* __restrict__ nb1,
    const float* __restrict__ nw2, const float* __restrict__ nb2,
    const float* __restrict__ ew1n, const float* __restrict__ eb1n,
    float* __restrict__ h_out, float* __restrict__ hpart, int do_hpart) {
  __shared__ float ht[2][HD], mt[2][HD], ut[2][HD];
  const int t = threadIdx.x;
  const int bid = XCD_SWZ((int)blockIdx.x, (int)gridDim.x);
  const int n0 = bid * 2;
  const int nd = t >> 7, oo = t & 127;
  ht[nd][oo] = h_in[(size_t)(n0 + nd) * HD + oo];
  mt[nd][oo] = msum[(size_t)(n0 + nd) * HD + oo];
  __syncthreads();
  float p1 = 0.f, p2 = 0.f;
#pragma unroll 8
  for (int f = 0; f < 128; f++) p1 = fmaf(ht[nd][f], nw1[(size_t)f * HD + oo], p1);
#pragma unroll 8
  for (int f = 0; f < 128; f++) p2 = fmaf(mt[nd][f], nw1[(size_t)(128 + f) * HD + oo], p2);
  ut[nd][oo] = silu_f(p1 + p2 + nb1[oo]);
  __syncthreads();
  float q1 = 0.f, q2 = 0.f;
#pragma unroll 8
  for (int f = 0; f < 64; f++) q1 = fmaf(ut[nd][f], nw2[(size_t)f * HD + oo], q1);
#pragma unroll 8
  for (int f = 64; f < 128; f++) q2 = fmaf(ut[nd][f], nw2[(size_t)f * HD + oo], q2);
  const float ho = ht[nd][oo] + q1 + q2 + nb2[oo];
  h_out[(size_t)(n0 + nd) * HD + oo] = ho;
  if (do_hpart) {
    // mt fully consumed (p2 loop) before the ut barrier; no reader since.
    mt[nd][oo] = ho;
    __syncthreads();
    float a = 0.f, b = 0.f;
#pragma unroll 8
    for (int f = 0; f < 64; f++) a = fmaf(mt[nd][f], ew1n[(size_t)f * HD + oo], a);
#pragma unroll 8
    for (int f = 64; f < 128; f++) b = fmaf(mt[nd][f], ew1n[(size_t)f * HD + oo], b);
    hpart[(size_t)(n0 + nd) * HD + oo] = a + b + eb1n[oo];
  }
}

// ---------------- edge kernel: 256 thr / 4 waves / 2 nodes ----------------
// Round-7 edge kernel + XCD swizzle (block permutation only; bit-identical).
__global__ __launch_bounds__(256, 4) void egnn_edge(
    const float* __restrict__ h_in, const float* __restrict__ pos_in,
    float* __restrict__ pos_out,
    const int* __restrict__ idx, const int* __restrict__ cnt,
    const float* __restrict__ hpart, const float* __restrict__ ew1d2,
    const float* __restrict__ eb2, const float* __restrict__ cb1,
    const float* __restrict__ cw2,
    float* __restrict__ msum, const u16* __restrict__ wbp) {
  __shared__ __align__(16) u32 xp[64 * XLD];
  __shared__ float hp_s[2][HD];
  __shared__ float rel_s[3][64], d2_s[64], mf_s[64], ce_s[64];
  __shared__ float ce_red[64][9];
  __shared__ int idx_s[64], cn_s[2];

  const int t = threadIdx.x;
  const int bid = XCD_SWZ((int)blockIdx.x, (int)gridDim.x);
  const int i0 = bid * 2;
  const int lane = t & 63;
  const int w = __builtin_amdgcn_readfirstlane(t >> 6);  // 0..3
  const int l16 = lane & 15, q = lane >> 4;

  if (t < 64) idx_s[t] = idx[(size_t)(i0 + (t >> 5)) * KE + (t & 31)];
  else if (t < 66) cn_s[t - 64] = cnt[i0 + (t - 64)];
  __syncthreads();
  const int nt0 = __builtin_amdgcn_readfirstlane((cn_s[0] + 15) >> 4);
  const int nt1 = __builtin_amdgcn_readfirstlane((cn_s[1] + 15) >> 4);
#define LIVE(Et) (((Et) < 2) ? ((Et) < nt0) : ((Et) - 2 < nt1))

  if (t < 64) {
    const int nd = t >> 5, ic = i0 + nd;
    const int j = idx_s[t];
    const float rx = pos_in[ic * 3 + 0] - pos_in[j * 3 + 0];
    const float ry = pos_in[ic * 3 + 1] - pos_in[j * 3 + 1];
    const float rz = pos_in[ic * 3 + 2] - pos_in[j * 3 + 2];
    rel_s[0][t] = rx; rel_s[1][t] = ry; rel_s[2][t] = rz;
    d2_s[t] = rx * rx + ry * ry + rz * rz;
    mf_s[t] = ((t & 31) < cn_s[nd]) ? 1.0f : 0.0f;
  }
  {
    const int nd = t >> 7, f = t & 127;
    hp_s[nd][f] = hpart[(size_t)(i0 + nd) * HD + f];
  }
  // gather hj -> hi/lo planes; thread covers 32 f of one e row
  {
    const int e = t & 63;
    const int myEt = e >> 4;
    const bool glive = (myEt < 2) ? (myEt < nt0) : (myEt - 2 < nt1);
    if (glive) {
      const int j = idx_s[e];
      const int f0 = (t >> 6) * 32;
      const float4* src = (const float4*)(h_in + (size_t)j * HD + f0);
#pragma unroll
      for (int half = 0; half < 2; half++) {
        float4 v0 = src[half * 4 + 0], v1 = src[half * 4 + 1];
        float4 v2 = src[half * 4 + 2], v3 = src[half * 4 + 3];
        u32 H0, L0, H1, L1, H2, L2, H3, L3, H4, L4, H5, L5, H6, L6, H7, L7;
        packplane(v0.x, v0.y, H0, L0); packplane(v0.z, v0.w, H1, L1);
        packplane(v1.x, v1.y, H2, L2); packplane(v1.z, v1.w, H3, L3);
        packplane(v2.x, v2.y, H4, L4); packplane(v2.z, v2.w, H5, L5);
        packplane(v3.x, v3.y, H6, L6); packplane(v3.z, v3.w, H7, L7);
        u32* dh = xp + e * XLD + ((f0 + half * 16) >> 1);
        uint4 a; a.x = H0; a.y = H1; a.z = H2; a.w = H3;
        uint4 b; b.x = H4; b.y = H5; b.z = H6; b.w = H7;
        uint4 c; c.x = L0; c.y = L1; c.z = L2; c.w = L3;
        uint4 d; d.x = L4; d.y = L5; d.z = L6; d.w = L7;
        *(uint4*)(dh) = a;        *(uint4*)(dh + 4) = b;
        *(uint4*)(dh + PLOF) = c; *(uint4*)(dh + PLOF + 4) = d;
      }
    }
  }
  __syncthreads();

  // macro: one full 3-term dual-tile MFMA pass over live e-tiles
#define MFMA_PASS(WPBASE, accA, accB)                                          \
  {                                                                            \
    f32x4 z = {0.f, 0.f, 0.f, 0.f};                                            \
    accA[0] = z; accA[1] = z; accA[2] = z; accA[3] = z;                        \
    accB[0] = z; accB[1] = z; accB[2] = z; accB[3] = z;                        \
    bf16x8 whA[4], wlA[4], whB[4], wlB[4];                                     \
    _Pragma("unroll")                                                          \
    for (int kt = 0; kt < 4; kt++) {                                           \
      const u16* wa = (WPBASE) + (size_t)((kt * 8 + w) * 64 + lane) * 16;      \
      whA[kt] = *(const bf16x8*)(wa); wlA[kt] = *(const bf16x8*)(wa + 8);      \
      const u16* wb = (WPBASE) + (size_t)((kt * 8 + w + 4) * 64 + lane) * 16;  \
      whB[kt] = *(const bf16x8*)(wb); wlB[kt] = *(const bf16x8*)(wb + 8);      \
    }                                                                          \
    _Pragma("unroll")                                                          \
    for (int Et = 0; Et < 4; Et++) {                                           \
      if (LIVE(Et)) {                                                          \
        _Pragma("unroll")                                                      \
        for (int kt = 0; kt < 4; kt++) {                                       \
          const u32* xr = xp + (Et * 16 + l16) * XLD + kt * 16 + q * 4;        \
          bf16x8 xh = *(const bf16x8*)(xr);                                    \
          bf16x8 xl = *(const bf16x8*)(xr + PLOF);                             \
          accA[Et] = __builtin_amdgcn_mfma_f32_16x16x32_bf16(whA[kt], xl, accA[Et], 0, 0, 0); \
          accA[Et] = __builtin_amdgcn_mfma_f32_16x16x32_bf16(wlA[kt], xh, accA[Et], 0, 0, 0); \
          accA[Et] = __builtin_amdgcn_mfma_f32_16x16x32_bf16(whA[kt], xh, accA[Et], 0, 0, 0); \
          accB[Et] = __builtin_amdgcn_mfma_f32_16x16x32_bf16(whB[kt], xl, accB[Et], 0, 0, 0); \
          accB[Et] = __builtin_amdgcn_mfma_f32_16x16x32_bf16(wlB[kt], xh, accB[Et], 0, 0, 0); \
          accB[Et] = __builtin_amdgcn_mfma_f32_16x16x32_bf16(whB[kt], xh, accB[Et], 0, 0, 0); \
        }                                                                      \
      }                                                                        \
    }                                                                          \
  }

  // ---- stage B ----
  {
    f32x4 accA[4], accB[4];
    MFMA_PASS(wbp, accA, accB)
    __syncthreads();  // all plane reads done before in-place overwrite
#define EPIB(ACC, OT)                                                          \
    {                                                                          \
      const int o = (OT) * 16 + q * 4;                                         \
      const float4 w24 = *(const float4*)(ew1d2 + o);                          \
      _Pragma("unroll")                                                        \
      for (int Et = 0; Et < 4; Et++) {                                         \
        if (LIVE(Et)) {                                                        \
          const int ee = Et * 16 + l16;                                        \
          const float d2e = d2_s[ee];                                          \
          const float4 hp4 = *(const float4*)(&hp_s[Et >> 1][o]);              \
          float s0 = silu_f(ACC[Et][0] + hp4.x + d2e * w24.x);                 \
          float s1 = silu_f(ACC[Et][1] + hp4.y + d2e * w24.y);                 \
          float s2 = silu_f(ACC[Et][2] + hp4.z + d2e * w24.z);                 \
          float s3 = silu_f(ACC[Et][3] + hp4.w + d2e * w24.w);                 \
          u32 H0, L0, H1, L1;                                                  \
          packplane(s0, s1, H0, L0);                                           \
          packplane(s2, s3, H1, L1);                                           \
          u32* dst = xp + ee * XLD + (OT) * 8 + q * 2;                         \
          uint2 hh; hh.x = H0; hh.y = H1;                                      \
          uint2 ll; ll.x = L0; ll.y = L1;                                      \
          *(uint2*)(dst) = hh;                                                 \
          *(uint2*)(dst + PLOF) = ll;                                          \
        }                                                                      \
      }                                                                        \
    }
    EPIB(accA, w)
    EPIB(accB, (w + 4))
#undef EPIB
  }
  __syncthreads();

  // ---- stage C (+ msum) ----
  {
    f32x4 accA[4], accB[4];
    MFMA_PASS(wbp + 32768, accA, accB)
    __syncthreads();  // all reads done before in-place overwrite
    float msA0[4] = {0.f, 0.f, 0.f, 0.f}, msA1[4] = {0.f, 0.f, 0.f, 0.f};
    float msB0[4] = {0.f, 0.f, 0.f, 0.f}, msB1[4] = {0.f, 0.f, 0.f, 0.f};
#define EPIC(ACC, OT, MS0, MS1)                                                \
    {                                                                          \
      const int o = (OT) * 16 + q * 4;                                         \
      const float4 eb4 = *(const float4*)(eb2 + o);                            \
      _Pragma("unroll")                                                        \
      for (int Et = 0; Et < 4; Et++) {                                         \
        if (LIVE(Et)) {                                                        \
          const int ee = Et * 16 + l16;                                        \
          const float mfv = mf_s[ee];                                          \
          float m0 = (mfv != 0.f) ? silu_f(ACC[Et][0] + eb4.x) : 0.f;          \
          float m1 = (mfv != 0.f) ? silu_f(ACC[Et][1] + eb4.y) : 0.f;          \
          float m2 = (mfv != 0.f) ? silu_f(ACC[Et][2] + eb4.z) : 0.f;          \
          float m3 = (mfv != 0.f) ? silu_f(ACC[Et][3] + eb4.w) : 0.f;          \
          if (Et < 2) { MS0[0] += m0; MS0[1] += m1; MS0[2] += m2; MS0[3] += m3; } \
          else        { MS1[0] += m0; MS1[1] += m1; MS1[2] += m2; MS1[3] += m3; } \
          u32 H0, L0, H1, L1;                                                  \
          packplane(m0, m1, H0, L0);                                           \
          packplane(m2, m3, H1, L1);                                           \
          u32* dst = xp + ee * XLD + (OT) * 8 + q * 2;                         \
          uint2 hh; hh.x = H0; hh.y = H1;                                      \
          uint2 ll; ll.x = L0; ll.y = L1;                                      \
          *(uint2*)(dst) = hh;                                                 \
          *(uint2*)(dst + PLOF) = ll;                                          \
        }                                                                      \
      }                                                                        \
    }
    EPIC(accA, w, msA0, msA1)
    EPIC(accB, (w + 4), msB0, msB1)
#undef EPIC
#define RED16(v) v += __shfl_xor(v, 1); v += __shfl_xor(v, 2); \
                 v += __shfl_xor(v, 4); v += __shfl_xor(v, 8);
#pragma unroll
    for (int r = 0; r < 4; r++) { RED16(msA0[r]) RED16(msA1[r]) RED16(msB0[r]) RED16(msB1[r]) }
#undef RED16
    if (l16 == 0) {
      float4 a0; a0.x = msA0[0]; a0.y = msA0[1]; a0.z = msA0[2]; a0.w = msA0[3];
      float4 a1; a1.x = msA1[0]; a1.y = msA1[1]; a1.z = msA1[2]; a1.w = msA1[3];
      float4 b0; b0.x = msB0[0]; b0.y = msB0[1]; b0.z = msB0[2]; b0.w = msB0[3];
      float4 b1; b1.x = msB1[0]; b1.y = msB1[1]; b1.z = msB1[2]; b1.w = msB1[3];
      *(float4*)(msum + (size_t)i0 * HD + w * 16 + q * 4) = a0;
      *(float4*)(msum + (size_t)(i0 + 1) * HD + w * 16 + q * 4) = a1;
      *(float4*)(msum + (size_t)i0 * HD + (w + 4) * 16 + q * 4) = b0;
      *(float4*)(msum + (size_t)(i0 + 1) * HD + (w + 4) * 16 + q * 4) = b1;
    }
  }
  __syncthreads();

  // ---- stage D: coord head ----
  {
    f32x4 accA[4], accB[4];
    MFMA_PASS(wbp + 65536, accA, accB)
#define EPID(ACC, OT)                                                          \
    {                                                                          \
      const int o = (OT) * 16 + q * 4;                                         \
      const float4 cb4 = *(const float4*)(cb1 + o);                            \
      const float4 cw4 = *(const float4*)(cw2 + o);                            \
      _Pragma("unroll")                                                        \
      for (int Et = 0; Et < 4; Et++) {                                         \
        if (LIVE(Et)) {                                                        \
          float p = silu_f(ACC[Et][0] + cb4.x) * cw4.x;                        \
          p = fmaf(silu_f(ACC[Et][1] + cb4.y), cw4.y, p);                      \
          p = fmaf(silu_f(ACC[Et][2] + cb4.z), cw4.z, p);                      \
          p = fmaf(silu_f(ACC[Et][3] + cb4.w), cw4.w, p);                      \
          p += __shfl_xor(p, 16);                                              \
          p += __shfl_xor(p, 32);                                              \
          if (lane < 16) ce_red[Et * 16 + lane][OT] = p;                       \
        }                                                                      \
      }                                                                        \
    }
    EPID(accA, w)
    EPID(accB, (w + 4))
#undef EPID
  }
  __syncthreads();
  if (t < 64) {
    float c = 0.f;
#pragma unroll
    for (int wv = 0; wv < 8; wv++) c += ce_red[t][wv];
    ce_s[t] = (mf_s[t] != 0.f) ? c : 0.f;
  }
  __syncthreads();
  if (t < 6) {
    const int nd = t / 3, ax = t - nd * 3, ic = i0 + nd;
    float s = 0.f;
#pragma unroll
    for (int k = 0; k < 32; k++) s = fmaf(rel_s[ax][nd * 32 + k], ce_s[nd * 32 + k], s);
    const float cntf = fmaxf((float)cn_s[nd], 1.f);
    pos_out[ic * 3 + ax] = pos_in[ic * 3 + ax] + s / cntf;
  }
#undef LIVE
#undef MFMA_PASS
}

// ---------------- final heads (per node) ----------------
__global__ __launch_bounds__(256) void heads_kernel(
    const float* __restrict__ h, const float* __restrict__ pos,
    const float* __restrict__ fw1, const float* __restrict__ fb1,
    const float* __restrict__ fw2, const float* __restrict__ fb2,
    const float* __restrict__ cw1g, const float* __restrict__ cb1g,
    const float* __restrict__ cw2g, const float* __restrict__ cb2g,
    const float* __restrict__ sw, const float* __restrict__ sb,
    const float* __restrict__ iw,
    float* __restrict__ At, float* __restrict__ Bt,
    void* __restrict__ out, const int* __restrict__ flag) {
  __shared__ float hi_s[HD], v1[HD], red_s[256];
  const int i = blockIdx.x, t = threadIdx.x;
  const int fm = *flag;
  if (t < HD) hi_s[t] = h[(size_t)i * HD + t];
  __syncthreads();
  const int o = t & 127, ph = t >> 7;
  // forces MLP1
  {
    float p = 0.f;
#pragma unroll 4
    for (int f = ph * 64; f < ph * 64 + 64; f++) p = fmaf(hi_s[f], fw1[f * HD + o], p);
    red_s[t] = p;
  }
  __syncthreads();
  if (t < HD) v1[t] = tanhf(red_s[t] + red_s[t + 128] + fb1[t]);
  __syncthreads();
  if (t < 3) {
    float p = 0.f;
    for (int f = 0; f < HD; f++) p = fmaf(v1[f], fw2[f * 3 + t], p);
    stout(out, fm, OFF_F + (size_t)i * 3 + t, p + fb2[t]);
  }
  __syncthreads();
  // conformer MLP1
  {
    float p = 0.f;
#pragma unroll 4
    for (int f = ph * 64; f < ph * 64 + 64; f++) p = fmaf(hi_s[f], cw1g[f * HD + o], p);
    red_s[t] = p;
  }
  __syncthreads();
  if (t < HD) v1[t] = fmaxf(red_s[t] + red_s[t + 128] + cb1g[t], 0.f);
  __syncthreads();
  // conformer MLP2
  {
    const int oo = t & 63, pc = t >> 6;
    float p = 0.f;
#pragma unroll 4
    for (int f = pc * 32; f < pc * 32 + 32; f++) p = fmaf(v1[f], cw2g[f * 64 + oo], p);
    red_s[t] = p;
  }
  __syncthreads();
  if (t < 64)
    stout(out, fm, OFF_C + (size_t)i * 64 + t,
          red_s[t] + red_s[t + 64] + red_s[t + 128] + red_s[t + 192] + cb2g[t]);
  __syncthreads();
  // steric
  if (t < HD) red_s[t] = hi_s[t] * sw[t];
  __syncthreads();
  if (t == 0) {
    float p = 0.f;
    for (int f = 0; f < HD; f++) p += red_s[f];
    stout(out, fm, OFF_ST + (size_t)i, p + sb[0]);
  }
  __syncthreads();
  // interaction head per-node dots
  {
    const int g = t >> 5, l = t & 31;
    float p = 0.f;
    if (g < 6) {
      const int tt = g >> 1, half = g & 1;
#pragma unroll
      for (int r2 = 0; r2 < 4; r2++)
        p = fmaf(hi_s[l * 4 + r2], iw[tt * 258 + half * 128 + l * 4 + r2], p);
    }
    red_s[t] = p;
  }
  __syncthreads();
  if (t < 6) {
    float p = 0.f;
    for (int l = 0; l < 32; l++) p += red_s[t * 32 + l];
    const int tt = t >> 1;
    if ((t & 1) == 0) At[tt * NN + i] = p;
    else Bt[tt * NN + i] = p;
  }
  if (t < HD) stout(out, fm, OFF_H + (size_t)i * HD + t, hi_s[t]);
  if (t >= 128 && t < 131) stout(out, fm, OFF_POS + (size_t)i * 3 + (t - 128), pos[i * 3 + (t - 128)]);
}

// ---------------- interaction scores ----------------
__global__ void scores_kernel(const float* __restrict__ pos, const int* __restrict__ idx2,
                              const int* __restrict__ cnt2, const float* __restrict__ At,
                              const float* __restrict__ Bt, const float* __restrict__ iw,
                              const float* __restrict__ ib, void* __restrict__ out,
                              const int* __restrict__ flag) {
  int tid = blockIdx.x * 256 + threadIdx.x;
  if (tid >= 3 * NN * KI) return;
  const int fm = *flag;
  const int tt = tid / (NN * KI);
  const int r = tid % (NN * KI);
  const int n = r / KI;
  const int k = r % KI;
  float v = 0.f;
  if (k < cnt2[n]) {
    int j = idx2[n * KI + k];
    float dx = pos[n * 3 + 0] - pos[j * 3 + 0];
    float dy = pos[n * 3 + 1] - pos[j * 3 + 1];
    float dz = pos[n * 3 + 2] - pos[j * 3 + 2];
    float d2 = dx * dx + dy * dy + dz * dz;
    float dist = sqrtf(d2 + 1e-12f);
    float s = At[tt * NN + n] + Bt[tt * NN + j] + dist * iw[tt * 258 + 256] +
              (dist * 0.1f) * iw[tt * 258 + 257] + ib[tt];
    v = 1.f / (1.f + __expf(-s));
  }
  stout(out, fm, OFF_S + (size_t)tid, v);
}

extern "C" void kernel_launch(void* const* d_in, const int* in_sizes, int n_in,
                              void* d_out, int out_size, void* d_ws, size_t ws_size,
                              hipStream_t stream) {
  (void)in_sizes; (void)n_in; (void)out_size; (void)ws_size;

  float* wsf = (float*)d_ws;
  float* h_a = wsf + 0;             // 524288
  float* pos_a = wsf + 524288;      // 12288
  float* h_b = wsf + 536576;        // 524288
  float* pos_b = wsf + 1060864;     // 12288
  float* At = wsf + 1073152;        // 12288
  float* Bt = wsf + 1085440;        // 12288
  const int W0 = 1097728;

  static const int wcnt[23] = {197376, 768, 98304, 768, 98304, 768, 768,
                               196608, 768, 98304, 768, 16384, 128, 384, 3,
                               774, 3, 16384, 128, 8192, 64, 128, 1};
  int woff[23];
  {
    int o = W0;
    for (int k = 0; k < 23; k++) { woff[k] = o; o += wcnt[k]; }
  }
  const int IOFF = woff[22] + wcnt[22];
  int* ibase = (int*)d_ws;
  int* idx1 = ibase + IOFF;
  int* cnt1 = idx1 + NN * KE;
  int* idx2 = cnt1 + NN;
  int* cnt2 = idx2 + NN * KI;
  int* gstart = cnt2 + NN;
  int* flag = gstart + 33;
  // packed interleaved MFMA weight fragments, 16B-aligned
  int wboff = (int)((flag + 1) - ibase);
  wboff = (wboff + 3) & ~3;
  u16* WBP = (u16*)(ibase + wboff);
  // hpart / msum staging buffers (fp32, NN x HD each)
  float* HPART = wsf + (wboff + 18 * 32768 / 2);
  float* MSUM = HPART + (size_t)NN * HD;

  const float* EW1 = wsf + woff[0];
  const float* EB1 = wsf + woff[1];
  const float* EB2 = wsf + woff[3];
  const float* CB1 = wsf + woff[5];
  const float* CW2 = wsf + woff[6];
  const float* NW1 = wsf + woff[7];
  const float* NB1 = wsf + woff[8];
  const float* NW2 = wsf + woff[9];
  const float* NB2 = wsf + woff[10];
  const float* FW1 = wsf + woff[11];
  const float* FB1 = wsf + woff[12];
  const float* FW2 = wsf + woff[13];
  const float* FB2 = wsf + woff[14];
  const float* IW = wsf + woff[15];
  const float* IB = wsf + woff[16];
  const float* CW1G = wsf + woff[17];
  const float* CB1G = wsf + woff[18];
  const float* CW2G = wsf + woff[19];
  const float* CB2G = wsf + woff[20];
  const float* SW = wsf + woff[21];
  const float* SB = wsf + woff[22];

  probe_dtype<<<1, 256, 0, stream>>>((const u16*)d_in[0], flag);

  CvtTable tab;
  tab.src[0] = d_in[0]; tab.dstoff[0] = 0;       tab.cnt[0] = NN * HD;
  tab.src[1] = d_in[1]; tab.dstoff[1] = 524288;  tab.cnt[1] = NN * 3;
  for (int k = 0; k < 23; k++) {
    tab.src[2 + k] = d_in[3 + k];
    tab.dstoff[2 + k] = woff[k];
    tab.cnt[2 + k] = wcnt[k];
  }
  {
    dim3 g((NN * HD + 255) / 256, 25, 1);
    convert_all<<<g, 256, 0, stream>>>(tab, wsf, flag);
  }
  pack_weights<<<(18 * 32768 + 255) / 256, 256, 0, stream>>>(
      wsf, woff[0], woff[2], woff[4], WBP);

  const int* batch = (const int*)d_in[2];
  graph_bounds<<<NN / 256, 256, 0, stream>>>(batch, gstart);

  const float cut2s[3] = {9.f, 36.f, 100.f};
  float *hin = h_a, *pin = pos_a, *hout = h_b, *pout = pos_b;
  // hpart for layer 0
  hpart_kernel<<<NN / 2, 256, 0, stream>>>(h_a, EW1, EB1, HPART);
  for (int l = 0; l < 6; l++) {
    if ((l & 1) == 0)
      neigh_kernel<<<NN / 4, 256, 0, stream>>>(pin, batch, gstart, idx1, cnt1, KE, cut2s[l >> 1]);
    egnn_edge<<<NN / 2, 256, 0, stream>>>(
        hin, pin, pout, idx1, cnt1, HPART,
        EW1 + (size_t)l * 257 * HD + 256 * HD,
        EB2 + (size_t)l * HD, CB1 + (size_t)l * HD, CW2 + (size_t)l * HD,
        MSUM, WBP + (size_t)l * 3 * 32768);
    const int ln = (l < 5) ? (l + 1) : l;   // last layer's hpart is unused
    node_hpart_kernel<<<NN / 2, 256, 0, stream>>>(
        hin, MSUM,
        NW1 + (size_t)l * 256 * HD, NB1 + (size_t)l * HD,
        NW2 + (size_t)l * HD * HD, NB2 + (size_t)l * HD,
        EW1 + (size_t)ln * 257 * HD, EB1 + (size_t)ln * HD,
        hout, HPART, (l < 5) ? 1 : 0);
    float* th = hin; hin = hout; hout = th;
    float* tp = pin; pin = pout; pout = tp;
  }
  neigh_kernel<<<NN / 4, 256, 0, stream>>>(pin, batch, gstart, idx2, cnt2, KI, 100.f);
  heads_kernel<<<NN, 256, 0, stream>>>(hin, pin, FW1, FB1, FW2, FB2, CW1G, CB1G, CW2G, CB2G,
                                       SW, SB, IW, At, Bt, d_out, flag);
  scores_kernel<<<(3 * NN * KI + 255) / 256, 256, 0, stream>>>(
      pin, idx2, cnt2, At, Bt, IW, IB, d_out, flag);
}

// Round 14
// 784.647 us; speedup vs baseline: 1.4240x; 1.0812x over previous
//
#include <hip/hip_runtime.h>
#include <hip/hip_bf16.h>

#define NN 4096
#define HD 128
#define KE 32
#define KI 20
#define XLD 132   // X LDS row stride in u32 (16B-aligned rows)
#define PLOF 68   // lo-plane column offset within a row (16B-aligned)

// output element offsets
#define OFF_H   0
#define OFF_POS 524288
#define OFF_F   536576
#define OFF_S   548864
#define OFF_C   794624
#define OFF_ST  1056768

// XCD-aware bijective block swizzle (grid divisible by 8): consecutive logical
// blocks land on the SAME XCD -> per-XCD L2 keeps the graph-local h/hpart span
// hot (round 13: edge FETCH_SIZE 12.4MB -> 5.6MB).
#define XCD_SWZ(bid0, nwg) ((((bid0) & 7) * ((nwg) >> 3)) + ((bid0) >> 3))

typedef unsigned short u16;
typedef unsigned int u32;
typedef unsigned long long u64;
typedef __attribute__((ext_vector_type(8))) short bf16x8;   // 8 bf16 (4 VGPR)
typedef __attribute__((ext_vector_type(4))) float f32x4;

__device__ __forceinline__ float b2f(u16 u) {
  union { u32 i; float f; } c; c.i = ((u32)u) << 16; return c.f;
}
__device__ __forceinline__ float silu_f(float x) { return x / (1.f + __expf(-x)); }
__device__ __forceinline__ void stout(void* out, int fp32m, size_t i, float v) {
  if (fp32m) ((float*)out)[i] = v;
  else ((__hip_bfloat16*)out)[i] = __float2bfloat16(v);
}
// RNE float->bf16 bits (reference path, used in pack_weights)
__device__ __forceinline__ u32 f2b(float f) {
  u32 u = __float_as_uint(f);
  return (u + 0x7fffu + ((u >> 16) & 1u)) >> 16;
}
// hi/lo split of two adjacent values -> plane words (H=[b:a] hi, L=[b:a] lo)
__device__ __forceinline__ void packplane(float a, float b, u32& H, u32& L) {
  asm("v_cvt_pk_bf16_f32 %0, %1, %2" : "=v"(H) : "v"(a), "v"(b));
  float hfa = __uint_as_float(H << 16);
  float hfb = __uint_as_float(H & 0xffff0000u);
  asm("v_cvt_pk_bf16_f32 %0, %1, %2" : "=v"(L) : "v"(a - hfa), "v"(b - hfb));
}

// ---------------- dtype probe ----------------
__global__ void probe_dtype(const u16* __restrict__ h, int* __restrict__ flag) {
  if (threadIdx.x == 0) atomicExch(flag, 0);
  __syncthreads();
  int bad = 0;
  for (int i = threadIdx.x; i < 8192; i += 256) {
    float v = b2f(h[i]);
    if (!(v > -1000.f && v < 1000.f)) bad = 1;
  }
  if (bad) atomicOr(flag, 1);
}

// ---------------- convert all float tensors -> fp32 workspace ----------------
struct CvtTable {
  const void* src[25];
  int dstoff[25];
  int cnt[25];
};

__global__ void convert_all(CvtTable tab, float* __restrict__ wsf, const int* __restrict__ flag) {
  const int seg = blockIdx.y;
  const int i = blockIdx.x * 256 + threadIdx.x;
  if (i >= tab.cnt[seg]) return;
  float v;
  if (*flag) v = ((const float*)tab.src[seg])[i];
  else       v = b2f(((const u16*)tab.src[seg])[i]);
  wsf[tab.dstoff[seg] + i] = v;
}

// ------- pack stage weights: interleaved hi/lo MFMA fragments -------
// Layout: [mat 18][kt 4][ot 8][lane 64][16 u16] where [0..8)=hi j, [8..16)=lo j.
__global__ void pack_weights(const float* __restrict__ wsf, int offEW1, int offEW2, int offCW1,
                             u16* __restrict__ WBP) {
  int tid = blockIdx.x * 256 + threadIdx.x;
  if (tid >= 18 * 32768) return;
  int m = tid >> 15;
  int rix = tid & 32767;
  int layer = m / 3, s = m % 3;
  const float* src;
  if (s == 0)      src = wsf + offEW1 + (size_t)layer * 257 * HD + 128 * HD;
  else if (s == 1) src = wsf + offEW2 + (size_t)layer * HD * HD;
  else             src = wsf + offCW1 + (size_t)layer * HD * HD;
  int jh = rix & 15, lane = (rix >> 4) & 63, ot = (rix >> 10) & 7, kt = rix >> 13;
  int j = jh & 7;
  int f = kt * 32 + (lane >> 4) * 8 + j;
  int o = ot * 16 + (lane & 15);
  float v = src[f * HD + o];
  u32 hb = f2b(v);
  float hf = __uint_as_float(hb << 16);
  u32 lb = f2b(v - hf);
  WBP[tid] = (jh < 8) ? (u16)hb : (u16)lb;
}

// ---------------- graph boundaries from sorted batch ----------------
__global__ void graph_bounds(const int* __restrict__ batch, int* __restrict__ gstart) {
  int n = blockIdx.x * 256 + threadIdx.x;
  if (n >= NN) return;
  int v = batch[n];
  int pv = (n == 0) ? -1 : batch[n - 1];
  for (int b = pv + 1; b <= v; b++) gstart[b] = n;
  if (n == NN - 1) for (int b = v + 1; b <= 32; b++) gstart[b] = NN;
}

// ---------------- exact k-NN within cutoff (one wave per node) ----------------
__global__ __launch_bounds__(256) void neigh_kernel(
    const float* __restrict__ pos, const int* __restrict__ batch,
    const int* __restrict__ gstart, int* __restrict__ idx, int* __restrict__ cnt,
    int Ksel, float cut2) {
  const int lane = threadIdx.x & 63;
  const int bid = XCD_SWZ((int)blockIdx.x, (int)gridDim.x);
  const int i = bid * 4 + (threadIdx.x >> 6);
  const int b = batch[i];
  const int gs = gstart[b];
  const int ge = gstart[b + 1];
  const int span = ge - gs;
  const float px = pos[i * 3 + 0], py = pos[i * 3 + 1], pz = pos[i * 3 + 2];
  u64 key[16];
#pragma unroll
  for (int tq = 0; tq < 16; tq++) {
    u64 k64 = ~0ull;
    if (tq * 64 < span) {
      int j = gs + tq * 64 + lane;
      if (j < ge && j != i) {
        float dx = px - pos[j * 3 + 0];
        float dy = py - pos[j * 3 + 1];
        float dz = pz - pos[j * 3 + 2];
        float d2 = dx * dx + dy * dy + dz * dz;
        if (d2 <= cut2) k64 = (((u64)__float_as_uint(d2)) << 32) | (u32)j;
      }
    }
    key[tq] = k64;
  }
  u64 thresh = 0;
  int myidx = i;
  int mycnt = 0;
  for (int s = 0; s < Ksel; s++) {
    u64 m = ~0ull;
#pragma unroll
    for (int tq = 0; tq < 16; tq++) {
      if (tq * 64 < span) {
        u64 kk = key[tq];
        if (kk >= thresh && kk < m) m = kk;
      }
    }
    for (int off = 32; off > 0; off >>= 1) {
      u64 o = __shfl_down(m, (unsigned)off, 64);
      if (o < m) m = o;
    }
    m = __shfl(m, 0, 64);
    if (m != ~0ull) {
      if (lane == s) myidx = (int)(m & 0xffffffffu);
      mycnt++;
      thresh = m + 1;
    } else break;
  }
  if (lane < Ksel) idx[i * Ksel + lane] = myidx;
  if (lane == 0) cnt[i] = mycnt;
}

// ---------------- hpart: hpart[n][o] = h[n] . ew1[0:128,o] + eb1[o] ----------
__global__ __launch_bounds__(256) void hpart_kernel(
    const float* __restrict__ h, const float* __restrict__ ew1,
    const float* __restrict__ eb1, float* __restrict__ hpart) {
  __shared__ float ht[2][HD];
  const int t = threadIdx.x;
  const int bid = XCD_SWZ((int)blockIdx.x, (int)gridDim.x);
  const int n0 = bid * 2;
  const int nd = t >> 7, oo = t & 127;
  ht[nd][oo] = h[(size_t)(n0 + nd) * HD + oo];
  __syncthreads();
  float a = 0.f, b = 0.f;
#pragma unroll 8
  for (int f = 0; f < 64; f++) a = fmaf(ht[nd][f], ew1[(size_t)f * HD + oo], a);
#pragma unroll 8
  for (int f = 64; f < 128; f++) b = fmaf(ht[nd][f], ew1[(size_t)f * HD + oo], b);
  hpart[(size_t)(n0 + nd) * HD + oo] = a + b + eb1[oo];
}

// ------- fused node MLP (layer l) + hpart (layer l+1), 4 nodes/block -------
// Thread (g=t>>7, oo=t&127) computes output oo for nodes {g, g+2}: each weight
// load feeds 2 fmaf, halving per-node L2 weight traffic (round-13 analysis:
// node_hpart was L2-BW-bound on weight re-reads, ~800MB/dispatch at 2 nodes/blk)
// and doubling ILP. Per-node fp chains verbatim -> bit-identical output.
__global__ __launch_bounds__(256) void node_hpart_kernel(
    const float* __restrict__ h_in, const float* __restrict__ msum,
    const float* __restrict__ nw1, const float* __restrict__ nb1,
    const float* __restrict__ nw2, const float* __restrict__ nb2,
    const float* __restrict__ ew1n, const float* __restrict__ eb1n,
    float* __restrict__ h_out, float* __restrict__ hpart, int do_hpart) {
  __shared__ float ht[4][HD], mt[4][HD], ut[4][HD];
  const int t = threadIdx.x;
  const int bid = XCD_SWZ((int)blockIdx.x, (int)gridDim.x);
  const int n0 = bid * 4;
  const int g = t >> 7, oo = t & 127;  // g in {0,1}; thread owns nodes g, g+2
  const int na = g, nb = g + 2;
  ht[na][oo] = h_in[(size_t)(n0 + na) * HD + oo];
  ht[nb][oo] = h_in[(size_t)(n0 + nb) * HD + oo];
  mt[na][oo] = msum[(size_t)(n0 + na) * HD + oo];
  mt[nb][oo] = msum[(size_t)(n0 + nb) * HD + oo];
  __syncthreads();
  float p1a = 0.f, p1b = 0.f, p2a = 0.f, p2b = 0.f;
#pragma unroll 8
  for (int f = 0; f < 128; f++) {
    const float wv = nw1[(size_t)f * HD + oo];
    p1a = fmaf(ht[na][f], wv, p1a);
    p1b = fmaf(ht[nb][f], wv, p1b);
  }
#pragma unroll 8
  for (int f = 0; f < 128; f++) {
    const float wv = nw1[(size_t)(128 + f) * HD + oo];
    p2a = fmaf(mt[na][f], wv, p2a);
    p2b = fmaf(mt[nb][f], wv, p2b);
  }
  ut[na][oo] = silu_f(p1a + p2a + nb1[oo]);
  ut[nb][oo] = silu_f(p1b + p2b + nb1[oo]);
  __syncthreads();
  float q1a = 0.f, q1b = 0.f, q2a = 0.f, q2b = 0.f;
#pragma unroll 8
  for (int f = 0; f < 64; f++) {
    const float wv = nw2[(size_t)f * HD + oo];
    q1a = fmaf(ut[na][f], wv, q1a);
    q1b = fmaf(ut[nb][f], wv, q1b);
  }
#pragma unroll 8
  for (int f = 64; f < 128; f++) {
    const float wv = nw2[(size_t)f * HD + oo];
    q2a = fmaf(ut[na][f], wv, q2a);
    q2b = fmaf(ut[nb][f], wv, q2b);
  }
  const float hoa = ht[na][oo] + q1a + q2a + nb2[oo];
  const float hob = ht[nb][oo] + q1b + q2b + nb2[oo];
  h_out[(size_t)(n0 + na) * HD + oo] = hoa;
  h_out[(size_t)(n0 + nb) * HD + oo] = hob;
  if (do_hpart) {
    // mt fully consumed (p2 loop) before the ut barrier; no reader since.
    mt[na][oo] = hoa;
    mt[nb][oo] = hob;
    __syncthreads();
    float aa = 0.f, ab = 0.f, ba = 0.f, bb = 0.f;
#pragma unroll 8
    for (int f = 0; f < 64; f++) {
      const float wv = ew1n[(size_t)f * HD + oo];
      aa = fmaf(mt[na][f], wv, aa);
      ab = fmaf(mt[nb][f], wv, ab);
    }
#pragma unroll 8
    for (int f = 64; f < 128; f++) {
      const float wv = ew1n[(size_t)f * HD + oo];
      ba = fmaf(mt[na][f], wv, ba);
      bb = fmaf(mt[nb][f], wv, bb);
    }
    hpart[(size_t)(n0 + na) * HD + oo] = aa + ba + eb1n[oo];
    hpart[(size_t)(n0 + nb) * HD + oo] = ab + bb + eb1n[oo];
  }
}

// ---------------- edge kernel: 256 thr / 4 waves / 2 nodes ----------------
// Round-13 edge kernel, byte-identical (69.4 us dense, 64 VGPR, no spill).
__global__ __launch_bounds__(256, 4) void egnn_edge(
    const float* __restrict__ h_in, const float* __restrict__ pos_in,
    float* __restrict__ pos_out,
    const int* __restrict__ idx, const int* __restrict__ cnt,
    const float* __restrict__ hpart, const float* __restrict__ ew1d2,
    const float* __restrict__ eb2, const float* __restrict__ cb1,
    const float* __restrict__ cw2,
    float* __restrict__ msum, const u16* __restrict__ wbp) {
  __shared__ __align__(16) u32 xp[64 * XLD];
  __shared__ float hp_s[2][HD];
  __shared__ float rel_s[3][64], d2_s[64], mf_s[64], ce_s[64];
  __shared__ float ce_red[64][9];
  __shared__ int idx_s[64], cn_s[2];

  const int t = threadIdx.x;
  const int bid = XCD_SWZ((int)blockIdx.x, (int)gridDim.x);
  const int i0 = bid * 2;
  const int lane = t & 63;
  const int w = __builtin_amdgcn_readfirstlane(t >> 6);  // 0..3
  const int l16 = lane & 15, q = lane >> 4;

  if (t < 64) idx_s[t] = idx[(size_t)(i0 + (t >> 5)) * KE + (t & 31)];
  else if (t < 66) cn_s[t - 64] = cnt[i0 + (t - 64)];
  __syncthreads();
  const int nt0 = __builtin_amdgcn_readfirstlane((cn_s[0] + 15) >> 4);
  const int nt1 = __builtin_amdgcn_readfirstlane((cn_s[1] + 15) >> 4);
#define LIVE(Et) (((Et) < 2) ? ((Et) < nt0) : ((Et) - 2 < nt1))

  if (t < 64) {
    const int nd = t >> 5, ic = i0 + nd;
    const int j = idx_s[t];
    const float rx = pos_in[ic * 3 + 0] - pos_in[j * 3 + 0];
    const float ry = pos_in[ic * 3 + 1] - pos_in[j * 3 + 1];
    const float rz = pos_in[ic * 3 + 2] - pos_in[j * 3 + 2];
    rel_s[0][t] = rx; rel_s[1][t] = ry; rel_s[2][t] = rz;
    d2_s[t] = rx * rx + ry * ry + rz * rz;
    mf_s[t] = ((t & 31) < cn_s[nd]) ? 1.0f : 0.0f;
  }
  {
    const int nd = t >> 7, f = t & 127;
    hp_s[nd][f] = hpart[(size_t)(i0 + nd) * HD + f];
  }
  // gather hj -> hi/lo planes; thread covers 32 f of one e row
  {
    const int e = t & 63;
    const int myEt = e >> 4;
    const bool glive = (myEt < 2) ? (myEt < nt0) : (myEt - 2 < nt1);
    if (glive) {
      const int j = idx_s[e];
      const int f0 = (t >> 6) * 32;
      const float4* src = (const float4*)(h_in + (size_t)j * HD + f0);
#pragma unroll
      for (int half = 0; half < 2; half++) {
        float4 v0 = src[half * 4 + 0], v1 = src[half * 4 + 1];
        float4 v2 = src[half * 4 + 2], v3 = src[half * 4 + 3];
        u32 H0, L0, H1, L1, H2, L2, H3, L3, H4, L4, H5, L5, H6, L6, H7, L7;
        packplane(v0.x, v0.y, H0, L0); packplane(v0.z, v0.w, H1, L1);
        packplane(v1.x, v1.y, H2, L2); packplane(v1.z, v1.w, H3, L3);
        packplane(v2.x, v2.y, H4, L4); packplane(v2.z, v2.w, H5, L5);
        packplane(v3.x, v3.y, H6, L6); packplane(v3.z, v3.w, H7, L7);
        u32* dh = xp + e * XLD + ((f0 + half * 16) >> 1);
        uint4 a; a.x = H0; a.y = H1; a.z = H2; a.w = H3;
        uint4 b; b.x = H4; b.y = H5; b.z = H6; b.w = H7;
        uint4 c; c.x = L0; c.y = L1; c.z = L2; c.w = L3;
        uint4 d; d.x = L4; d.y = L5; d.z = L6; d.w = L7;
        *(uint4*)(dh) = a;        *(uint4*)(dh + 4) = b;
        *(uint4*)(dh + PLOF) = c; *(uint4*)(dh + PLOF + 4) = d;
      }
    }
  }
  __syncthreads();

  // macro: one full 3-term dual-tile MFMA pass over live e-tiles
#define MFMA_PASS(WPBASE, accA, accB)                                          \
  {                                                                            \
    f32x4 z = {0.f, 0.f, 0.f, 0.f};                                            \
    accA[0] = z; accA[1] = z; accA[2] = z; accA[3] = z;                        \
    accB[0] = z; accB[1] = z; accB[2] = z; accB[3] = z;                        \
    bf16x8 whA[4], wlA[4], whB[4], wlB[4];                                     \
    _Pragma("unroll")                                                          \
    for (int kt = 0; kt < 4; kt++) {                                           \
      const u16* wa = (WPBASE) + (size_t)((kt * 8 + w) * 64 + lane) * 16;      \
      whA[kt] = *(const bf16x8*)(wa); wlA[kt] = *(const bf16x8*)(wa + 8);      \
      const u16* wb = (WPBASE) + (size_t)((kt * 8 + w + 4) * 64 + lane) * 16;  \
      whB[kt] = *(const bf16x8*)(wb); wlB[kt] = *(const bf16x8*)(wb + 8);      \
    }                                                                          \
    _Pragma("unroll")                                                          \
    for (int Et = 0; Et < 4; Et++) {                                           \
      if (LIVE(Et)) {                                                          \
        _Pragma("unroll")                                                      \
        for (int kt = 0; kt < 4; kt++) {                                       \
          const u32* xr = xp + (Et * 16 + l16) * XLD + kt * 16 + q * 4;        \
          bf16x8 xh = *(const bf16x8*)(xr);                                    \
          bf16x8 xl = *(const bf16x8*)(xr + PLOF);                             \
          accA[Et] = __builtin_amdgcn_mfma_f32_16x16x32_bf16(whA[kt], xl, accA[Et], 0, 0, 0); \
          accA[Et] = __builtin_amdgcn_mfma_f32_16x16x32_bf16(wlA[kt], xh, accA[Et], 0, 0, 0); \
          accA[Et] = __builtin_amdgcn_mfma_f32_16x16x32_bf16(whA[kt], xh, accA[Et], 0, 0, 0); \
          accB[Et] = __builtin_amdgcn_mfma_f32_16x16x32_bf16(whB[kt], xl, accB[Et], 0, 0, 0); \
          accB[Et] = __builtin_amdgcn_mfma_f32_16x16x32_bf16(wlB[kt], xh, accB[Et], 0, 0, 0); \
          accB[Et] = __builtin_amdgcn_mfma_f32_16x16x32_bf16(whB[kt], xh, accB[Et], 0, 0, 0); \
        }                                                                      \
      }                                                                        \
    }                                                                          \
  }

  // ---- stage B ----
  {
    f32x4 accA[4], accB[4];
    MFMA_PASS(wbp, accA, accB)
    __syncthreads();  // all plane reads done before in-place overwrite
#define EPIB(ACC, OT)                                                          \
    {                                                                          \
      const int o = (OT) * 16 + q * 4;                                         \
      const float4 w24 = *(const float4*)(ew1d2 + o);                          \
      _Pragma("unroll")                                                        \
      for (int Et = 0; Et < 4; Et++) {                                         \
        if (LIVE(Et)) {                                                        \
          const int ee = Et * 16 + l16;                                        \
          const float d2e = d2_s[ee];                                          \
          const float4 hp4 = *(const float4*)(&hp_s[Et >> 1][o]);              \
          float s0 = silu_f(ACC[Et][0] + hp4.x + d2e * w24.x);                 \
          float s1 = silu_f(ACC[Et][1] + hp4.y + d2e * w24.y);                 \
          float s2 = silu_f(ACC[Et][2] + hp4.z + d2e * w24.z);                 \
          float s3 = silu_f(ACC[Et][3] + hp4.w + d2e * w24.w);                 \
          u32 H0, L0, H1, L1;                                                  \
          packplane(s0, s1, H0, L0);                                           \
          packplane(s2, s3, H1, L1);                                           \
          u32* dst = xp + ee * XLD + (OT) * 8 + q * 2;                         \
          uint2 hh; hh.x = H0; hh.y = H1;                                      \
          uint2 ll; ll.x = L0; ll.y = L1;                                      \
          *(uint2*)(dst) = hh;                                                 \
          *(uint2*)(dst + PLOF) = ll;                                          \
        }                                                                      \
      }                                                                        \
    }
    EPIB(accA, w)
    EPIB(accB, (w + 4))
#undef EPIB
  }
  __syncthreads();

  // ---- stage C (+ msum) ----
  {
    f32x4 accA[4], accB[4];
    MFMA_PASS(wbp + 32768, accA, accB)
    __syncthreads();  // all reads done before in-place overwrite
    float msA0[4] = {0.f, 0.f, 0.f, 0.f}, msA1[4] = {0.f, 0.f, 0.f, 0.f};
    float msB0[4] = {0.f, 0.f, 0.f, 0.f}, msB1[4] = {0.f, 0.f, 0.f, 0.f};
#define EPIC(ACC, OT, MS0, MS1)                                                \
    {                                                                          \
      const int o = (OT) * 16 + q * 4;                                         \
      const float4 eb4 = *(const float4*)(eb2 + o);                            \
      _Pragma("unroll")                                                        \
      for (int Et = 0; Et < 4; Et++) {                                         \
        if (LIVE(Et)) {                                                        \
          const int ee = Et * 16 + l16;                                        \
          const float mfv = mf_s[ee];                                          \
          float m0 = (mfv != 0.f) ? silu_f(ACC[Et][0] + eb4.x) : 0.f;          \
          float m1 = (mfv != 0.f) ? silu_f(ACC[Et][1] + eb4.y) : 0.f;          \
          float m2 = (mfv != 0.f) ? silu_f(ACC[Et][2] + eb4.z) : 0.f;          \
          float m3 = (mfv != 0.f) ? silu_f(ACC[Et][3] + eb4.w) : 0.f;          \
          if (Et < 2) { MS0[0] += m0; MS0[1] += m1; MS0[2] += m2; MS0[3] += m3; } \
          else        { MS1[0] += m0; MS1[1] += m1; MS1[2] += m2; MS1[3] += m3; } \
          u32 H0, L0, H1, L1;                                                  \
          packplane(m0, m1, H0, L0);                                           \
          packplane(m2, m3, H1, L1);                                           \
          u32* dst = xp + ee * XLD + (OT) * 8 + q * 2;                         \
          uint2 hh; hh.x = H0; hh.y = H1;                                      \
          uint2 ll; ll.x = L0; ll.y = L1;                                      \
          *(uint2*)(dst) = hh;                                                 \
          *(uint2*)(dst + PLOF) = ll;                                          \
        }                                                                      \
      }                                                                        \
    }
    EPIC(accA, w, msA0, msA1)
    EPIC(accB, (w + 4), msB0, msB1)
#undef EPIC
#define RED16(v) v += __shfl_xor(v, 1); v += __shfl_xor(v, 2); \
                 v += __shfl_xor(v, 4); v += __shfl_xor(v, 8);
#pragma unroll
    for (int r = 0; r < 4; r++) { RED16(msA0[r]) RED16(msA1[r]) RED16(msB0[r]) RED16(msB1[r]) }
#undef RED16
    if (l16 == 0) {
      float4 a0; a0.x = msA0[0]; a0.y = msA0[1]; a0.z = msA0[2]; a0.w = msA0[3];
      float4 a1; a1.x = msA1[0]; a1.y = msA1[1]; a1.z = msA1[2]; a1.w = msA1[3];
      float4 b0; b0.x = msB0[0]; b0.y = msB0[1]; b0.z = msB0[2]; b0.w = msB0[3];
      float4 b1; b1.x = msB1[0]; b1.y = msB1[1]; b1.z = msB1[2]; b1.w = msB1[3];
      *(float4*)(msum + (size_t)i0 * HD + w * 16 + q * 4) = a0;
      *(float4*)(msum + (size_t)(i0 + 1) * HD + w * 16 + q * 4) = a1;
      *(float4*)(msum + (size_t)i0 * HD + (w + 4) * 16 + q * 4) = b0;
      *(float4*)(msum + (size_t)(i0 + 1) * HD + (w + 4) * 16 + q * 4) = b1;
    }
  }
  __syncthreads();

  // ---- stage D: coord head ----
  {
    f32x4 accA[4], accB[4];
    MFMA_PASS(wbp + 65536, accA, accB)
#define EPID(ACC, OT)                                                          \
    {                                                                          \
      const int o = (OT) * 16 + q * 4;                                         \
      const float4 cb4 = *(const float4*)(cb1 + o);                            \
      const float4 cw4 = *(const float4*)(cw2 + o);                            \
      _Pragma("unroll")                                                        \
      for (int Et = 0; Et < 4; Et++) {                                         \
        if (LIVE(Et)) {                                                        \
          float p = silu_f(ACC[Et][0] + cb4.x) * cw4.x;                        \
          p = fmaf(silu_f(ACC[Et][1] + cb4.y), cw4.y, p);                      \
          p = fmaf(silu_f(ACC[Et][2] + cb4.z), cw4.z, p);                      \
          p = fmaf(silu_f(ACC[Et][3] + cb4.w), cw4.w, p);                      \
          p += __shfl_xor(p, 16);                                              \
          p += __shfl_xor(p, 32);                                              \
          if (lane < 16) ce_red[Et * 16 + lane][OT] = p;                       \
        }                                                                      \
      }                                                                        \
    }
    EPID(accA, w)
    EPID(accB, (w + 4))
#undef EPID
  }
  __syncthreads();
  if (t < 64) {
    float c = 0.f;
#pragma unroll
    for (int wv = 0; wv < 8; wv++) c += ce_red[t][wv];
    ce_s[t] = (mf_s[t] != 0.f) ? c : 0.f;
  }
  __syncthreads();
  if (t < 6) {
    const int nd = t / 3, ax = t - nd * 3, ic = i0 + nd;
    float s = 0.f;
#pragma unroll
    for (int k = 0; k < 32; k++) s = fmaf(rel_s[ax][nd * 32 + k], ce_s[nd * 32 + k], s);
    const float cntf = fmaxf((float)cn_s[nd], 1.f);
    pos_out[ic * 3 + ax] = pos_in[ic * 3 + ax] + s / cntf;
  }
#undef LIVE
#undef MFMA_PASS
}

// ---------------- final heads (per node) ----------------
__global__ __launch_bounds__(256) void heads_kernel(
    const float* __restrict__ h, const float* __restrict__ pos,
    const float* __restrict__ fw1, const float* __restrict__ fb1,
    const float* __restrict__ fw2, const float* __restrict__ fb2,
    const float* __restrict__ cw1g, const float* __restrict__ cb1g,
    const float* __restrict__ cw2g, const float* __restrict__ cb2g,
    const float* __restrict__ sw, const float* __restrict__ sb,
    const float* __restrict__ iw,
    float* __restrict__ At, float* __restrict__ Bt,
    void* __restrict__ out, const int* __restrict__ flag) {
  __shared__ float hi_s[HD], v1[HD], red_s[256];
  const int i = blockIdx.x, t = threadIdx.x;
  const int fm = *flag;
  if (t < HD) hi_s[t] = h[(size_t)i * HD + t];
  __syncthreads();
  const int o = t & 127, ph = t >> 7;
  // forces MLP1
  {
    float p = 0.f;
#pragma unroll 4
    for (int f = ph * 64; f < ph * 64 + 64; f++) p = fmaf(hi_s[f], fw1[f * HD + o], p);
    red_s[t] = p;
  }
  __syncthreads();
  if (t < HD) v1[t] = tanhf(red_s[t] + red_s[t + 128] + fb1[t]);
  __syncthreads();
  if (t < 3) {
    float p = 0.f;
    for (int f = 0; f < HD; f++) p = fmaf(v1[f], fw2[f * 3 + t], p);
    stout(out, fm, OFF_F + (size_t)i * 3 + t, p + fb2[t]);
  }
  __syncthreads();
  // conformer MLP1
  {
    float p = 0.f;
#pragma unroll 4
    for (int f = ph * 64; f < ph * 64 + 64; f++) p = fmaf(hi_s[f], cw1g[f * HD + o], p);
    red_s[t] = p;
  }
  __syncthreads();
  if (t < HD) v1[t] = fmaxf(red_s[t] + red_s[t + 128] + cb1g[t], 0.f);
  __syncthreads();
  // conformer MLP2
  {
    const int oo = t & 63, pc = t >> 6;
    float p = 0.f;
#pragma unroll 4
    for (int f = pc * 32; f < pc * 32 + 32; f++) p = fmaf(v1[f], cw2g[f * 64 + oo], p);
    red_s[t] = p;
  }
  __syncthreads();
  if (t < 64)
    stout(out, fm, OFF_C + (size_t)i * 64 + t,
          red_s[t] + red_s[t + 64] + red_s[t + 128] + red_s[t + 192] + cb2g[t]);
  __syncthreads();
  // steric
  if (t < HD) red_s[t] = hi_s[t] * sw[t];
  __syncthreads();
  if (t == 0) {
    float p = 0.f;
    for (int f = 0; f < HD; f++) p += red_s[f];
    stout(out, fm, OFF_ST + (size_t)i, p + sb[0]);
  }
  __syncthreads();
  // interaction head per-node dots
  {
    const int g = t >> 5, l = t & 31;
    float p = 0.f;
    if (g < 6) {
      const int tt = g >> 1, half = g & 1;
#pragma unroll
      for (int r2 = 0; r2 < 4; r2++)
        p = fmaf(hi_s[l * 4 + r2], iw[tt * 258 + half * 128 + l * 4 + r2], p);
    }
    red_s[t] = p;
  }
  __syncthreads();
  if (t < 6) {
    float p = 0.f;
    for (int l = 0; l < 32; l++) p += red_s[t * 32 + l];
    const int tt = t >> 1;
    if ((t & 1) == 0) At[tt * NN + i] = p;
    else Bt[tt * NN + i] = p;
  }
  if (t < HD) stout(out, fm, OFF_H + (size_t)i * HD + t, hi_s[t]);
  if (t >= 128 && t < 131) stout(out, fm, OFF_POS + (size_t)i * 3 + (t - 128), pos[i * 3 + (t - 128)]);
}

// ---------------- interaction scores ----------------
__global__ void scores_kernel(const float* __restrict__ pos, const int* __restrict__ idx2,
                              const int* __restrict__ cnt2, const float* __restrict__ At,
                              const float* __restrict__ Bt, const float* __restrict__ iw,
                              const float* __restrict__ ib, void* __restrict__ out,
                              const int* __restrict__ flag) {
  int tid = blockIdx.x * 256 + threadIdx.x;
  if (tid >= 3 * NN * KI) return;
  const int fm = *flag;
  const int tt = tid / (NN * KI);
  const int r = tid % (NN * KI);
  const int n = r / KI;
  const int k = r % KI;
  float v = 0.f;
  if (k < cnt2[n]) {
    int j = idx2[n * KI + k];
    float dx = pos[n * 3 + 0] - pos[j * 3 + 0];
    float dy = pos[n * 3 + 1] - pos[j * 3 + 1];
    float dz = pos[n * 3 + 2] - pos[j * 3 + 2];
    float d2 = dx * dx + dy * dy + dz * dz;
    float dist = sqrtf(d2 + 1e-12f);
    float s = At[tt * NN + n] + Bt[tt * NN + j] + dist * iw[tt * 258 + 256] +
              (dist * 0.1f) * iw[tt * 258 + 257] + ib[tt];
    v = 1.f / (1.f + __expf(-s));
  }
  stout(out, fm, OFF_S + (size_t)tid, v);
}

extern "C" void kernel_launch(void* const* d_in, const int* in_sizes, int n_in,
                              void* d_out, int out_size, void* d_ws, size_t ws_size,
                              hipStream_t stream) {
  (void)in_sizes; (void)n_in; (void)out_size; (void)ws_size;

  float* wsf = (float*)d_ws;
  float* h_a = wsf + 0;             // 524288
  float* pos_a = wsf + 524288;      // 12288
  float* h_b = wsf + 536576;        // 524288
  float* pos_b = wsf + 1060864;     // 12288
  float* At = wsf + 1073152;        // 12288
  float* Bt = wsf + 1085440;        // 12288
  const int W0 = 1097728;

  static const int wcnt[23] = {197376, 768, 98304, 768, 98304, 768, 768,
                               196608, 768, 98304, 768, 16384, 128, 384, 3,
                               774, 3, 16384, 128, 8192, 64, 128, 1};
  int woff[23];
  {
    int o = W0;
    for (int k = 0; k < 23; k++) { woff[k] = o; o += wcnt[k]; }
  }
  const int IOFF = woff[22] + wcnt[22];
  int* ibase = (int*)d_ws;
  int* idx1 = ibase + IOFF;
  int* cnt1 = idx1 + NN * KE;
  int* idx2 = cnt1 + NN;
  int* cnt2 = idx2 + NN * KI;
  int* gstart = cnt2 + NN;
  int* flag = gstart + 33;
  // packed interleaved MFMA weight fragments, 16B-aligned
  int wboff = (int)((flag + 1) - ibase);
  wboff = (wboff + 3) & ~3;
  u16* WBP = (u16*)(ibase + wboff);
  // hpart / msum staging buffers (fp32, NN x HD each)
  float* HPART = wsf + (wboff + 18 * 32768 / 2);
  float* MSUM = HPART + (size_t)NN * HD;

  const float* EW1 = wsf + woff[0];
  const float* EB1 = wsf + woff[1];
  const float* EB2 = wsf + woff[3];
  const float* CB1 = wsf + woff[5];
  const float* CW2 = wsf + woff[6];
  const float* NW1 = wsf + woff[7];
  const float* NB1 = wsf + woff[8];
  const float* NW2 = wsf + woff[9];
  const float* NB2 = wsf + woff[10];
  const float* FW1 = wsf + woff[11];
  const float* FB1 = wsf + woff[12];
  const float* FW2 = wsf + woff[13];
  const float* FB2 = wsf + woff[14];
  const float* IW = wsf + woff[15];
  const float* IB = wsf + woff[16];
  const float* CW1G = wsf + woff[17];
  const float* CB1G = wsf + woff[18];
  const float* CW2G = wsf + woff[19];
  const float* CB2G = wsf + woff[20];
  const float* SW = wsf + woff[21];
  const float* SB = wsf + woff[22];

  probe_dtype<<<1, 256, 0, stream>>>((const u16*)d_in[0], flag);

  CvtTable tab;
  tab.src[0] = d_in[0]; tab.dstoff[0] = 0;       tab.cnt[0] = NN * HD;
  tab.src[1] = d_in[1]; tab.dstoff[1] = 524288;  tab.cnt[1] = NN * 3;
  for (int k = 0; k < 23; k++) {
    tab.src[2 + k] = d_in[3 + k];
    tab.dstoff[2 + k] = woff[k];
    tab.cnt[2 + k] = wcnt[k];
  }
  {
    dim3 g((NN * HD + 255) / 256, 25, 1);
    convert_all<<<g, 256, 0, stream>>>(tab, wsf, flag);
  }
  pack_weights<<<(18 * 32768 + 255) / 256, 256, 0, stream>>>(
      wsf, woff[0], woff[2], woff[4], WBP);

  const int* batch = (const int*)d_in[2];
  graph_bounds<<<NN / 256, 256, 0, stream>>>(batch, gstart);

  const float cut2s[3] = {9.f, 36.f, 100.f};
  float *hin = h_a, *pin = pos_a, *hout = h_b, *pout = pos_b;
  // hpart for layer 0
  hpart_kernel<<<NN / 2, 256, 0, stream>>>(h_a, EW1, EB1, HPART);
  for (int l = 0; l < 6; l++) {
    if ((l & 1) == 0)
      neigh_kernel<<<NN / 4, 256, 0, stream>>>(pin, batch, gstart, idx1, cnt1, KE, cut2s[l >> 1]);
    egnn_edge<<<NN / 2, 256, 0, stream>>>(
        hin, pin, pout, idx1, cnt1, HPART,
        EW1 + (size_t)l * 257 * HD + 256 * HD,
        EB2 + (size_t)l * HD, CB1 + (size_t)l * HD, CW2 + (size_t)l * HD,
        MSUM, WBP + (size_t)l * 3 * 32768);
    const int ln = (l < 5) ? (l + 1) : l;   // last layer's hpart is unused
    node_hpart_kernel<<<NN / 4, 256, 0, stream>>>(
        hin, MSUM,
        NW1 + (size_t)l * 256 * HD, NB1 + (size_t)l * HD,
        NW2 + (size_t)l * HD * HD, NB2 + (size_t)l * HD,
        EW1 + (size_t)ln * 257 * HD, EB1 + (size_t)ln * HD,
        hout, HPART, (l < 5) ? 1 : 0);
    float* th = hin; hin = hout; hout = th;
    float* tp = pin; pin = pout; pout = tp;
  }
  neigh_kernel<<<NN / 4, 256, 0, stream>>>(pin, batch, gstart, idx2, cnt2, KI, 100.f);
  heads_kernel<<<NN, 256, 0, stream>>>(hin, pin, FW1, FB1, FW2, FB2, CW1G, CB1G, CW2G, CB2G,
                                       SW, SB, IW, At, Bt, d_out, flag);
  scores_kernel<<<(3 * NN * KI + 255) / 256, 256, 0, stream>>>(
      pin, idx2, cnt2, At, Bt, IW, IB, d_out, flag);
}

// Round 15
// 745.008 us; speedup vs baseline: 1.4998x; 1.0532x over previous
//
#include <hip/hip_runtime.h>
#include <hip/hip_bf16.h>

#define NN 4096
#define HD 128
#define KE 32
#define KI 20
#define XLD 132   // X LDS row stride in u32 (16B-aligned rows)
#define PLOF 68   // lo-plane column offset within a row (16B-aligned)

// output element offsets
#define OFF_H   0
#define OFF_POS 524288
#define OFF_F   536576
#define OFF_S   548864
#define OFF_C   794624
#define OFF_ST  1056768

// XCD-aware bijective block swizzle (grid divisible by 8): consecutive logical
// blocks land on the SAME XCD -> per-XCD L2 keeps the graph-local h/hpart span
// hot (round 13: edge FETCH_SIZE 12.4MB -> 5.6MB).
#define XCD_SWZ(bid0, nwg) ((((bid0) & 7) * ((nwg) >> 3)) + ((bid0) >> 3))

typedef unsigned short u16;
typedef unsigned int u32;
typedef unsigned long long u64;
typedef __attribute__((ext_vector_type(8))) short bf16x8;   // 8 bf16 (4 VGPR)
typedef __attribute__((ext_vector_type(4))) float f32x4;

__device__ __forceinline__ float b2f(u16 u) {
  union { u32 i; float f; } c; c.i = ((u32)u) << 16; return c.f;
}
// silu via hardware v_rcp_f32 (1 ulp): ~5 VALU vs ~14 for the IEEE divide.
// Perturbation ~1e-7 relative -- 4 orders below the 2^-17 split-GEMM error.
__device__ __forceinline__ float silu_f(float x) {
  return x * __builtin_amdgcn_rcpf(1.f + __expf(-x));
}
__device__ __forceinline__ void stout(void* out, int fp32m, size_t i, float v) {
  if (fp32m) ((float*)out)[i] = v;
  else ((__hip_bfloat16*)out)[i] = __float2bfloat16(v);
}
// RNE float->bf16 bits (reference path, used in pack_weights)
__device__ __forceinline__ u32 f2b(float f) {
  u32 u = __float_as_uint(f);
  return (u + 0x7fffu + ((u >> 16) & 1u)) >> 16;
}
// hi/lo split of two adjacent values -> plane words (H=[b:a] hi, L=[b:a] lo)
__device__ __forceinline__ void packplane(float a, float b, u32& H, u32& L) {
  asm("v_cvt_pk_bf16_f32 %0, %1, %2" : "=v"(H) : "v"(a), "v"(b));
  float hfa = __uint_as_float(H << 16);
  float hfb = __uint_as_float(H & 0xffff0000u);
  asm("v_cvt_pk_bf16_f32 %0, %1, %2" : "=v"(L) : "v"(a - hfa), "v"(b - hfb));
}

// ---------------- dtype probe ----------------
__global__ void probe_dtype(const u16* __restrict__ h, int* __restrict__ flag) {
  if (threadIdx.x == 0) atomicExch(flag, 0);
  __syncthreads();
  int bad = 0;
  for (int i = threadIdx.x; i < 8192; i += 256) {
    float v = b2f(h[i]);
    if (!(v > -1000.f && v < 1000.f)) bad = 1;
  }
  if (bad) atomicOr(flag, 1);
}

// ---------------- convert all float tensors -> fp32 workspace ----------------
struct CvtTable {
  const void* src[25];
  int dstoff[25];
  int cnt[25];
};

__global__ void convert_all(CvtTable tab, float* __restrict__ wsf, const int* __restrict__ flag) {
  const int seg = blockIdx.y;
  const int i = blockIdx.x * 256 + threadIdx.x;
  if (i >= tab.cnt[seg]) return;
  float v;
  if (*flag) v = ((const float*)tab.src[seg])[i];
  else       v = b2f(((const u16*)tab.src[seg])[i]);
  wsf[tab.dstoff[seg] + i] = v;
}

// ------- pack stage weights: interleaved hi/lo MFMA fragments -------
// Layout: [mat 18][kt 4][ot 8][lane 64][16 u16] where [0..8)=hi j, [8..16)=lo j.
__global__ void pack_weights(const float* __restrict__ wsf, int offEW1, int offEW2, int offCW1,
                             u16* __restrict__ WBP) {
  int tid = blockIdx.x * 256 + threadIdx.x;
  if (tid >= 18 * 32768) return;
  int m = tid >> 15;
  int rix = tid & 32767;
  int layer = m / 3, s = m % 3;
  const float* src;
  if (s == 0)      src = wsf + offEW1 + (size_t)layer * 257 * HD + 128 * HD;
  else if (s == 1) src = wsf + offEW2 + (size_t)layer * HD * HD;
  else             src = wsf + offCW1 + (size_t)layer * HD * HD;
  int jh = rix & 15, lane = (rix >> 4) & 63, ot = (rix >> 10) & 7, kt = rix >> 13;
  int j = jh & 7;
  int f = kt * 32 + (lane >> 4) * 8 + j;
  int o = ot * 16 + (lane & 15);
  float v = src[f * HD + o];
  u32 hb = f2b(v);
  float hf = __uint_as_float(hb << 16);
  u32 lb = f2b(v - hf);
  WBP[tid] = (jh < 8) ? (u16)hb : (u16)lb;
}

// ---------------- graph boundaries from sorted batch ----------------
__global__ void graph_bounds(const int* __restrict__ batch, int* __restrict__ gstart) {
  int n = blockIdx.x * 256 + threadIdx.x;
  if (n >= NN) return;
  int v = batch[n];
  int pv = (n == 0) ? -1 : batch[n - 1];
  for (int b = pv + 1; b <= v; b++) gstart[b] = n;
  if (n == NN - 1) for (int b = v + 1; b <= 32; b++) gstart[b] = NN;
}

// ---------------- exact k-NN within cutoff (one wave per node) ----------------
__global__ __launch_bounds__(256) void neigh_kernel(
    const float* __restrict__ pos, const int* __restrict__ batch,
    const int* __restrict__ gstart, int* __restrict__ idx, int* __restrict__ cnt,
    int Ksel, float cut2) {
  const int lane = threadIdx.x & 63;
  const int bid = XCD_SWZ((int)blockIdx.x, (int)gridDim.x);
  const int i = bid * 4 + (threadIdx.x >> 6);
  const int b = batch[i];
  const int gs = gstart[b];
  const int ge = gstart[b + 1];
  const int span = ge - gs;
  const float px = pos[i * 3 + 0], py = pos[i * 3 + 1], pz = pos[i * 3 + 2];
  u64 key[16];
#pragma unroll
  for (int tq = 0; tq < 16; tq++) {
    u64 k64 = ~0ull;
    if (tq * 64 < span) {
      int j = gs + tq * 64 + lane;
      if (j < ge && j != i) {
        float dx = px - pos[j * 3 + 0];
        float dy = py - pos[j * 3 + 1];
        float dz = pz - pos[j * 3 + 2];
        float d2 = dx * dx + dy * dy + dz * dz;
        if (d2 <= cut2) k64 = (((u64)__float_as_uint(d2)) << 32) | (u32)j;
      }
    }
    key[tq] = k64;
  }
  u64 thresh = 0;
  int myidx = i;
  int mycnt = 0;
  for (int s = 0; s < Ksel; s++) {
    u64 m = ~0ull;
#pragma unroll
    for (int tq = 0; tq < 16; tq++) {
      if (tq * 64 < span) {
        u64 kk = key[tq];
        if (kk >= thresh && kk < m) m = kk;
      }
    }
    for (int off = 32; off > 0; off >>= 1) {
      u64 o = __shfl_down(m, (unsigned)off, 64);
      if (o < m) m = o;
    }
    m = __shfl(m, 0, 64);
    if (m != ~0ull) {
      if (lane == s) myidx = (int)(m & 0xffffffffu);
      mycnt++;
      thresh = m + 1;
    } else break;
  }
  if (lane < Ksel) idx[i * Ksel + lane] = myidx;
  if (lane == 0) cnt[i] = mycnt;
}

// ---------------- hpart: hpart[n][o] = h[n] . ew1[0:128,o] + eb1[o] ----------
__global__ __launch_bounds__(256) void hpart_kernel(
    const float* __restrict__ h, const float* __restrict__ ew1,
    const float* __restrict__ eb1, float* __restrict__ hpart) {
  __shared__ float ht[2][HD];
  const int t = threadIdx.x;
  const int bid = XCD_SWZ((int)blockIdx.x, (int)gridDim.x);
  const int n0 = bid * 2;
  const int nd = t >> 7, oo = t & 127;
  ht[nd][oo] = h[(size_t)(n0 + nd) * HD + oo];
  __syncthreads();
  float a = 0.f, b = 0.f;
#pragma unroll 8
  for (int f = 0; f < 64; f++) a = fmaf(ht[nd][f], ew1[(size_t)f * HD + oo], a);
#pragma unroll 8
  for (int f = 64; f < 128; f++) b = fmaf(ht[nd][f], ew1[(size_t)f * HD + oo], b);
  hpart[(size_t)(n0 + nd) * HD + oo] = a + b + eb1[oo];
}

// ------- fused node MLP (layer l) + hpart (layer l+1), 4 nodes/block -------
// Thread (g=t>>7, oo=t&127) computes output oo for nodes {g, g+2}: each weight
// load feeds 2 fmaf, halving per-node L2 weight traffic and doubling ILP.
__global__ __launch_bounds__(256) void node_hpart_kernel(
    const float* __restrict__ h_in, const float* __restrict__ msum,
    const float* __restrict__ nw1, const float* __restrict__ nb1,
    const float* __restrict__ nw2, const float* __restrict__ nb2,
    const float* __restrict__ ew1n, const float* __restrict__ eb1n,
    float* __restrict__ h_out, float* __restrict__ hpart, int do_hpart) {
  __shared__ float ht[4][HD], mt[4][HD], ut[4][HD];
  const int t = threadIdx.x;
  const int bid = XCD_SWZ((int)blockIdx.x, (int)gridDim.x);
  const int n0 = bid * 4;
  const int g = t >> 7, oo = t & 127;  // g in {0,1}; thread owns nodes g, g+2
  const int na = g, nb = g + 2;
  ht[na][oo] = h_in[(size_t)(n0 + na) * HD + oo];
  ht[nb][oo] = h_in[(size_t)(n0 + nb) * HD + oo];
  mt[na][oo] = msum[(size_t)(n0 + na) * HD + oo];
  mt[nb][oo] = msum[(size_t)(n0 + nb) * HD + oo];
  __syncthreads();
  float p1a = 0.f, p1b = 0.f, p2a = 0.f, p2b = 0.f;
#pragma unroll 8
  for (int f = 0; f < 128; f++) {
    const float wv = nw1[(size_t)f * HD + oo];
    p1a = fmaf(ht[na][f], wv, p1a);
    p1b = fmaf(ht[nb][f], wv, p1b);
  }
#pragma unroll 8
  for (int f = 0; f < 128; f++) {
    const float wv = nw1[(size_t)(128 + f) * HD + oo];
    p2a = fmaf(mt[na][f], wv, p2a);
    p2b = fmaf(mt[nb][f], wv, p2b);
  }
  ut[na][oo] = silu_f(p1a + p2a + nb1[oo]);
  ut[nb][oo] = silu_f(p1b + p2b + nb1[oo]);
  __syncthreads();
  float q1a = 0.f, q1b = 0.f, q2a = 0.f, q2b = 0.f;
#pragma unroll 8
  for (int f = 0; f < 64; f++) {
    const float wv = nw2[(size_t)f * HD + oo];
    q1a = fmaf(ut[na][f], wv, q1a);
    q1b = fmaf(ut[nb][f], wv, q1b);
  }
#pragma unroll 8
  for (int f = 64; f < 128; f++) {
    const float wv = nw2[(size_t)f * HD + oo];
    q2a = fmaf(ut[na][f], wv, q2a);
    q2b = fmaf(ut[nb][f], wv, q2b);
  }
  const float hoa = ht[na][oo] + q1a + q2a + nb2[oo];
  const float hob = ht[nb][oo] + q1b + q2b + nb2[oo];
  h_out[(size_t)(n0 + na) * HD + oo] = hoa;
  h_out[(size_t)(n0 + nb) * HD + oo] = hob;
  if (do_hpart) {
    // mt fully consumed (p2 loop) before the ut barrier; no reader since.
    mt[na][oo] = hoa;
    mt[nb][oo] = hob;
    __syncthreads();
    float aa = 0.f, ab = 0.f, ba = 0.f, bb = 0.f;
#pragma unroll 8
    for (int f = 0; f < 64; f++) {
      const float wv = ew1n[(size_t)f * HD + oo];
      aa = fmaf(mt[na][f], wv, aa);
      ab = fmaf(mt[nb][f], wv, ab);
    }
#pragma unroll 8
    for (int f = 64; f < 128; f++) {
      const float wv = ew1n[(size_t)f * HD + oo];
      ba = fmaf(mt[na][f], wv, ba);
      bb = fmaf(mt[nb][f], wv, bb);
    }
    hpart[(size_t)(n0 + na) * HD + oo] = aa + ba + eb1n[oo];
    hpart[(size_t)(n0 + nb) * HD + oo] = ab + bb + eb1n[oo];
  }
}

// ---------------- edge kernel: 256 thr / 4 waves / 2 nodes ----------------
// Round-13 structure; silu now uses hardware rcp (~9 VALU saved per call,
// ~96 calls/thread -> ~25% of the edge VALU stream).
__global__ __launch_bounds__(256, 4) void egnn_edge(
    const float* __restrict__ h_in, const float* __restrict__ pos_in,
    float* __restrict__ pos_out,
    const int* __restrict__ idx, const int* __restrict__ cnt,
    const float* __restrict__ hpart, const float* __restrict__ ew1d2,
    const float* __restrict__ eb2, const float* __restrict__ cb1,
    const float* __restrict__ cw2,
    float* __restrict__ msum, const u16* __restrict__ wbp) {
  __shared__ __align__(16) u32 xp[64 * XLD];
  __shared__ float hp_s[2][HD];
  __shared__ float rel_s[3][64], d2_s[64], mf_s[64], ce_s[64];
  __shared__ float ce_red[64][9];
  __shared__ int idx_s[64], cn_s[2];

  const int t = threadIdx.x;
  const int bid = XCD_SWZ((int)blockIdx.x, (int)gridDim.x);
  const int i0 = bid * 2;
  const int lane = t & 63;
  const int w = __builtin_amdgcn_readfirstlane(t >> 6);  // 0..3
  const int l16 = lane & 15, q = lane >> 4;

  if (t < 64) idx_s[t] = idx[(size_t)(i0 + (t >> 5)) * KE + (t & 31)];
  else if (t < 66) cn_s[t - 64] = cnt[i0 + (t - 64)];
  __syncthreads();
  const int nt0 = __builtin_amdgcn_readfirstlane((cn_s[0] + 15) >> 4);
  const int nt1 = __builtin_amdgcn_readfirstlane((cn_s[1] + 15) >> 4);
#define LIVE(Et) (((Et) < 2) ? ((Et) < nt0) : ((Et) - 2 < nt1))

  if (t < 64) {
    const int nd = t >> 5, ic = i0 + nd;
    const int j = idx_s[t];
    const float rx = pos_in[ic * 3 + 0] - pos_in[j * 3 + 0];
    const float ry = pos_in[ic * 3 + 1] - pos_in[j * 3 + 1];
    const float rz = pos_in[ic * 3 + 2] - pos_in[j * 3 + 2];
    rel_s[0][t] = rx; rel_s[1][t] = ry; rel_s[2][t] = rz;
    d2_s[t] = rx * rx + ry * ry + rz * rz;
    mf_s[t] = ((t & 31) < cn_s[nd]) ? 1.0f : 0.0f;
  }
  {
    const int nd = t >> 7, f = t & 127;
    hp_s[nd][f] = hpart[(size_t)(i0 + nd) * HD + f];
  }
  // gather hj -> hi/lo planes; thread covers 32 f of one e row
  {
    const int e = t & 63;
    const int myEt = e >> 4;
    const bool glive = (myEt < 2) ? (myEt < nt0) : (myEt - 2 < nt1);
    if (glive) {
      const int j = idx_s[e];
      const int f0 = (t >> 6) * 32;
      const float4* src = (const float4*)(h_in + (size_t)j * HD + f0);
#pragma unroll
      for (int half = 0; half < 2; half++) {
        float4 v0 = src[half * 4 + 0], v1 = src[half * 4 + 1];
        float4 v2 = src[half * 4 + 2], v3 = src[half * 4 + 3];
        u32 H0, L0, H1, L1, H2, L2, H3, L3, H4, L4, H5, L5, H6, L6, H7, L7;
        packplane(v0.x, v0.y, H0, L0); packplane(v0.z, v0.w, H1, L1);
        packplane(v1.x, v1.y, H2, L2); packplane(v1.z, v1.w, H3, L3);
        packplane(v2.x, v2.y, H4, L4); packplane(v2.z, v2.w, H5, L5);
        packplane(v3.x, v3.y, H6, L6); packplane(v3.z, v3.w, H7, L7);
        u32* dh = xp + e * XLD + ((f0 + half * 16) >> 1);
        uint4 a; a.x = H0; a.y = H1; a.z = H2; a.w = H3;
        uint4 b; b.x = H4; b.y = H5; b.z = H6; b.w = H7;
        uint4 c; c.x = L0; c.y = L1; c.z = L2; c.w = L3;
        uint4 d; d.x = L4; d.y = L5; d.z = L6; d.w = L7;
        *(uint4*)(dh) = a;        *(uint4*)(dh + 4) = b;
        *(uint4*)(dh + PLOF) = c; *(uint4*)(dh + PLOF + 4) = d;
      }
    }
  }
  __syncthreads();

  // macro: one full 3-term dual-tile MFMA pass over live e-tiles
#define MFMA_PASS(WPBASE, accA, accB)                                          \
  {                                                                            \
    f32x4 z = {0.f, 0.f, 0.f, 0.f};                                            \
    accA[0] = z; accA[1] = z; accA[2] = z; accA[3] = z;                        \
    accB[0] = z; accB[1] = z; accB[2] = z; accB[3] = z;                        \
    bf16x8 whA[4], wlA[4], whB[4], wlB[4];                                     \
    _Pragma("unroll")                                                          \
    for (int kt = 0; kt < 4; kt++) {                                           \
      const u16* wa = (WPBASE) + (size_t)((kt * 8 + w) * 64 + lane) * 16;      \
      whA[kt] = *(const bf16x8*)(wa); wlA[kt] = *(const bf16x8*)(wa + 8);      \
      const u16* wb = (WPBASE) + (size_t)((kt * 8 + w + 4) * 64 + lane) * 16;  \
      whB[kt] = *(const bf16x8*)(wb); wlB[kt] = *(const bf16x8*)(wb + 8);      \
    }                                                                          \
    _Pragma("unroll")                                                          \
    for (int Et = 0; Et < 4; Et++) {                                           \
      if (LIVE(Et)) {                                                          \
        _Pragma("unroll")                                                      \
        for (int kt = 0; kt < 4; kt++) {                                       \
          const u32* xr = xp + (Et * 16 + l16) * XLD + kt * 16 + q * 4;        \
          bf16x8 xh = *(const bf16x8*)(xr);                                    \
          bf16x8 xl = *(const bf16x8*)(xr + PLOF);                             \
          accA[Et] = __builtin_amdgcn_mfma_f32_16x16x32_bf16(whA[kt], xl, accA[Et], 0, 0, 0); \
          accA[Et] = __builtin_amdgcn_mfma_f32_16x16x32_bf16(wlA[kt], xh, accA[Et], 0, 0, 0); \
          accA[Et] = __builtin_amdgcn_mfma_f32_16x16x32_bf16(whA[kt], xh, accA[Et], 0, 0, 0); \
          accB[Et] = __builtin_amdgcn_mfma_f32_16x16x32_bf16(whB[kt], xl, accB[Et], 0, 0, 0); \
          accB[Et] = __builtin_amdgcn_mfma_f32_16x16x32_bf16(wlB[kt], xh, accB[Et], 0, 0, 0); \
          accB[Et] = __builtin_amdgcn_mfma_f32_16x16x32_bf16(whB[kt], xh, accB[Et], 0, 0, 0); \
        }                                                                      \
      }                                                                        \
    }                                                                          \
  }

  // ---- stage B ----
  {
    f32x4 accA[4], accB[4];
    MFMA_PASS(wbp, accA, accB)
    __syncthreads();  // all plane reads done before in-place overwrite
#define EPIB(ACC, OT)                                                          \
    {                                                                          \
      const int o = (OT) * 16 + q * 4;                                         \
      const float4 w24 = *(const float4*)(ew1d2 + o);                          \
      _Pragma("unroll")                                                        \
      for (int Et = 0; Et < 4; Et++) {                                         \
        if (LIVE(Et)) {                                                        \
          const int ee = Et * 16 + l16;                                        \
          const float d2e = d2_s[ee];                                          \
          const float4 hp4 = *(const float4*)(&hp_s[Et >> 1][o]);              \
          float s0 = silu_f(ACC[Et][0] + hp4.x + d2e * w24.x);                 \
          float s1 = silu_f(ACC[Et][1] + hp4.y + d2e * w24.y);                 \
          float s2 = silu_f(ACC[Et][2] + hp4.z + d2e * w24.z);                 \
          float s3 = silu_f(ACC[Et][3] + hp4.w + d2e * w24.w);                 \
          u32 H0, L0, H1, L1;                                                  \
          packplane(s0, s1, H0, L0);                                           \
          packplane(s2, s3, H1, L1);                                           \
          u32* dst = xp + ee * XLD + (OT) * 8 + q * 2;                         \
          uint2 hh; hh.x = H0; hh.y = H1;                                      \
          uint2 ll; ll.x = L0; ll.y = L1;                                      \
          *(uint2*)(dst) = hh;                                                 \
          *(uint2*)(dst + PLOF) = ll;                                          \
        }                                                                      \
      }                                                                        \
    }
    EPIB(accA, w)
    EPIB(accB, (w + 4))
#undef EPIB
  }
  __syncthreads();

  // ---- stage C (+ msum) ----
  {
    f32x4 accA[4], accB[4];
    MFMA_PASS(wbp + 32768, accA, accB)
    __syncthreads();  // all reads done before in-place overwrite
    float msA0[4] = {0.f, 0.f, 0.f, 0.f}, msA1[4] = {0.f, 0.f, 0.f, 0.f};
    float msB0[4] = {0.f, 0.f, 0.f, 0.f}, msB1[4] = {0.f, 0.f, 0.f, 0.f};
#define EPIC(ACC, OT, MS0, MS1)                                                \
    {                                                                          \
      const int o = (OT) * 16 + q * 4;                                         \
      const float4 eb4 = *(const float4*)(eb2 + o);                            \
      _Pragma("unroll")                                                        \
      for (int Et = 0; Et < 4; Et++) {                                         \
        if (LIVE(Et)) {                                                        \
          const int ee = Et * 16 + l16;                                        \
          const float mfv = mf_s[ee];                                          \
          float m0 = (mfv != 0.f) ? silu_f(ACC[Et][0] + eb4.x) : 0.f;          \
          float m1 = (mfv != 0.f) ? silu_f(ACC[Et][1] + eb4.y) : 0.f;          \
          float m2 = (mfv != 0.f) ? silu_f(ACC[Et][2] + eb4.z) : 0.f;          \
          float m3 = (mfv != 0.f) ? silu_f(ACC[Et][3] + eb4.w) : 0.f;          \
          if (Et < 2) { MS0[0] += m0; MS0[1] += m1; MS0[2] += m2; MS0[3] += m3; } \
          else        { MS1[0] += m0; MS1[1] += m1; MS1[2] += m2; MS1[3] += m3; } \
          u32 H0, L0, H1, L1;                                                  \
          packplane(m0, m1, H0, L0);                                           \
          packplane(m2, m3, H1, L1);                                           \
          u32* dst = xp + ee * XLD + (OT) * 8 + q * 2;                         \
          uint2 hh; hh.x = H0; hh.y = H1;                                      \
          uint2 ll; ll.x = L0; ll.y = L1;                                      \
          *(uint2*)(dst) = hh;                                                 \
          *(uint2*)(dst + PLOF) = ll;                                          \
        }                                                                      \
      }                                                                        \
    }
    EPIC(accA, w, msA0, msA1)
    EPIC(accB, (w + 4), msB0, msB1)
#undef EPIC
#define RED16(v) v += __shfl_xor(v, 1); v += __shfl_xor(v, 2); \
                 v += __shfl_xor(v, 4); v += __shfl_xor(v, 8);
#pragma unroll
    for (int r = 0; r < 4; r++) { RED16(msA0[r]) RED16(msA1[r]) RED16(msB0[r]) RED16(msB1[r]) }
#undef RED16
    if (l16 == 0) {
      float4 a0; a0.x = msA0[0]; a0.y = msA0[1]; a0.z = msA0[2]; a0.w = msA0[3];
      float4 a1; a1.x = msA1[0]; a1.y = msA1[1]; a1.z = msA1[2]; a1.w = msA1[3];
      float4 b0; b0.x = msB0[0]; b0.y = msB0[1]; b0.z = msB0[2]; b0.w = msB0[3];
      float4 b1; b1.x = msB1[0]; b1.y = msB1[1]; b1.z = msB1[2]; b1.w = msB1[3];
      *(float4*)(msum + (size_t)i0 * HD + w * 16 + q * 4) = a0;
      *(float4*)(msum + (size_t)(i0 + 1) * HD + w * 16 + q * 4) = a1;
      *(float4*)(msum + (size_t)i0 * HD + (w + 4) * 16 + q * 4) = b0;
      *(float4*)(msum + (size_t)(i0 + 1) * HD + (w + 4) * 16 + q * 4) = b1;
    }
  }
  __syncthreads();

  // ---- stage D: coord head ----
  {
    f32x4 accA[4], accB[4];
    MFMA_PASS(wbp + 65536, accA, accB)
#define EPID(ACC, OT)                                                          \
    {                                                                          \
      const int o = (OT) * 16 + q * 4;                                         \
      const float4 cb4 = *(const float4*)(cb1 + o);                            \
      const float4 cw4 = *(const float4*)(cw2 + o);                            \
      _Pragma("unroll")                                                        \
      for (int Et = 0; Et < 4; Et++) {                                         \
        if (LIVE(Et)) {                                                        \
          float p = silu_f(ACC[Et][0] + cb4.x) * cw4.x;                        \
          p = fmaf(silu_f(ACC[Et][1] + cb4.y), cw4.y, p);                      \
          p = fmaf(silu_f(ACC[Et][2] + cb4.z), cw4.z, p);                      \
          p = fmaf(silu_f(ACC[Et][3] + cb4.w), cw4.w, p);                      \
          p += __shfl_xor(p, 16);                                              \
          p += __shfl_xor(p, 32);                                              \
          if (lane < 16) ce_red[Et * 16 + lane][OT] = p;                       \
        }                                                                      \
      }                                                                        \
    }
    EPID(accA, w)
    EPID(accB, (w + 4))
#undef EPID
  }
  __syncthreads();
  if (t < 64) {
    float c = 0.f;
#pragma unroll
    for (int wv = 0; wv < 8; wv++) c += ce_red[t][wv];
    ce_s[t] = (mf_s[t] != 0.f) ? c : 0.f;
  }
  __syncthreads();
  if (t < 6) {
    const int nd = t / 3, ax = t - nd * 3, ic = i0 + nd;
    float s = 0.f;
#pragma unroll
    for (int k = 0; k < 32; k++) s = fmaf(rel_s[ax][nd * 32 + k], ce_s[nd * 32 + k], s);
    const float cntf = fmaxf((float)cn_s[nd], 1.f);
    pos_out[ic * 3 + ax] = pos_in[ic * 3 + ax] + s / cntf;
  }
#undef LIVE
#undef MFMA_PASS
}

// ---------------- final heads (per node) ----------------
__global__ __launch_bounds__(256) void heads_kernel(
    const float* __restrict__ h, const float* __restrict__ pos,
    const float* __restrict__ fw1, const float* __restrict__ fb1,
    const float* __restrict__ fw2, const float* __restrict__ fb2,
    const float* __restrict__ cw1g, const float* __restrict__ cb1g,
    const float* __restrict__ cw2g, const float* __restrict__ cb2g,
    const float* __restrict__ sw, const float* __restrict__ sb,
    const float* __restrict__ iw,
    float* __restrict__ At, float* __restrict__ Bt,
    void* __restrict__ out, const int* __restrict__ flag) {
  __shared__ float hi_s[HD], v1[HD], red_s[256];
  const int i = blockIdx.x, t = threadIdx.x;
  const int fm = *flag;
  if (t < HD) hi_s[t] = h[(size_t)i * HD + t];
  __syncthreads();
  const int o = t & 127, ph = t >> 7;
  // forces MLP1
  {
    float p = 0.f;
#pragma unroll 4
    for (int f = ph * 64; f < ph * 64 + 64; f++) p = fmaf(hi_s[f], fw1[f * HD + o], p);
    red_s[t] = p;
  }
  __syncthreads();
  if (t < HD) v1[t] = tanhf(red_s[t] + red_s[t + 128] + fb1[t]);
  __syncthreads();
  if (t < 3) {
    float p = 0.f;
    for (int f = 0; f < HD; f++) p = fmaf(v1[f], fw2[f * 3 + t], p);
    stout(out, fm, OFF_F + (size_t)i * 3 + t, p + fb2[t]);
  }
  __syncthreads();
  // conformer MLP1
  {
    float p = 0.f;
#pragma unroll 4
    for (int f = ph * 64; f < ph * 64 + 64; f++) p = fmaf(hi_s[f], cw1g[f * HD + o], p);
    red_s[t] = p;
  }
  __syncthreads();
  if (t < HD) v1[t] = fmaxf(red_s[t] + red_s[t + 128] + cb1g[t], 0.f);
  __syncthreads();
  // conformer MLP2
  {
    const int oo = t & 63, pc = t >> 6;
    float p = 0.f;
#pragma unroll 4
    for (int f = pc * 32; f < pc * 32 + 32; f++) p = fmaf(v1[f], cw2g[f * 64 + oo], p);
    red_s[t] = p;
  }
  __syncthreads();
  if (t < 64)
    stout(out, fm, OFF_C + (size_t)i * 64 + t,
          red_s[t] + red_s[t + 64] + red_s[t + 128] + red_s[t + 192] + cb2g[t]);
  __syncthreads();
  // steric
  if (t < HD) red_s[t] = hi_s[t] * sw[t];
  __syncthreads();
  if (t == 0) {
    float p = 0.f;
    for (int f = 0; f < HD; f++) p += red_s[f];
    stout(out, fm, OFF_ST + (size_t)i, p + sb[0]);
  }
  __syncthreads();
  // interaction head per-node dots
  {
    const int g = t >> 5, l = t & 31;
    float p = 0.f;
    if (g < 6) {
      const int tt = g >> 1, half = g & 1;
#pragma unroll
      for (int r2 = 0; r2 < 4; r2++)
        p = fmaf(hi_s[l * 4 + r2], iw[tt * 258 + half * 128 + l * 4 + r2], p);
    }
    red_s[t] = p;
  }
  __syncthreads();
  if (t < 6) {
    float p = 0.f;
    for (int l = 0; l < 32; l++) p += red_s[t * 32 + l];
    const int tt = t >> 1;
    if ((t & 1) == 0) At[tt * NN + i] = p;
    else Bt[tt * NN + i] = p;
  }
  if (t < HD) stout(out, fm, OFF_H + (size_t)i * HD + t, hi_s[t]);
  if (t >= 128 && t < 131) stout(out, fm, OFF_POS + (size_t)i * 3 + (t - 128), pos[i * 3 + (t - 128)]);
}

// ---------------- interaction scores ----------------
__global__ void scores_kernel(const float* __restrict__ pos, const int* __restrict__ idx2,
                              const int* __restrict__ cnt2, const float* __restrict__ At,
                              const float* __restrict__ Bt, const float* __restrict__ iw,
                              const float* __restrict__ ib, void* __restrict__ out,
                              const int* __restrict__ flag) {
  int tid = blockIdx.x * 256 + threadIdx.x;
  if (tid >= 3 * NN * KI) return;
  const int fm = *flag;
  const int tt = tid / (NN * KI);
  const int r = tid % (NN * KI);
  const int n = r / KI;
  const int k = r % KI;
  float v = 0.f;
  if (k < cnt2[n]) {
    int j = idx2[n * KI + k];
    float dx = pos[n * 3 + 0] - pos[j * 3 + 0];
    float dy = pos[n * 3 + 1] - pos[j * 3 + 1];
    float dz = pos[n * 3 + 2] - pos[j * 3 + 2];
    float d2 = dx * dx + dy * dy + dz * dz;
    float dist = sqrtf(d2 + 1e-12f);
    float s = At[tt * NN + n] + Bt[tt * NN + j] + dist * iw[tt * 258 + 256] +
              (dist * 0.1f) * iw[tt * 258 + 257] + ib[tt];
    v = __builtin_amdgcn_rcpf(1.f + __expf(-s));
  }
  stout(out, fm, OFF_S + (size_t)tid, v);
}

extern "C" void kernel_launch(void* const* d_in, const int* in_sizes, int n_in,
                              void* d_out, int out_size, void* d_ws, size_t ws_size,
                              hipStream_t stream) {
  (void)in_sizes; (void)n_in; (void)out_size; (void)ws_size;

  float* wsf = (float*)d_ws;
  float* h_a = wsf + 0;             // 524288
  float* pos_a = wsf + 524288;      // 12288
  float* h_b = wsf + 536576;        // 524288
  float* pos_b = wsf + 1060864;     // 12288
  float* At = wsf + 1073152;        // 12288
  float* Bt = wsf + 1085440;        // 12288
  const int W0 = 1097728;

  static const int wcnt[23] = {197376, 768, 98304, 768, 98304, 768, 768,
                               196608, 768, 98304, 768, 16384, 128, 384, 3,
                               774, 3, 16384, 128, 8192, 64, 128, 1};
  int woff[23];
  {
    int o = W0;
    for (int k = 0; k < 23; k++) { woff[k] = o; o += wcnt[k]; }
  }
  const int IOFF = woff[22] + wcnt[22];
  int* ibase = (int*)d_ws;
  int* idx1 = ibase + IOFF;
  int* cnt1 = idx1 + NN * KE;
  int* idx2 = cnt1 + NN;
  int* cnt2 = idx2 + NN * KI;
  int* gstart = cnt2 + NN;
  int* flag = gstart + 33;
  // packed interleaved MFMA weight fragments, 16B-aligned
  int wboff = (int)((flag + 1) - ibase);
  wboff = (wboff + 3) & ~3;
  u16* WBP = (u16*)(ibase + wboff);
  // hpart / msum staging buffers (fp32, NN x HD each)
  float* HPART = wsf + (wboff + 18 * 32768 / 2);
  float* MSUM = HPART + (size_t)NN * HD;

  const float* EW1 = wsf + woff[0];
  const float* EB1 = wsf + woff[1];
  const float* EB2 = wsf + woff[3];
  const float* CB1 = wsf + woff[5];
  const float* CW2 = wsf + woff[6];
  const float* NW1 = wsf + woff[7];
  const float* NB1 = wsf + woff[8];
  const float* NW2 = wsf + woff[9];
  const float* NB2 = wsf + woff[10];
  const float* FW1 = wsf + woff[11];
  const float* FB1 = wsf + woff[12];
  const float* FW2 = wsf + woff[13];
  const float* FB2 = wsf + woff[14];
  const float* IW = wsf + woff[15];
  const float* IB = wsf + woff[16];
  const float* CW1G = wsf + woff[17];
  const float* CB1G = wsf + woff[18];
  const float* CW2G = wsf + woff[19];
  const float* CB2G = wsf + woff[20];
  const float* SW = wsf + woff[21];
  const float* SB = wsf + woff[22];

  probe_dtype<<<1, 256, 0, stream>>>((const u16*)d_in[0], flag);

  CvtTable tab;
  tab.src[0] = d_in[0]; tab.dstoff[0] = 0;       tab.cnt[0] = NN * HD;
  tab.src[1] = d_in[1]; tab.dstoff[1] = 524288;  tab.cnt[1] = NN * 3;
  for (int k = 0; k < 23; k++) {
    tab.src[2 + k] = d_in[3 + k];
    tab.dstoff[2 + k] = woff[k];
    tab.cnt[2 + k] = wcnt[k];
  }
  {
    dim3 g((NN * HD + 255) / 256, 25, 1);
    convert_all<<<g, 256, 0, stream>>>(tab, wsf, flag);
  }
  pack_weights<<<(18 * 32768 + 255) / 256, 256, 0, stream>>>(
      wsf, woff[0], woff[2], woff[4], WBP);

  const int* batch = (const int*)d_in[2];
  graph_bounds<<<NN / 256, 256, 0, stream>>>(batch, gstart);

  const float cut2s[3] = {9.f, 36.f, 100.f};
  float *hin = h_a, *pin = pos_a, *hout = h_b, *pout = pos_b;
  // hpart for layer 0
  hpart_kernel<<<NN / 2, 256, 0, stream>>>(h_a, EW1, EB1, HPART);
  for (int l = 0; l < 6; l++) {
    if ((l & 1) == 0)
      neigh_kernel<<<NN / 4, 256, 0, stream>>>(pin, batch, gstart, idx1, cnt1, KE, cut2s[l >> 1]);
    egnn_edge<<<NN / 2, 256, 0, stream>>>(
        hin, pin, pout, idx1, cnt1, HPART,
        EW1 + (size_t)l * 257 * HD + 256 * HD,
        EB2 + (size_t)l * HD, CB1 + (size_t)l * HD, CW2 + (size_t)l * HD,
        MSUM, WBP + (size_t)l * 3 * 32768);
    const int ln = (l < 5) ? (l + 1) : l;   // last layer's hpart is unused
    node_hpart_kernel<<<NN / 4, 256, 0, stream>>>(
        hin, MSUM,
        NW1 + (size_t)l * 256 * HD, NB1 + (size_t)l * HD,
        NW2 + (size_t)l * HD * HD, NB2 + (size_t)l * HD,
        EW1 + (size_t)ln * 257 * HD, EB1 + (size_t)ln * HD,
        hout, HPART, (l < 5) ? 1 : 0);
    float* th = hin; hin = hout; hout = th;
    float* tp = pin; pin = pout; pout = tp;
  }
  neigh_kernel<<<NN / 4, 256, 0, stream>>>(pin, batch, gstart, idx2, cnt2, KI, 100.f);
  heads_kernel<<<NN, 256, 0, stream>>>(hin, pin, FW1, FB1, FW2, FB2, CW1G, CB1G, CW2G, CB2G,
                                       SW, SB, IW, At, Bt, d_out, flag);
  scores_kernel<<<(3 * NN * KI + 255) / 256, 256, 0, stream>>>(
      pin, idx2, cnt2, At, Bt, IW, IB, d_out, flag);
}